// Round 8
// baseline (3437.154 us; speedup 1.0000x reference)
//
#include <hip/hip_runtime.h>
#include <hip/hip_bf16.h>
#include <stdint.h>
#include <stddef.h>

#define N_ 50000
#define E_ 600000
#define F_ 128
#define H_ 128
#define G_ 64
#define P_ 32
#define C_ 10

typedef __hip_bfloat16 bf16;

__device__ __forceinline__ float b2f(bf16 x){ return __bfloat162float(x); }
__device__ __forceinline__ float us2f(unsigned short u){ return __uint_as_float(((unsigned int)u)<<16); }
__device__ __forceinline__ unsigned short f2us(float x){ bf16 h = __float2bfloat16(x); return *(unsigned short*)&h; }
__device__ __forceinline__ float eluf(float x){ return x>0.f ? x : expm1f(x); }
__device__ __forceinline__ float bnf(float x,float m,float v,float g,float b){ return (x-m)*rsqrtf(v+1e-5f)*g+b; }
__device__ __forceinline__ float lrelu(float x){ return x>0.f ? x : 0.2f*x; }
__device__ __forceinline__ float expc(float x){ return __expf(fminf(x, 50.f)); }
__device__ __forceinline__ void atomAddF(float* a, float v){ unsafeAtomicAdd(a, v); }

union U8 { unsigned short s[8]; uint4 v; };

// ---------------- GEMM core: 64 rows x 128 cols per block, 256 threads ----------------
__device__ __forceinline__ void gemm_core(const float (*As)[132], const unsigned short (*Ws)[128],
                                          int cg, int rg, float acc[4][8]){
  for(int k=0;k<128;k++){
    uint4 wv = *(const uint4*)&Ws[k][cg*8];
    float w[8];
    w[0]=__uint_as_float(wv.x<<16); w[1]=__uint_as_float(wv.x&0xFFFF0000u);
    w[2]=__uint_as_float(wv.y<<16); w[3]=__uint_as_float(wv.y&0xFFFF0000u);
    w[4]=__uint_as_float(wv.z<<16); w[5]=__uint_as_float(wv.z&0xFFFF0000u);
    w[6]=__uint_as_float(wv.w<<16); w[7]=__uint_as_float(wv.w&0xFFFF0000u);
    float a0=As[rg*4+0][k], a1=As[rg*4+1][k], a2=As[rg*4+2][k], a3=As[rg*4+3][k];
    #pragma unroll
    for(int j=0;j<8;j++){
      acc[0][j]+=a0*w[j]; acc[1][j]+=a1*w[j]; acc[2][j]+=a2*w[j]; acc[3][j]+=a3*w[j];
    }
  }
}

__device__ __forceinline__ void stage_W128f(const float* W, unsigned short (*Ws)[128], int tid){
  unsigned short* d = &Ws[0][0];
  #pragma unroll
  for(int i=0;i<8;i++){
    int base = (tid + i*256)*8;
    float4 a = *(const float4*)(W + base);
    float4 b = *(const float4*)(W + base + 4);
    U8 u;
    u.s[0]=f2us(a.x); u.s[1]=f2us(a.y); u.s[2]=f2us(a.z); u.s[3]=f2us(a.w);
    u.s[4]=f2us(b.x); u.s[5]=f2us(b.y); u.s[6]=f2us(b.z); u.s[7]=f2us(b.w);
    *(uint4*)(d + base) = u.v;
  }
}

__global__ __launch_bounds__(256) void k_gemm_x_w1(const float* __restrict__ X, const float* __restrict__ W,
                                                   bf16* __restrict__ HB){
  __shared__ __align__(16) float As[64][132];
  __shared__ __align__(16) unsigned short Ws[128][128];
  const int tid = threadIdx.x;
  const int row0 = blockIdx.x*64;
  stage_W128f(W, Ws, tid);
  #pragma unroll
  for(int i=0;i<8;i++){
    int v = tid + i*256;
    int r = v>>5, c4 = (v&31)<<2;
    int gr = row0 + r;
    float4 f = make_float4(0.f,0.f,0.f,0.f);
    if(gr < N_) f = *(const float4*)(X + (size_t)gr*F_ + c4);
    *(float4*)&As[r][c4] = f;
  }
  __syncthreads();
  const int cg = tid&15, rg = tid>>4;
  float acc[4][8];
  #pragma unroll
  for(int r=0;r<4;r++) for(int j=0;j<8;j++) acc[r][j]=0.f;
  gemm_core(As, Ws, cg, rg, acc);
  #pragma unroll
  for(int r=0;r<4;r++){
    int gr = row0 + rg*4 + r;
    if(gr < N_){
      U8 u;
      #pragma unroll
      for(int j=0;j<8;j++) u.s[j] = f2us(acc[r][j]);
      *(uint4*)((unsigned short*)HB + (size_t)gr*H_ + cg*8) = u.v;
    }
  }
}

__global__ __launch_bounds__(256) void k_sage(const float* __restrict__ Ma, const float* __restrict__ cnt,
    const bf16* __restrict__ H1B, const float* __restrict__ Wl, const float* __restrict__ Wr,
    const float* __restrict__ bs, const float* __restrict__ g2, const float* __restrict__ be2,
    const float* __restrict__ m2, const float* __restrict__ v2, bf16* __restrict__ H2B){
  __shared__ __align__(16) float As[64][132];
  __shared__ __align__(16) unsigned short Ws[128][128];
  const int tid = threadIdx.x;
  const int row0 = blockIdx.x*64;
  const int cg = tid&15, rg = tid>>4;
  float acc[4][8];
  #pragma unroll
  for(int r=0;r<4;r++) for(int j=0;j<8;j++) acc[r][j]=0.f;

  stage_W128f(Wl, Ws, tid);
  #pragma unroll
  for(int i=0;i<8;i++){
    int v = tid + i*256;
    int r = v>>5, c4 = (v&31)<<2;
    int gr = row0 + r;
    float4 f = make_float4(0.f,0.f,0.f,0.f);
    if(gr < N_){
      float inv = 1.f/fmaxf(cnt[gr],1.f);
      float4 s = *(const float4*)(Ma + (size_t)gr*H_ + c4);
      f.x=s.x*inv; f.y=s.y*inv; f.z=s.z*inv; f.w=s.w*inv;
    }
    *(float4*)&As[r][c4] = f;
  }
  __syncthreads();
  gemm_core(As, Ws, cg, rg, acc);
  __syncthreads();
  stage_W128f(Wr, Ws, tid);
  #pragma unroll
  for(int i=0;i<8;i++){
    int v = tid + i*256;
    int r = v>>5, c4 = (v&31)<<2;
    int gr = row0 + r;
    float4 f = make_float4(0.f,0.f,0.f,0.f);
    if(gr < N_){
      ushort4 u = *(const ushort4*)((const unsigned short*)H1B + (size_t)gr*H_ + c4);
      f.x=us2f(u.x); f.y=us2f(u.y); f.z=us2f(u.z); f.w=us2f(u.w);
    }
    *(float4*)&As[r][c4] = f;
  }
  __syncthreads();
  gemm_core(As, Ws, cg, rg, acc);

  float bsv[8], gv[8], bev[8], mv[8], vv[8];
  #pragma unroll
  for(int j=0;j<8;j++){
    int c = cg*8+j;
    bsv[j]=bs[c]; gv[j]=g2[c]; bev[j]=be2[c]; mv[j]=m2[c]; vv[j]=v2[c];
  }
  #pragma unroll
  for(int r=0;r<4;r++){
    int gr = row0 + rg*4 + r;
    if(gr < N_){
      U8 u;
      #pragma unroll
      for(int j=0;j<8;j++){
        float x = acc[r][j] + bsv[j];
        u.s[j] = f2us(eluf(bnf(x, mv[j], vv[j], gv[j], bev[j])));
      }
      *(uint4*)((unsigned short*)H2B + (size_t)gr*H_ + cg*8) = u.v;
    }
  }
}

__global__ __launch_bounds__(256) void k_gat_gemm_h(const bf16* __restrict__ H2B, const float* __restrict__ Wg,
                                                    int hh, bf16* __restrict__ HGH){
  __shared__ __align__(16) float As[64][132];
  __shared__ __align__(16) unsigned short Ws[128][128];
  const int tid = threadIdx.x;
  const int row0 = blockIdx.x*64;
  const int cg = tid&15, rg = tid>>4;
  #pragma unroll
  for(int i=0;i<8;i++){
    int v = tid + i*256;
    int r = v>>5, c4 = (v&31)<<2;
    int gr = row0 + r;
    float4 f = make_float4(0.f,0.f,0.f,0.f);
    if(gr < N_){
      ushort4 u = *(const ushort4*)((const unsigned short*)H2B + (size_t)gr*H_ + c4);
      f.x=us2f(u.x); f.y=us2f(u.y); f.z=us2f(u.z); f.w=us2f(u.w);
    }
    *(float4*)&As[r][c4] = f;
  }
  #pragma unroll
  for(int i=0;i<8;i++){
    int v = tid + i*256;
    int k = v>>4, cs = v&15;
    const float* p = Wg + (size_t)k*384 + hh*128 + cs*8;
    float4 a = *(const float4*)p;
    float4 b = *(const float4*)(p+4);
    U8 u;
    u.s[0]=f2us(a.x); u.s[1]=f2us(a.y); u.s[2]=f2us(a.z); u.s[3]=f2us(a.w);
    u.s[4]=f2us(b.x); u.s[5]=f2us(b.y); u.s[6]=f2us(b.z); u.s[7]=f2us(b.w);
    *(uint4*)&Ws[k][cs*8] = u.v;
  }
  __syncthreads();
  float acc[4][8];
  #pragma unroll
  for(int r=0;r<4;r++) for(int j=0;j<8;j++) acc[r][j]=0.f;
  gemm_core(As, Ws, cg, rg, acc);
  #pragma unroll
  for(int r=0;r<4;r++){
    int gr = row0 + rg*4 + r;
    if(gr < N_){
      U8 u;
      #pragma unroll
      for(int j=0;j<8;j++) u.s[j] = f2us(acc[r][j]);
      *(uint4*)((unsigned short*)HGH + (size_t)gr*H_ + cg*8) = u.v;
    }
  }
}

// ---------------- node / edge kernels ----------------
__global__ __launch_bounds__(256) void k_count(const int* __restrict__ dst, float* __restrict__ cnt){
  int e = blockIdx.x*256 + threadIdx.x;
  if(e < E_) atomAddF(&cnt[dst[e]], 1.f);
}

__global__ __launch_bounds__(256) void k_dinv(const float* __restrict__ cnt, float* __restrict__ dinv){
  int n = blockIdx.x*256 + threadIdx.x;
  if(n < N_) dinv[n] = rsqrtf(cnt[n] + 1.f);
}

__global__ __launch_bounds__(256) void k_gcn_edge(const int* __restrict__ src, const int* __restrict__ dst,
    const float* __restrict__ dinv, const bf16* __restrict__ HB, float* __restrict__ ACC){
  int t = blockIdx.x*256 + threadIdx.x;
  int e = t>>6, f2 = t&63;
  int s = src[e], d = dst[e];
  float c = dinv[s]*dinv[d];
  unsigned int hv = *(const unsigned int*)((const unsigned short*)HB + (size_t)s*H_ + f2*2);
  atomAddF(&ACC[(size_t)d*H_ + f2*2],     us2f((unsigned short)(hv & 0xFFFFu))*c);
  atomAddF(&ACC[(size_t)d*H_ + f2*2 + 1], us2f((unsigned short)(hv >> 16))*c);
}

__global__ __launch_bounds__(256) void k_gcn_fin(const float* __restrict__ ACC, const float* __restrict__ dinv,
    const float* __restrict__ b1, const float* __restrict__ g1, const float* __restrict__ be1,
    const float* __restrict__ m1, const float* __restrict__ v1, bf16* HB){
  int i = blockIdx.x*256 + threadIdx.x;
  if(i < N_*H_){
    int n = i>>7, f = i&127;
    float dv = dinv[n];
    float x = ACC[i] + b2f(HB[i])*dv*dv + b1[f];
    HB[i] = __float2bfloat16(eluf(bnf(x, m1[f], v1[f], g1[f], be1[f])));
  }
}

__global__ __launch_bounds__(256) void k_sage_edge(const int* __restrict__ src, const int* __restrict__ dst,
    const bf16* __restrict__ H1B, float* __restrict__ ACC){
  int t = blockIdx.x*256 + threadIdx.x;
  int e = t>>6, f2 = t&63;
  int s = src[e], d = dst[e];
  unsigned int hv = *(const unsigned int*)((const unsigned short*)H1B + (size_t)s*H_ + f2*2);
  atomAddF(&ACC[(size_t)d*H_ + f2*2],     us2f((unsigned short)(hv & 0xFFFFu)));
  atomAddF(&ACC[(size_t)d*H_ + f2*2 + 1], us2f((unsigned short)(hv >> 16)));
}

__global__ __launch_bounds__(256) void k_al_h(const bf16* __restrict__ HGH, const float* __restrict__ a_src,
    const float* __restrict__ a_dst, int hh, float* __restrict__ als, float* __restrict__ ald){
  int n = (blockIdx.x*blockDim.x + threadIdx.x) >> 6;
  int lane = threadIdx.x & 63;
  if(n >= N_) return;
  unsigned int hv = *(const unsigned int*)((const unsigned short*)HGH + (size_t)n*H_ + lane*2);
  float h0 = us2f((unsigned short)(hv & 0xFFFFu));
  float h1v = us2f((unsigned short)(hv >> 16));
  float2 sv = *(const float2*)(a_src + hh*128 + lane*2);
  float2 dv = *(const float2*)(a_dst + hh*128 + lane*2);
  float ps = h0*sv.x + h1v*sv.y;
  float pd = h0*dv.x + h1v*dv.y;
  #pragma unroll
  for(int o=32;o>0;o>>=1){ ps += __shfl_down(ps,o,64); pd += __shfl_down(pd,o,64); }
  if(lane==0){ als[n]=ps; ald[n]=pd; }
}

__global__ __launch_bounds__(256) void k_dinit_h(const float* __restrict__ als, const float* __restrict__ ald,
                                                 float* __restrict__ den){
  int n = blockIdx.x*256 + threadIdx.x;
  if(n < N_) den[n] = expc(lrelu(als[n]+ald[n]));
}

__global__ __launch_bounds__(256) void k_att_den_h(const int* __restrict__ src, const int* __restrict__ dst,
    const float* __restrict__ als, const float* __restrict__ ald, float* __restrict__ den){
  int e = blockIdx.x*256 + threadIdx.x;
  if(e < E_){
    int s = src[e], d = dst[e];
    atomAddF(&den[d], expc(lrelu(als[s]+ald[d])));
  }
}

__global__ __launch_bounds__(256) void k_h3init_h(const bf16* __restrict__ HGH, const float* __restrict__ als,
    const float* __restrict__ ald, const float* __restrict__ den, int hh, float* __restrict__ ACC){
  int i = blockIdx.x*256 + threadIdx.x;
  if(i < N_*H_){
    int n = i>>7;
    float ex = expc(lrelu(als[n]+ald[n]));
    float a = ex / fmaxf(den[n], 1e-20f);
    float val = a * b2f(HGH[i]) * (1.f/3.f);
    ACC[i] = (hh==0) ? val : (ACC[i] + val);
  }
}

__global__ __launch_bounds__(256) void k_att_agg_h(const int* __restrict__ src, const int* __restrict__ dst,
    const float* __restrict__ als, const float* __restrict__ ald, const float* __restrict__ den,
    const bf16* __restrict__ HGH, float* __restrict__ ACC){
  int t = blockIdx.x*256 + threadIdx.x;
  int e = t>>6, f2 = t&63;
  int s = src[e], d = dst[e];
  float a = expc(lrelu(als[s]+ald[d])) / fmaxf(den[d], 1e-20f) * (1.f/3.f);
  unsigned int hv = *(const unsigned int*)((const unsigned short*)HGH + (size_t)s*H_ + f2*2);
  atomAddF(&ACC[(size_t)d*H_ + f2*2],     a * us2f((unsigned short)(hv & 0xFFFFu)));
  atomAddF(&ACC[(size_t)d*H_ + f2*2 + 1], a * us2f((unsigned short)(hv >> 16)));
}

__global__ __launch_bounds__(256) void k_h3fin_pool(const float* __restrict__ ACC, const float* __restrict__ bg,
    const float* __restrict__ g3, const float* __restrict__ be3, const float* __restrict__ m3, const float* __restrict__ v3,
    const int* __restrict__ batch, float* __restrict__ pooled, float* __restrict__ gcnt){
  int i = blockIdx.x*256 + threadIdx.x;
  if(i < N_*H_){
    int n = i>>7, f = i&127;
    float x = ACC[i] + bg[f];
    x = eluf(bnf(x, m3[f], v3[f], g3[f], be3[f]));
    int b = batch[n]; b = b<0?0:(b>63?63:b);
    atomAddF(&pooled[b*H_ + f], x);
    if(f == 0) atomAddF(&gcnt[b], 1.f);
  }
}

// per-graph head — fp32 output buffer
__global__ __launch_bounds__(128) void k_head(const float* __restrict__ pooledacc, const float* __restrict__ gcnt,
    const float* __restrict__ protos, const float* __restrict__ Wc, const float* __restrict__ bc,
    const float* __restrict__ Wd1, const float* __restrict__ bd1, const float* __restrict__ Wd2, const float* __restrict__ bd2,
    float* __restrict__ out){
  const int g = blockIdx.x, t = threadIdx.x;
  __shared__ float p[128], xn[128], red[128], sims[32], es[32], asg[32], pe[128], t1[256];
  __shared__ float nrm;
  float cg_ = fmaxf(gcnt[g], 1.f);
  p[t] = pooledacc[g*128 + t] / cg_;
  __syncthreads();
  red[t] = p[t]*p[t];
  __syncthreads();
  for(int s=64;s>0;s>>=1){ if(t<s) red[t]+=red[t+s]; __syncthreads(); }
  if(t==0) nrm = fmaxf(sqrtf(red[0]), 1e-8f);
  __syncthreads();
  xn[t] = p[t]/nrm;
  __syncthreads();
  if(t<32){
    float s=0.f, pn=0.f;
    for(int f=0;f<128;f++){ float pv=protos[t*128+f]; s += xn[f]*pv; pn += pv*pv; }
    sims[t] = s / fmaxf(sqrtf(pn), 1e-8f);
  }
  __syncthreads();
  if(t<32){
    float mx=-1e30f;
    for(int j=0;j<32;j++) mx = fmaxf(mx, sims[j]);
    es[t] = __expf(sims[t]-mx);
  }
  __syncthreads();
  if(t<32){
    float sm=0.f;
    for(int j=0;j<32;j++) sm += es[j];
    float a = es[t]/fmaxf(sm,1e-20f);
    asg[t] = a;
    out[8832 + g*32 + t] = a;               // assignments [G,P]
  }
  __syncthreads();
  {
    float s=0.f;
    for(int pp=0;pp<32;pp++) s += asg[pp]*protos[pp*128+t];
    pe[t] = s;
    out[640 + g*128 + t] = s;               // proto_emb [G,H]
  }
  __syncthreads();
  if(t<10){
    float s = bc[t];
    for(int f=0;f<128;f++) s += pe[f]*Wc[f*10+t];
    out[g*10 + t] = s;                      // logits [G,C]
  }
  for(int j=t;j<256;j+=128){
    float s = bd1[j];
    for(int f=0;f<128;f++) s += p[f]*Wd1[f*256+j];
    t1[j] = fmaxf(s, 0.f);
  }
  __syncthreads();
  {
    float s = bd2[t];
    for(int j=0;j<256;j++) s += t1[j]*Wd2[j*128+t];
    out[10880 + g*128 + t] = s;             // reconstructed [G,F]
  }
}

__global__ void k_sentinel(float* out, float code){
  out[0] = code;
}

extern "C" void kernel_launch(void* const* d_in, const int* in_sizes, int n_in,
                              void* d_out, int out_size, void* d_ws, size_t ws_size,
                              hipStream_t stream){
  const float* X    = (const float*)d_in[0];
  const int*  EI    = (const int*)d_in[1];
  const int*  batch = (const int*)d_in[2];
  const int* src = EI;
  const int* dst = EI + E_;

  // input-order mapping: dict order (default) vs reference-parameter order (in_sizes[5]==128 -> g1)
  int iW1,ib1,iWl,iWr,ibs,iWg,ias,iad,ibg,ipr,iWc,ibc,iWd1,ibd1,iWd2,ibd2;
  int ig1,ibe1,im1,iv1,ig2,ibe2,im2,iv2,ig3,ibe3,im3,iv3;
  if(n_in >= 31 && in_sizes[5] == 128){
    iW1=3; ib1=4; ig1=5; ibe1=6; im1=7; iv1=8;
    iWl=9; iWr=10; ibs=11; ig2=12; ibe2=13; im2=14; iv2=15;
    iWg=16; ias=17; iad=18; ibg=19; ig3=20; ibe3=21; im3=22; iv3=23;
    ipr=24; iWc=25; ibc=26; iWd1=27; ibd1=28; iWd2=29; ibd2=30;
  }else{
    iW1=3; ib1=4; iWl=5; iWr=6; ibs=7; iWg=8; ias=9; iad=10; ibg=11;
    ipr=12; iWc=13; ibc=14; iWd1=15; ibd1=16; iWd2=17; ibd2=18;
    ig1=19; ibe1=20; im1=21; iv1=22; ig2=23; ibe2=24; im2=25; iv2=26;
    ig3=27; ibe3=28; im3=29; iv3=30;
  }
  const float* W1 = (const float*)d_in[iW1];   const float* b1 = (const float*)d_in[ib1];
  const float* Wl = (const float*)d_in[iWl];   const float* Wr = (const float*)d_in[iWr];
  const float* bs = (const float*)d_in[ibs];   const float* Wg = (const float*)d_in[iWg];
  const float* a_src = (const float*)d_in[ias]; const float* a_dst = (const float*)d_in[iad];
  const float* bg = (const float*)d_in[ibg];   const float* protos = (const float*)d_in[ipr];
  const float* Wc = (const float*)d_in[iWc];   const float* bc = (const float*)d_in[ibc];
  const float* Wd1 = (const float*)d_in[iWd1]; const float* bd1 = (const float*)d_in[ibd1];
  const float* Wd2 = (const float*)d_in[iWd2]; const float* bd2 = (const float*)d_in[ibd2];
  const float* g1 = (const float*)d_in[ig1];   const float* be1 = (const float*)d_in[ibe1];
  const float* m1 = (const float*)d_in[im1];   const float* v1 = (const float*)d_in[iv1];
  const float* g2 = (const float*)d_in[ig2];   const float* be2 = (const float*)d_in[ibe2];
  const float* m2 = (const float*)d_in[im2];   const float* v2 = (const float*)d_in[iv2];
  const float* g3 = (const float*)d_in[ig3];   const float* be3 = (const float*)d_in[ibe3];
  const float* m3 = (const float*)d_in[im3];   const float* v3 = (const float*)d_in[iv3];

  // workspace: ACC f32 NF | RA bf16 NF | RB bf16 NF | tail f32 (52.23 MB)
  const size_t NF = (size_t)N_*H_;
  const size_t tailN = (size_t)5*N_ + G_*H_ + G_;
  const size_t NEED = NF*8 + tailN*4;
  if(ws_size < NEED){
    k_sentinel<<<1,1,0,stream>>>((float*)d_out, 1000.f + (float)(ws_size>>20));
    return;
  }
  float* ACC = (float*)d_ws;
  bf16*  RA  = (bf16*)(ACC + NF);    // hb -> h1b (in place) -> hgh (per head)
  bf16*  RB  = RA + NF;              // h2b
  float* tail = (float*)(RB + NF);
  float* cnt  = tail;
  float* dinv = cnt + N_;
  float* als  = dinv + N_;
  float* ald  = als + N_;
  float* den  = ald + N_;
  float* pooled = den + N_;
  float* gcnt = pooled + (size_t)G_*H_;

  // ---- GCN ----
  hipMemsetAsync(cnt, 0, N_*sizeof(float), stream);
  k_count<<<(E_+255)/256, 256, 0, stream>>>(dst, cnt);
  k_dinv<<<(N_+255)/256, 256, 0, stream>>>(cnt, dinv);
  hipMemsetAsync(ACC, 0, NF*sizeof(float), stream);
  k_gemm_x_w1<<<(N_+63)/64, 256, 0, stream>>>(X, W1, RA);
  k_gcn_edge<<<(E_*64)/256, 256, 0, stream>>>(src, dst, dinv, RA, ACC);
  k_gcn_fin<<<(N_*H_+255)/256, 256, 0, stream>>>(ACC, dinv, b1, g1, be1, m1, v1, RA);
  // ---- SAGE ----
  hipMemsetAsync(ACC, 0, NF*sizeof(float), stream);
  k_sage_edge<<<(E_*64)/256, 256, 0, stream>>>(src, dst, RA, ACC);
  k_sage<<<(N_+63)/64, 256, 0, stream>>>(ACC, cnt, RA, Wl, Wr, bs, g2, be2, m2, v2, RB);
  // ---- GAT (per head) ----
  for(int hh=0; hh<3; hh++){
    k_gat_gemm_h<<<(N_+63)/64, 256, 0, stream>>>(RB, Wg, hh, RA);
    k_al_h<<<(N_*64)/256, 256, 0, stream>>>(RA, a_src, a_dst, hh, als, ald);
    k_dinit_h<<<(N_+255)/256, 256, 0, stream>>>(als, ald, den);
    k_att_den_h<<<(E_+255)/256, 256, 0, stream>>>(src, dst, als, ald, den);
    k_h3init_h<<<(N_*H_+255)/256, 256, 0, stream>>>(RA, als, ald, den, hh, ACC);
    k_att_agg_h<<<(E_*64)/256, 256, 0, stream>>>(src, dst, als, ald, den, RA, ACC);
  }
  // ---- pool + heads ----
  hipMemsetAsync(pooled, 0, (size_t)(G_*H_+G_)*sizeof(float), stream);
  k_h3fin_pool<<<(N_*H_+255)/256, 256, 0, stream>>>(ACC, bg, g3, be3, m3, v3, batch, pooled, gcnt);
  k_head<<<G_, 128, 0, stream>>>(pooled, gcnt, protos, Wc, bc, Wd1, bd1, Wd2, bd2, (float*)d_out);
}

// Round 9
// 1410.487 us; speedup vs baseline: 2.4369x; 2.4369x over previous
//
#include <hip/hip_runtime.h>
#include <hip/hip_bf16.h>
#include <stdint.h>
#include <stddef.h>

#define N_ 50000
#define E_ 600000
#define F_ 128
#define H_ 128
#define G_ 64
#define P_ 32
#define C_ 10

typedef __hip_bfloat16 bf16;

__device__ __forceinline__ float b2f(bf16 x){ return __bfloat162float(x); }
__device__ __forceinline__ float us2f(unsigned short u){ return __uint_as_float(((unsigned int)u)<<16); }
__device__ __forceinline__ unsigned short f2us(float x){ bf16 h = __float2bfloat16(x); return *(unsigned short*)&h; }
__device__ __forceinline__ float eluf(float x){ return x>0.f ? x : expm1f(x); }
__device__ __forceinline__ float bnf(float x,float m,float v,float g,float b){ return (x-m)*rsqrtf(v+1e-5f)*g+b; }
__device__ __forceinline__ float lrelu(float x){ return x>0.f ? x : 0.2f*x; }
__device__ __forceinline__ float expc(float x){ return __expf(fminf(x, 50.f)); }
__device__ __forceinline__ void atomAddF(float* a, float v){ unsafeAtomicAdd(a, v); }

union U8 { unsigned short s[8]; uint4 v; };

// ---------------- GEMM core: 64 rows x 128 cols per block, 256 threads ----------------
__device__ __forceinline__ void gemm_core(const float (*As)[132], const unsigned short (*Ws)[128],
                                          int cg, int rg, float acc[4][8]){
  for(int k=0;k<128;k++){
    uint4 wv = *(const uint4*)&Ws[k][cg*8];
    float w[8];
    w[0]=__uint_as_float(wv.x<<16); w[1]=__uint_as_float(wv.x&0xFFFF0000u);
    w[2]=__uint_as_float(wv.y<<16); w[3]=__uint_as_float(wv.y&0xFFFF0000u);
    w[4]=__uint_as_float(wv.z<<16); w[5]=__uint_as_float(wv.z&0xFFFF0000u);
    w[6]=__uint_as_float(wv.w<<16); w[7]=__uint_as_float(wv.w&0xFFFF0000u);
    float a0=As[rg*4+0][k], a1=As[rg*4+1][k], a2=As[rg*4+2][k], a3=As[rg*4+3][k];
    #pragma unroll
    for(int j=0;j<8;j++){
      acc[0][j]+=a0*w[j]; acc[1][j]+=a1*w[j]; acc[2][j]+=a2*w[j]; acc[3][j]+=a3*w[j];
    }
  }
}

__device__ __forceinline__ void stage_W128f(const float* W, unsigned short (*Ws)[128], int tid){
  unsigned short* d = &Ws[0][0];
  #pragma unroll
  for(int i=0;i<8;i++){
    int base = (tid + i*256)*8;
    float4 a = *(const float4*)(W + base);
    float4 b = *(const float4*)(W + base + 4);
    U8 u;
    u.s[0]=f2us(a.x); u.s[1]=f2us(a.y); u.s[2]=f2us(a.z); u.s[3]=f2us(a.w);
    u.s[4]=f2us(b.x); u.s[5]=f2us(b.y); u.s[6]=f2us(b.z); u.s[7]=f2us(b.w);
    *(uint4*)(d + base) = u.v;
  }
}

// stage 64x128 bf16 node-feature tile into As (fp32)
__device__ __forceinline__ void stage_A_bf16(const bf16* B, int row0, float (*As)[132], int tid){
  #pragma unroll
  for(int i=0;i<8;i++){
    int v = tid + i*256;
    int r = v>>5, c4 = (v&31)<<2;
    int gr = row0 + r;
    float4 f = make_float4(0.f,0.f,0.f,0.f);
    if(gr < N_){
      ushort4 u = *(const ushort4*)((const unsigned short*)B + (size_t)gr*H_ + c4);
      f.x=us2f(u.x); f.y=us2f(u.y); f.z=us2f(u.z); f.w=us2f(u.w);
    }
    *(float4*)&As[r][c4] = f;
  }
}

// hb(bf16) = X(f32) @ W1(f32)
__global__ __launch_bounds__(256) void k_gemm_x_w1(const float* __restrict__ X, const float* __restrict__ W,
                                                   bf16* __restrict__ HB){
  __shared__ __align__(16) float As[64][132];
  __shared__ __align__(16) unsigned short Ws[128][128];
  const int tid = threadIdx.x;
  const int row0 = blockIdx.x*64;
  stage_W128f(W, Ws, tid);
  #pragma unroll
  for(int i=0;i<8;i++){
    int v = tid + i*256;
    int r = v>>5, c4 = (v&31)<<2;
    int gr = row0 + r;
    float4 f = make_float4(0.f,0.f,0.f,0.f);
    if(gr < N_) f = *(const float4*)(X + (size_t)gr*F_ + c4);
    *(float4*)&As[r][c4] = f;
  }
  __syncthreads();
  const int cg = tid&15, rg = tid>>4;
  float acc[4][8];
  #pragma unroll
  for(int r=0;r<4;r++) for(int j=0;j<8;j++) acc[r][j]=0.f;
  gemm_core(As, Ws, cg, rg, acc);
  #pragma unroll
  for(int r=0;r<4;r++){
    int gr = row0 + rg*4 + r;
    if(gr < N_){
      U8 u;
      #pragma unroll
      for(int j=0;j<8;j++) u.s[j] = f2us(acc[r][j]);
      *(uint4*)((unsigned short*)HB + (size_t)gr*H_ + cg*8) = u.v;
    }
  }
}

// h2b(bf16) = elu(bn2( meanB@Wl + h1B@Wr + bs ))
__global__ __launch_bounds__(256) void k_sage(const bf16* __restrict__ MaB, const bf16* __restrict__ H1B,
    const float* __restrict__ Wl, const float* __restrict__ Wr,
    const float* __restrict__ bs, const float* __restrict__ g2, const float* __restrict__ be2,
    const float* __restrict__ m2, const float* __restrict__ v2, bf16* __restrict__ H2B){
  __shared__ __align__(16) float As[64][132];
  __shared__ __align__(16) unsigned short Ws[128][128];
  const int tid = threadIdx.x;
  const int row0 = blockIdx.x*64;
  const int cg = tid&15, rg = tid>>4;
  float acc[4][8];
  #pragma unroll
  for(int r=0;r<4;r++) for(int j=0;j<8;j++) acc[r][j]=0.f;

  stage_W128f(Wl, Ws, tid);
  stage_A_bf16(MaB, row0, As, tid);
  __syncthreads();
  gemm_core(As, Ws, cg, rg, acc);
  __syncthreads();
  stage_W128f(Wr, Ws, tid);
  stage_A_bf16(H1B, row0, As, tid);
  __syncthreads();
  gemm_core(As, Ws, cg, rg, acc);

  float bsv[8], gv[8], bev[8], mv[8], vv[8];
  #pragma unroll
  for(int j=0;j<8;j++){
    int c = cg*8+j;
    bsv[j]=bs[c]; gv[j]=g2[c]; bev[j]=be2[c]; mv[j]=m2[c]; vv[j]=v2[c];
  }
  #pragma unroll
  for(int r=0;r<4;r++){
    int gr = row0 + rg*4 + r;
    if(gr < N_){
      U8 u;
      #pragma unroll
      for(int j=0;j<8;j++){
        float x = acc[r][j] + bsv[j];
        u.s[j] = f2us(eluf(bnf(x, mv[j], vv[j], gv[j], bev[j])));
      }
      *(uint4*)((unsigned short*)H2B + (size_t)gr*H_ + cg*8) = u.v;
    }
  }
}

// hgh(bf16) = h2b @ Wg[:, hh*128:(hh+1)*128]   (Wg fp32, 128x384)
__global__ __launch_bounds__(256) void k_gat_gemm_h(const bf16* __restrict__ H2B, const float* __restrict__ Wg,
                                                    int hh, bf16* __restrict__ HGH){
  __shared__ __align__(16) float As[64][132];
  __shared__ __align__(16) unsigned short Ws[128][128];
  const int tid = threadIdx.x;
  const int row0 = blockIdx.x*64;
  const int cg = tid&15, rg = tid>>4;
  stage_A_bf16(H2B, row0, As, tid);
  #pragma unroll
  for(int i=0;i<8;i++){
    int v = tid + i*256;
    int k = v>>4, cs = v&15;
    const float* p = Wg + (size_t)k*384 + hh*128 + cs*8;
    float4 a = *(const float4*)p;
    float4 b = *(const float4*)(p+4);
    U8 u;
    u.s[0]=f2us(a.x); u.s[1]=f2us(a.y); u.s[2]=f2us(a.z); u.s[3]=f2us(a.w);
    u.s[4]=f2us(b.x); u.s[5]=f2us(b.y); u.s[6]=f2us(b.z); u.s[7]=f2us(b.w);
    *(uint4*)&Ws[k][cs*8] = u.v;
  }
  __syncthreads();
  float acc[4][8];
  #pragma unroll
  for(int r=0;r<4;r++) for(int j=0;j<8;j++) acc[r][j]=0.f;
  gemm_core(As, Ws, cg, rg, acc);
  #pragma unroll
  for(int r=0;r<4;r++){
    int gr = row0 + rg*4 + r;
    if(gr < N_){
      U8 u;
      #pragma unroll
      for(int j=0;j<8;j++) u.s[j] = f2us(acc[r][j]);
      *(uint4*)((unsigned short*)HGH + (size_t)gr*H_ + cg*8) = u.v;
    }
  }
}

// ---------------- CSR build ----------------
__global__ __launch_bounds__(256) void k_count(const int* __restrict__ dst, int* __restrict__ cnt){
  int e = blockIdx.x*256 + threadIdx.x;
  if(e < E_) atomicAdd(&cnt[dst[e]], 1);
}

// single-block exclusive scan of cnt -> row_ptr & tmp; also dinv = rsqrt(cnt+1)
__global__ __launch_bounds__(1024) void k_scan(const int* __restrict__ cnt, int* __restrict__ row_ptr,
                                               int* __restrict__ tmp, float* __restrict__ dinv){
  __shared__ int sh[1024];
  __shared__ int carry_s;
  const int t = threadIdx.x;
  if(t==0) carry_s = 0;
  __syncthreads();
  for(int base=0; base<N_; base+=1024){
    int i = base + t;
    int v = (i<N_) ? cnt[i] : 0;
    sh[t] = v;
    __syncthreads();
    for(int o=1;o<1024;o<<=1){
      int add = (t>=o) ? sh[t-o] : 0;
      __syncthreads();
      sh[t] += add;
      __syncthreads();
    }
    int excl = carry_s + sh[t] - v;
    if(i<N_){
      row_ptr[i] = excl;
      tmp[i] = excl;
      dinv[i] = rsqrtf((float)v + 1.f);
    }
    __syncthreads();
    if(t==0) carry_s += sh[1023];
    __syncthreads();
  }
  if(t==0) row_ptr[N_] = carry_s;
}

__global__ __launch_bounds__(256) void k_scatter(const int* __restrict__ src, const int* __restrict__ dst,
                                                 int* __restrict__ tmp, int* __restrict__ esrc){
  int e = blockIdx.x*256 + threadIdx.x;
  if(e < E_){
    int d = dst[e];
    int pos = atomicAdd(&tmp[d], 1);
    esrc[pos] = src[e];
  }
}

// ---------------- CSR gather kernels (1 wave = 1 node, 2 feats/lane) ----------------
__global__ __launch_bounds__(256) void k_gcn_gather(const int* __restrict__ row_ptr, const int* __restrict__ esrc,
    const float* __restrict__ dinv, const bf16* __restrict__ HB,
    const float* __restrict__ b1, const float* __restrict__ g1, const float* __restrict__ be1,
    const float* __restrict__ m1, const float* __restrict__ v1, bf16* __restrict__ H1B){
  int n = blockIdx.x*4 + (threadIdx.x>>6);
  int lane = threadIdx.x & 63;
  if(n >= N_) return;
  int beg = row_ptr[n], end = row_ptr[n+1];
  float dn = dinv[n];
  float a0 = 0.f, a1 = 0.f;
  const unsigned short* hb = (const unsigned short*)HB;
  for(int e=beg; e<end; e++){
    int s = esrc[e];
    float c = dinv[s]*dn;
    unsigned int hv = *(const unsigned int*)(hb + (size_t)s*H_ + lane*2);
    a0 += c*us2f((unsigned short)(hv & 0xFFFFu));
    a1 += c*us2f((unsigned short)(hv >> 16));
  }
  unsigned int hv = *(const unsigned int*)(hb + (size_t)n*H_ + lane*2);
  int f0 = lane*2, f1 = f0+1;
  float x0 = a0 + us2f((unsigned short)(hv & 0xFFFFu))*dn*dn + b1[f0];
  float x1 = a1 + us2f((unsigned short)(hv >> 16))*dn*dn + b1[f1];
  x0 = eluf(bnf(x0, m1[f0], v1[f0], g1[f0], be1[f0]));
  x1 = eluf(bnf(x1, m1[f1], v1[f1], g1[f1], be1[f1]));
  unsigned int o = ((unsigned int)f2us(x1)<<16) | f2us(x0);
  *(unsigned int*)((unsigned short*)H1B + (size_t)n*H_ + lane*2) = o;
}

__global__ __launch_bounds__(256) void k_sage_gather(const int* __restrict__ row_ptr, const int* __restrict__ esrc,
    const bf16* __restrict__ H1B, bf16* __restrict__ MeanB){
  int n = blockIdx.x*4 + (threadIdx.x>>6);
  int lane = threadIdx.x & 63;
  if(n >= N_) return;
  int beg = row_ptr[n], end = row_ptr[n+1];
  float a0 = 0.f, a1 = 0.f;
  const unsigned short* hb = (const unsigned short*)H1B;
  for(int e=beg; e<end; e++){
    int s = esrc[e];
    unsigned int hv = *(const unsigned int*)(hb + (size_t)s*H_ + lane*2);
    a0 += us2f((unsigned short)(hv & 0xFFFFu));
    a1 += us2f((unsigned short)(hv >> 16));
  }
  float inv = 1.f / fmaxf((float)(end-beg), 1.f);
  unsigned int o = ((unsigned int)f2us(a1*inv)<<16) | f2us(a0*inv);
  *(unsigned int*)((unsigned short*)MeanB + (size_t)n*H_ + lane*2) = o;
}

// attention logits per node for head hh
__global__ __launch_bounds__(256) void k_al_h(const bf16* __restrict__ HGH, const float* __restrict__ a_src,
    const float* __restrict__ a_dst, int hh, float* __restrict__ als, float* __restrict__ ald){
  int n = (blockIdx.x*blockDim.x + threadIdx.x) >> 6;
  int lane = threadIdx.x & 63;
  if(n >= N_) return;
  unsigned int hv = *(const unsigned int*)((const unsigned short*)HGH + (size_t)n*H_ + lane*2);
  float h0 = us2f((unsigned short)(hv & 0xFFFFu));
  float h1v = us2f((unsigned short)(hv >> 16));
  float2 sv = *(const float2*)(a_src + hh*128 + lane*2);
  float2 dv = *(const float2*)(a_dst + hh*128 + lane*2);
  float ps = h0*sv.x + h1v*sv.y;
  float pd = h0*dv.x + h1v*dv.y;
  #pragma unroll
  for(int o=32;o>0;o>>=1){ ps += __shfl_down(ps,o,64); pd += __shfl_down(pd,o,64); }
  if(lane==0){ als[n]=ps; ald[n]=pd; }
}

// GAT gather for head hh: two passes (den, weighted sum) + self loop; accumulate head mean into ACCB (bf16)
__global__ __launch_bounds__(256) void k_gat_gather(const int* __restrict__ row_ptr, const int* __restrict__ esrc,
    const float* __restrict__ als, const float* __restrict__ ald, const bf16* __restrict__ HGH,
    int hh, bf16* __restrict__ ACCB){
  int n = blockIdx.x*4 + (threadIdx.x>>6);
  int lane = threadIdx.x & 63;
  if(n >= N_) return;
  int beg = row_ptr[n], end = row_ptr[n+1];
  float aldn = ald[n];
  float eself = expc(lrelu(als[n] + aldn));
  float den = eself;
  for(int e=beg; e<end; e++){
    den += expc(lrelu(als[esrc[e]] + aldn));
  }
  const unsigned short* hb = (const unsigned short*)HGH;
  unsigned int hv = *(const unsigned int*)(hb + (size_t)n*H_ + lane*2);
  float a0 = eself*us2f((unsigned short)(hv & 0xFFFFu));
  float a1 = eself*us2f((unsigned short)(hv >> 16));
  for(int e=beg; e<end; e++){
    int s = esrc[e];
    float w = expc(lrelu(als[s] + aldn));
    unsigned int sv = *(const unsigned int*)(hb + (size_t)s*H_ + lane*2);
    a0 += w*us2f((unsigned short)(sv & 0xFFFFu));
    a1 += w*us2f((unsigned short)(sv >> 16));
  }
  float inv = 1.f/(3.f*den);
  a0 *= inv; a1 *= inv;
  unsigned int* acc = (unsigned int*)((unsigned short*)ACCB + (size_t)n*H_ + lane*2);
  if(hh != 0){
    unsigned int old = *acc;
    a0 += us2f((unsigned short)(old & 0xFFFFu));
    a1 += us2f((unsigned short)(old >> 16));
  }
  *acc = ((unsigned int)f2us(a1)<<16) | f2us(a0);
}

// h3 finalize (+bg, bn3, elu) + pooled accumulation (reads bf16 acc)
__global__ __launch_bounds__(256) void k_h3fin_pool(const bf16* __restrict__ ACCB, const float* __restrict__ bg,
    const float* __restrict__ g3, const float* __restrict__ be3, const float* __restrict__ m3, const float* __restrict__ v3,
    const int* __restrict__ batch, float* __restrict__ pooled, float* __restrict__ gcnt){
  int i = blockIdx.x*256 + threadIdx.x;
  if(i < N_*H_){
    int n = i>>7, f = i&127;
    float x = b2f(ACCB[i]) + bg[f];
    x = eluf(bnf(x, m3[f], v3[f], g3[f], be3[f]));
    int b = batch[n]; b = b<0?0:(b>63?63:b);
    atomAddF(&pooled[b*H_ + f], x);
    if(f == 0) atomAddF(&gcnt[b], 1.f);
  }
}

// per-graph head — fp32 output
__global__ __launch_bounds__(128) void k_head(const float* __restrict__ pooledacc, const float* __restrict__ gcnt,
    const float* __restrict__ protos, const float* __restrict__ Wc, const float* __restrict__ bc,
    const float* __restrict__ Wd1, const float* __restrict__ bd1, const float* __restrict__ Wd2, const float* __restrict__ bd2,
    float* __restrict__ out){
  const int g = blockIdx.x, t = threadIdx.x;
  __shared__ float p[128], xn[128], red[128], sims[32], es[32], asg[32], pe[128], t1[256];
  __shared__ float nrm;
  float cg_ = fmaxf(gcnt[g], 1.f);
  p[t] = pooledacc[g*128 + t] / cg_;
  __syncthreads();
  red[t] = p[t]*p[t];
  __syncthreads();
  for(int s=64;s>0;s>>=1){ if(t<s) red[t]+=red[t+s]; __syncthreads(); }
  if(t==0) nrm = fmaxf(sqrtf(red[0]), 1e-8f);
  __syncthreads();
  xn[t] = p[t]/nrm;
  __syncthreads();
  if(t<32){
    float s=0.f, pn=0.f;
    for(int f=0;f<128;f++){ float pv=protos[t*128+f]; s += xn[f]*pv; pn += pv*pv; }
    sims[t] = s / fmaxf(sqrtf(pn), 1e-8f);
  }
  __syncthreads();
  if(t<32){
    float mx=-1e30f;
    for(int j=0;j<32;j++) mx = fmaxf(mx, sims[j]);
    es[t] = __expf(sims[t]-mx);
  }
  __syncthreads();
  if(t<32){
    float sm=0.f;
    for(int j=0;j<32;j++) sm += es[j];
    float a = es[t]/fmaxf(sm,1e-20f);
    asg[t] = a;
    out[8832 + g*32 + t] = a;               // assignments [G,P]
  }
  __syncthreads();
  {
    float s=0.f;
    for(int pp=0;pp<32;pp++) s += asg[pp]*protos[pp*128+t];
    pe[t] = s;
    out[640 + g*128 + t] = s;               // proto_emb [G,H]
  }
  __syncthreads();
  if(t<10){
    float s = bc[t];
    for(int f=0;f<128;f++) s += pe[f]*Wc[f*10+t];
    out[g*10 + t] = s;                      // logits [G,C]
  }
  for(int j=t;j<256;j+=128){
    float s = bd1[j];
    for(int f=0;f<128;f++) s += p[f]*Wd1[f*256+j];
    t1[j] = fmaxf(s, 0.f);
  }
  __syncthreads();
  {
    float s = bd2[t];
    for(int j=0;j<256;j++) s += t1[j]*Wd2[j*128+t];
    out[10880 + g*128 + t] = s;             // reconstructed [G,F]
  }
}

__global__ void k_sentinel(float* out, float code){
  out[0] = code;
}

extern "C" void kernel_launch(void* const* d_in, const int* in_sizes, int n_in,
                              void* d_out, int out_size, void* d_ws, size_t ws_size,
                              hipStream_t stream){
  const float* X    = (const float*)d_in[0];
  const int*  EI    = (const int*)d_in[1];
  const int*  batch = (const int*)d_in[2];
  const int* src = EI;
  const int* dst = EI + E_;

  // input-order mapping (dict order confirmed; keep param-order fallback)
  int iW1,ib1,iWl,iWr,ibs,iWg,ias,iad,ibg,ipr,iWc,ibc,iWd1,ibd1,iWd2,ibd2;
  int ig1,ibe1,im1,iv1,ig2,ibe2,im2,iv2,ig3,ibe3,im3,iv3;
  if(n_in >= 31 && in_sizes[5] == 128){
    iW1=3; ib1=4; ig1=5; ibe1=6; im1=7; iv1=8;
    iWl=9; iWr=10; ibs=11; ig2=12; ibe2=13; im2=14; iv2=15;
    iWg=16; ias=17; iad=18; ibg=19; ig3=20; ibe3=21; im3=22; iv3=23;
    ipr=24; iWc=25; ibc=26; iWd1=27; ibd1=28; iWd2=29; ibd2=30;
  }else{
    iW1=3; ib1=4; iWl=5; iWr=6; ibs=7; iWg=8; ias=9; iad=10; ibg=11;
    ipr=12; iWc=13; ibc=14; iWd1=15; ibd1=16; iWd2=17; ibd2=18;
    ig1=19; ibe1=20; im1=21; iv1=22; ig2=23; ibe2=24; im2=25; iv2=26;
    ig3=27; ibe3=28; im3=29; iv3=30;
  }
  const float* W1 = (const float*)d_in[iW1];   const float* b1 = (const float*)d_in[ib1];
  const float* Wl = (const float*)d_in[iWl];   const float* Wr = (const float*)d_in[iWr];
  const float* bs = (const float*)d_in[ibs];   const float* Wg = (const float*)d_in[iWg];
  const float* a_src = (const float*)d_in[ias]; const float* a_dst = (const float*)d_in[iad];
  const float* bg = (const float*)d_in[ibg];   const float* protos = (const float*)d_in[ipr];
  const float* Wc = (const float*)d_in[iWc];   const float* bc = (const float*)d_in[ibc];
  const float* Wd1 = (const float*)d_in[iWd1]; const float* bd1 = (const float*)d_in[ibd1];
  const float* Wd2 = (const float*)d_in[iWd2]; const float* bd2 = (const float*)d_in[ibd2];
  const float* g1 = (const float*)d_in[ig1];   const float* be1 = (const float*)d_in[ibe1];
  const float* m1 = (const float*)d_in[im1];   const float* v1 = (const float*)d_in[iv1];
  const float* g2 = (const float*)d_in[ig2];   const float* be2 = (const float*)d_in[ibe2];
  const float* m2 = (const float*)d_in[im2];   const float* v2 = (const float*)d_in[iv2];
  const float* g3 = (const float*)d_in[ig3];   const float* be3 = (const float*)d_in[ibe3];
  const float* m3 = (const float*)d_in[im3];   const float* v3 = (const float*)d_in[iv3];

  // ---- workspace: RA | RB | RC (bf16 NF each) | int cnt,row_ptr,tmp,esrc | float dinv,als,ald,pooled,gcnt ----
  const size_t NF = (size_t)N_*H_;
  const size_t intN = (size_t)N_ + (N_+1) + N_ + E_;
  const size_t fltN = (size_t)3*N_ + G_*H_ + G_;
  const size_t NEED = NF*2*3 + intN*4 + fltN*4;
  if(ws_size < NEED){
    k_sentinel<<<1,1,0,stream>>>((float*)d_out, 1000.f + (float)(ws_size>>20));
    return;
  }
  bf16* RA = (bf16*)d_ws;            // h -> h2 -> (dead)
  bf16* RB = RA + NF;                // h1 -> hgh (per head)
  bf16* RC = RB + NF;                // mean_nb -> h3 accumulator
  int*  cnt     = (int*)(RC + NF);
  int*  row_ptr = cnt + N_;
  int*  tmp     = row_ptr + (N_+1);
  int*  esrc    = tmp + N_;
  float* dinv   = (float*)(esrc + E_);
  float* als    = dinv + N_;
  float* ald    = als + N_;
  float* pooled = ald + N_;
  float* gcnt   = pooled + (size_t)G_*H_;

  // ---- CSR build ----
  hipMemsetAsync(cnt, 0, N_*sizeof(int), stream);
  k_count<<<(E_+255)/256, 256, 0, stream>>>(dst, cnt);
  k_scan<<<1, 1024, 0, stream>>>(cnt, row_ptr, tmp, dinv);
  k_scatter<<<(E_+255)/256, 256, 0, stream>>>(src, dst, tmp, esrc);

  const int GB = (N_+3)/4;   // gather blocks (4 nodes/block)
  // ---- GCN ----
  k_gemm_x_w1<<<(N_+63)/64, 256, 0, stream>>>(X, W1, RA);
  k_gcn_gather<<<GB, 256, 0, stream>>>(row_ptr, esrc, dinv, RA, b1, g1, be1, m1, v1, RB);
  // ---- SAGE ----
  k_sage_gather<<<GB, 256, 0, stream>>>(row_ptr, esrc, RB, RC);
  k_sage<<<(N_+63)/64, 256, 0, stream>>>(RC, RB, Wl, Wr, bs, g2, be2, m2, v2, RA);
  // ---- GAT (per head) ----
  for(int hh=0; hh<3; hh++){
    k_gat_gemm_h<<<(N_+63)/64, 256, 0, stream>>>(RA, Wg, hh, RB);
    k_al_h<<<(N_*64)/256, 256, 0, stream>>>(RB, a_src, a_dst, hh, als, ald);
    k_gat_gather<<<GB, 256, 0, stream>>>(row_ptr, esrc, als, ald, RB, hh, RC);
  }
  // ---- pool + heads ----
  hipMemsetAsync(pooled, 0, (size_t)(G_*H_+G_)*sizeof(float), stream);
  k_h3fin_pool<<<(N_*H_+255)/256, 256, 0, stream>>>(RC, bg, g3, be3, m3, v3, batch, pooled, gcnt);
  k_head<<<G_, 128, 0, stream>>>(pooled, gcnt, protos, Wc, bc, Wd1, bd1, Wd2, bd2, (float*)d_out);
}

// Round 10
// 1011.428 us; speedup vs baseline: 3.3983x; 1.3945x over previous
//
#include <hip/hip_runtime.h>
#include <hip/hip_bf16.h>
#include <stdint.h>
#include <stddef.h>

#define N_ 50000
#define E_ 600000
#define F_ 128
#define H_ 128
#define G_ 64
#define P_ 32
#define C_ 10

typedef __hip_bfloat16 bf16;

__device__ __forceinline__ float b2f(bf16 x){ return __bfloat162float(x); }
__device__ __forceinline__ float us2f(unsigned short u){ return __uint_as_float(((unsigned int)u)<<16); }
__device__ __forceinline__ unsigned short f2us(float x){ bf16 h = __float2bfloat16(x); return *(unsigned short*)&h; }
__device__ __forceinline__ float eluf(float x){ return x>0.f ? x : expm1f(x); }
__device__ __forceinline__ float bnf(float x,float m,float v,float g,float b){ return (x-m)*rsqrtf(v+1e-5f)*g+b; }
__device__ __forceinline__ float lrelu(float x){ return x>0.f ? x : 0.2f*x; }
__device__ __forceinline__ float expc(float x){ return __expf(fminf(x, 50.f)); }
__device__ __forceinline__ void atomAddF(float* a, float v){ unsafeAtomicAdd(a, v); }

union U8 { unsigned short s[8]; uint4 v; };

// ---------------- GEMM core: 64 rows x 128 cols per block, 256 threads ----------------
__device__ __forceinline__ void gemm_core(const float (*As)[132], const unsigned short (*Ws)[128],
                                          int cg, int rg, float acc[4][8]){
  for(int k=0;k<128;k++){
    uint4 wv = *(const uint4*)&Ws[k][cg*8];
    float w[8];
    w[0]=__uint_as_float(wv.x<<16); w[1]=__uint_as_float(wv.x&0xFFFF0000u);
    w[2]=__uint_as_float(wv.y<<16); w[3]=__uint_as_float(wv.y&0xFFFF0000u);
    w[4]=__uint_as_float(wv.z<<16); w[5]=__uint_as_float(wv.z&0xFFFF0000u);
    w[6]=__uint_as_float(wv.w<<16); w[7]=__uint_as_float(wv.w&0xFFFF0000u);
    float a0=As[rg*4+0][k], a1=As[rg*4+1][k], a2=As[rg*4+2][k], a3=As[rg*4+3][k];
    #pragma unroll
    for(int j=0;j<8;j++){
      acc[0][j]+=a0*w[j]; acc[1][j]+=a1*w[j]; acc[2][j]+=a2*w[j]; acc[3][j]+=a3*w[j];
    }
  }
}

__device__ __forceinline__ void stage_W128f(const float* W, unsigned short (*Ws)[128], int tid){
  unsigned short* d = &Ws[0][0];
  #pragma unroll
  for(int i=0;i<8;i++){
    int base = (tid + i*256)*8;
    float4 a = *(const float4*)(W + base);
    float4 b = *(const float4*)(W + base + 4);
    U8 u;
    u.s[0]=f2us(a.x); u.s[1]=f2us(a.y); u.s[2]=f2us(a.z); u.s[3]=f2us(a.w);
    u.s[4]=f2us(b.x); u.s[5]=f2us(b.y); u.s[6]=f2us(b.z); u.s[7]=f2us(b.w);
    *(uint4*)(d + base) = u.v;
  }
}

__device__ __forceinline__ void stage_A_bf16(const bf16* B, int row0, float (*As)[132], int tid){
  #pragma unroll
  for(int i=0;i<8;i++){
    int v = tid + i*256;
    int r = v>>5, c4 = (v&31)<<2;
    int gr = row0 + r;
    float4 f = make_float4(0.f,0.f,0.f,0.f);
    if(gr < N_){
      ushort4 u = *(const ushort4*)((const unsigned short*)B + (size_t)gr*H_ + c4);
      f.x=us2f(u.x); f.y=us2f(u.y); f.z=us2f(u.z); f.w=us2f(u.w);
    }
    *(float4*)&As[r][c4] = f;
  }
}

// hb(bf16) = X(f32) @ W1(f32)
__global__ __launch_bounds__(256) void k_gemm_x_w1(const float* __restrict__ X, const float* __restrict__ W,
                                                   bf16* __restrict__ HB){
  __shared__ __align__(16) float As[64][132];
  __shared__ __align__(16) unsigned short Ws[128][128];
  const int tid = threadIdx.x;
  const int row0 = blockIdx.x*64;
  stage_W128f(W, Ws, tid);
  #pragma unroll
  for(int i=0;i<8;i++){
    int v = tid + i*256;
    int r = v>>5, c4 = (v&31)<<2;
    int gr = row0 + r;
    float4 f = make_float4(0.f,0.f,0.f,0.f);
    if(gr < N_) f = *(const float4*)(X + (size_t)gr*F_ + c4);
    *(float4*)&As[r][c4] = f;
  }
  __syncthreads();
  const int cg = tid&15, rg = tid>>4;
  float acc[4][8];
  #pragma unroll
  for(int r=0;r<4;r++) for(int j=0;j<8;j++) acc[r][j]=0.f;
  gemm_core(As, Ws, cg, rg, acc);
  #pragma unroll
  for(int r=0;r<4;r++){
    int gr = row0 + rg*4 + r;
    if(gr < N_){
      U8 u;
      #pragma unroll
      for(int j=0;j<8;j++) u.s[j] = f2us(acc[r][j]);
      *(uint4*)((unsigned short*)HB + (size_t)gr*H_ + cg*8) = u.v;
    }
  }
}

// h2b(bf16) = elu(bn2( meanB@Wl + h1B@Wr + bs ))
__global__ __launch_bounds__(256) void k_sage(const bf16* __restrict__ MaB, const bf16* __restrict__ H1B,
    const float* __restrict__ Wl, const float* __restrict__ Wr,
    const float* __restrict__ bs, const float* __restrict__ g2, const float* __restrict__ be2,
    const float* __restrict__ m2, const float* __restrict__ v2, bf16* __restrict__ H2B){
  __shared__ __align__(16) float As[64][132];
  __shared__ __align__(16) unsigned short Ws[128][128];
  const int tid = threadIdx.x;
  const int row0 = blockIdx.x*64;
  const int cg = tid&15, rg = tid>>4;
  float acc[4][8];
  #pragma unroll
  for(int r=0;r<4;r++) for(int j=0;j<8;j++) acc[r][j]=0.f;

  stage_W128f(Wl, Ws, tid);
  stage_A_bf16(MaB, row0, As, tid);
  __syncthreads();
  gemm_core(As, Ws, cg, rg, acc);
  __syncthreads();
  stage_W128f(Wr, Ws, tid);
  stage_A_bf16(H1B, row0, As, tid);
  __syncthreads();
  gemm_core(As, Ws, cg, rg, acc);

  float bsv[8], gv[8], bev[8], mv[8], vv[8];
  #pragma unroll
  for(int j=0;j<8;j++){
    int c = cg*8+j;
    bsv[j]=bs[c]; gv[j]=g2[c]; bev[j]=be2[c]; mv[j]=m2[c]; vv[j]=v2[c];
  }
  #pragma unroll
  for(int r=0;r<4;r++){
    int gr = row0 + rg*4 + r;
    if(gr < N_){
      U8 u;
      #pragma unroll
      for(int j=0;j<8;j++){
        float x = acc[r][j] + bsv[j];
        u.s[j] = f2us(eluf(bnf(x, mv[j], vv[j], gv[j], bev[j])));
      }
      *(uint4*)((unsigned short*)H2B + (size_t)gr*H_ + cg*8) = u.v;
    }
  }
}

// hgh(bf16) = h2b @ Wg[:, hh*128:(hh+1)*128]
__global__ __launch_bounds__(256) void k_gat_gemm_h(const bf16* __restrict__ H2B, const float* __restrict__ Wg,
                                                    int hh, bf16* __restrict__ HGH){
  __shared__ __align__(16) float As[64][132];
  __shared__ __align__(16) unsigned short Ws[128][128];
  const int tid = threadIdx.x;
  const int row0 = blockIdx.x*64;
  const int cg = tid&15, rg = tid>>4;
  stage_A_bf16(H2B, row0, As, tid);
  #pragma unroll
  for(int i=0;i<8;i++){
    int v = tid + i*256;
    int k = v>>4, cs = v&15;
    const float* p = Wg + (size_t)k*384 + hh*128 + cs*8;
    float4 a = *(const float4*)p;
    float4 b = *(const float4*)(p+4);
    U8 u;
    u.s[0]=f2us(a.x); u.s[1]=f2us(a.y); u.s[2]=f2us(a.z); u.s[3]=f2us(a.w);
    u.s[4]=f2us(b.x); u.s[5]=f2us(b.y); u.s[6]=f2us(b.z); u.s[7]=f2us(b.w);
    *(uint4*)&Ws[k][cs*8] = u.v;
  }
  __syncthreads();
  float acc[4][8];
  #pragma unroll
  for(int r=0;r<4;r++) for(int j=0;j<8;j++) acc[r][j]=0.f;
  gemm_core(As, Ws, cg, rg, acc);
  #pragma unroll
  for(int r=0;r<4;r++){
    int gr = row0 + rg*4 + r;
    if(gr < N_){
      U8 u;
      #pragma unroll
      for(int j=0;j<8;j++) u.s[j] = f2us(acc[r][j]);
      *(uint4*)((unsigned short*)HGH + (size_t)gr*H_ + cg*8) = u.v;
    }
  }
}

// ---------------- CSR build ----------------
__global__ __launch_bounds__(256) void k_count(const int* __restrict__ dst, int* __restrict__ cnt){
  int e = blockIdx.x*256 + threadIdx.x;
  if(e < E_) atomicAdd(&cnt[dst[e]], 1);
}

// single-block exclusive scan (shuffle-based): row_ptr, tmp, dinv
__global__ __launch_bounds__(1024) void k_scan(const int* __restrict__ cnt, int* __restrict__ row_ptr,
                                               int* __restrict__ tmp, float* __restrict__ dinv){
  __shared__ int wsum[16];
  __shared__ int carry_s;
  const int t = threadIdx.x;
  const int lane = t & 63, wid = t >> 6;
  if(t==0) carry_s = 0;
  __syncthreads();
  for(int base=0; base<N_; base+=1024){
    int i = base + t;
    int v = (i<N_) ? cnt[i] : 0;
    int x = v;
    #pragma unroll
    for(int o=1;o<64;o<<=1){
      int y = __shfl_up(x, o, 64);
      if(lane >= o) x += y;
    }
    if(lane==63) wsum[wid] = x;
    __syncthreads();
    if(wid==0){
      int s = (lane<16) ? wsum[lane] : 0;
      #pragma unroll
      for(int o=1;o<16;o<<=1){
        int y = __shfl_up(s, o, 64);
        if(lane >= o) s += y;
      }
      if(lane<16) wsum[lane] = s;   // inclusive wave sums
    }
    __syncthreads();
    int waveoff = (wid>0) ? wsum[wid-1] : 0;
    int incl = carry_s + waveoff + x;
    int excl = incl - v;
    if(i<N_){
      row_ptr[i] = excl;
      tmp[i] = excl;
      dinv[i] = rsqrtf((float)v + 1.f);
    }
    __syncthreads();
    if(t==1023) carry_s = incl;
    __syncthreads();
  }
  if(t==0) row_ptr[N_] = carry_s;
}

__global__ __launch_bounds__(256) void k_scatter(const int* __restrict__ src, const int* __restrict__ dst,
                                                 int* __restrict__ tmp, int* __restrict__ esrc){
  int e = blockIdx.x*256 + threadIdx.x;
  if(e < E_){
    int d = dst[e];
    int pos = atomicAdd(&tmp[d], 1);
    esrc[pos] = src[e];
  }
}

// ---------------- CSR gather kernels (1 wave = 1 node, 2 feats/lane) ----------------
__global__ __launch_bounds__(256) void k_gcn_gather(const int* __restrict__ row_ptr, const int* __restrict__ esrc,
    const float* __restrict__ dinv, const bf16* __restrict__ HB,
    const float* __restrict__ b1, const float* __restrict__ g1, const float* __restrict__ be1,
    const float* __restrict__ m1, const float* __restrict__ v1, bf16* __restrict__ H1B){
  int n = blockIdx.x*4 + (threadIdx.x>>6);
  int lane = threadIdx.x & 63;
  if(n >= N_) return;
  int beg = row_ptr[n], end = row_ptr[n+1];
  float dn = dinv[n];
  float a0 = 0.f, a1 = 0.f;
  const unsigned short* hb = (const unsigned short*)HB;
  for(int e=beg; e<end; e++){
    int s = esrc[e];
    float c = dinv[s]*dn;
    unsigned int hv = *(const unsigned int*)(hb + (size_t)s*H_ + lane*2);
    a0 += c*us2f((unsigned short)(hv & 0xFFFFu));
    a1 += c*us2f((unsigned short)(hv >> 16));
  }
  unsigned int hv = *(const unsigned int*)(hb + (size_t)n*H_ + lane*2);
  int f0 = lane*2, f1 = f0+1;
  float x0 = a0 + us2f((unsigned short)(hv & 0xFFFFu))*dn*dn + b1[f0];
  float x1 = a1 + us2f((unsigned short)(hv >> 16))*dn*dn + b1[f1];
  x0 = eluf(bnf(x0, m1[f0], v1[f0], g1[f0], be1[f0]));
  x1 = eluf(bnf(x1, m1[f1], v1[f1], g1[f1], be1[f1]));
  unsigned int o = ((unsigned int)f2us(x1)<<16) | f2us(x0);
  *(unsigned int*)((unsigned short*)H1B + (size_t)n*H_ + lane*2) = o;
}

__global__ __launch_bounds__(256) void k_sage_gather(const int* __restrict__ row_ptr, const int* __restrict__ esrc,
    const bf16* __restrict__ H1B, bf16* __restrict__ MeanB){
  int n = blockIdx.x*4 + (threadIdx.x>>6);
  int lane = threadIdx.x & 63;
  if(n >= N_) return;
  int beg = row_ptr[n], end = row_ptr[n+1];
  float a0 = 0.f, a1 = 0.f;
  const unsigned short* hb = (const unsigned short*)H1B;
  for(int e=beg; e<end; e++){
    int s = esrc[e];
    unsigned int hv = *(const unsigned int*)(hb + (size_t)s*H_ + lane*2);
    a0 += us2f((unsigned short)(hv & 0xFFFFu));
    a1 += us2f((unsigned short)(hv >> 16));
  }
  float inv = 1.f / fmaxf((float)(end-beg), 1.f);
  unsigned int o = ((unsigned int)f2us(a1*inv)<<16) | f2us(a0*inv);
  *(unsigned int*)((unsigned short*)MeanB + (size_t)n*H_ + lane*2) = o;
}

// attention logits per node for head hh
__global__ __launch_bounds__(256) void k_al_h(const bf16* __restrict__ HGH, const float* __restrict__ a_src,
    const float* __restrict__ a_dst, int hh, float* __restrict__ als, float* __restrict__ ald){
  int n = (blockIdx.x*blockDim.x + threadIdx.x) >> 6;
  int lane = threadIdx.x & 63;
  if(n >= N_) return;
  unsigned int hv = *(const unsigned int*)((const unsigned short*)HGH + (size_t)n*H_ + lane*2);
  float h0 = us2f((unsigned short)(hv & 0xFFFFu));
  float h1v = us2f((unsigned short)(hv >> 16));
  float2 sv = *(const float2*)(a_src + hh*128 + lane*2);
  float2 dv = *(const float2*)(a_dst + hh*128 + lane*2);
  float ps = h0*sv.x + h1v*sv.y;
  float pd = h0*dv.x + h1v*dv.y;
  #pragma unroll
  for(int o=32;o>0;o>>=1){ ps += __shfl_down(ps,o,64); pd += __shfl_down(pd,o,64); }
  if(lane==0){ als[n]=ps; ald[n]=pd; }
}

// GAT gather for head hh: den pass + weighted-sum pass + self loop; head-mean into bf16 acc
__global__ __launch_bounds__(256) void k_gat_gather(const int* __restrict__ row_ptr, const int* __restrict__ esrc,
    const float* __restrict__ als, const float* __restrict__ ald, const bf16* __restrict__ HGH,
    int hh, bf16* __restrict__ ACCB){
  int n = blockIdx.x*4 + (threadIdx.x>>6);
  int lane = threadIdx.x & 63;
  if(n >= N_) return;
  int beg = row_ptr[n], end = row_ptr[n+1];
  float aldn = ald[n];
  float eself = expc(lrelu(als[n] + aldn));
  float den = eself;
  for(int e=beg; e<end; e++){
    den += expc(lrelu(als[esrc[e]] + aldn));
  }
  const unsigned short* hb = (const unsigned short*)HGH;
  unsigned int hv = *(const unsigned int*)(hb + (size_t)n*H_ + lane*2);
  float a0 = eself*us2f((unsigned short)(hv & 0xFFFFu));
  float a1 = eself*us2f((unsigned short)(hv >> 16));
  for(int e=beg; e<end; e++){
    int s = esrc[e];
    float w = expc(lrelu(als[s] + aldn));
    unsigned int sv = *(const unsigned int*)(hb + (size_t)s*H_ + lane*2);
    a0 += w*us2f((unsigned short)(sv & 0xFFFFu));
    a1 += w*us2f((unsigned short)(sv >> 16));
  }
  float inv = 1.f/(3.f*den);
  a0 *= inv; a1 *= inv;
  unsigned int* acc = (unsigned int*)((unsigned short*)ACCB + (size_t)n*H_ + lane*2);
  if(hh != 0){
    unsigned int old = *acc;
    a0 += us2f((unsigned short)(old & 0xFFFFu));
    a1 += us2f((unsigned short)(old >> 16));
  }
  *acc = ((unsigned int)f2us(a1)<<16) | f2us(a0);
}

// h3 finalize + pool: wave = 16-node span, register-accumulate per batch segment (batch is sorted)
#define NPW_ 16
__global__ __launch_bounds__(256) void k_h3fin_pool(const bf16* __restrict__ ACCB, const float* __restrict__ bg,
    const float* __restrict__ g3, const float* __restrict__ be3, const float* __restrict__ m3, const float* __restrict__ v3,
    const int* __restrict__ batch, float* __restrict__ pooled, float* __restrict__ gcnt){
  int wave = blockIdx.x*4 + (threadIdx.x>>6);
  int lane = threadIdx.x & 63;
  int n0 = wave*NPW_;
  if(n0 >= N_) return;
  int n1 = n0 + NPW_; if(n1 > N_) n1 = N_;
  int f0 = lane*2, f1 = f0+1;
  float bg0=bg[f0], bg1=bg[f1];
  float g30=g3[f0], g31=g3[f1], be30=be3[f0], be31=be3[f1];
  float m30=m3[f0], m31=m3[f1], v30=v3[f0], v31=v3[f1];
  float r0=0.f, r1=0.f;
  int cur = batch[n0];
  int seg = 0;
  for(int n=n0; n<n1; n++){
    int b = batch[n];
    if(b != cur){
      atomAddF(&pooled[cur*H_ + f0], r0);
      atomAddF(&pooled[cur*H_ + f1], r1);
      if(lane==0) atomAddF(&gcnt[cur], (float)seg);
      r0 = 0.f; r1 = 0.f; seg = 0; cur = b;
    }
    unsigned int hv = *(const unsigned int*)((const unsigned short*)ACCB + (size_t)n*H_ + lane*2);
    float x0 = us2f((unsigned short)(hv & 0xFFFFu)) + bg0;
    float x1 = us2f((unsigned short)(hv >> 16)) + bg1;
    r0 += eluf(bnf(x0, m30, v30, g30, be30));
    r1 += eluf(bnf(x1, m31, v31, g31, be31));
    seg++;
  }
  atomAddF(&pooled[cur*H_ + f0], r0);
  atomAddF(&pooled[cur*H_ + f1], r1);
  if(lane==0) atomAddF(&gcnt[cur], (float)seg);
}

// per-graph head — fp32 output
__global__ __launch_bounds__(128) void k_head(const float* __restrict__ pooledacc, const float* __restrict__ gcnt,
    const float* __restrict__ protos, const float* __restrict__ Wc, const float* __restrict__ bc,
    const float* __restrict__ Wd1, const float* __restrict__ bd1, const float* __restrict__ Wd2, const float* __restrict__ bd2,
    float* __restrict__ out){
  const int g = blockIdx.x, t = threadIdx.x;
  __shared__ float p[128], xn[128], red[128], sims[32], es[32], asg[32], pe[128], t1[256];
  __shared__ float nrm;
  float cg_ = fmaxf(gcnt[g], 1.f);
  p[t] = pooledacc[g*128 + t] / cg_;
  __syncthreads();
  red[t] = p[t]*p[t];
  __syncthreads();
  for(int s=64;s>0;s>>=1){ if(t<s) red[t]+=red[t+s]; __syncthreads(); }
  if(t==0) nrm = fmaxf(sqrtf(red[0]), 1e-8f);
  __syncthreads();
  xn[t] = p[t]/nrm;
  __syncthreads();
  if(t<32){
    float s=0.f, pn=0.f;
    for(int f=0;f<128;f++){ float pv=protos[t*128+f]; s += xn[f]*pv; pn += pv*pv; }
    sims[t] = s / fmaxf(sqrtf(pn), 1e-8f);
  }
  __syncthreads();
  if(t<32){
    float mx=-1e30f;
    for(int j=0;j<32;j++) mx = fmaxf(mx, sims[j]);
    es[t] = __expf(sims[t]-mx);
  }
  __syncthreads();
  if(t<32){
    float sm=0.f;
    for(int j=0;j<32;j++) sm += es[j];
    float a = es[t]/fmaxf(sm,1e-20f);
    asg[t] = a;
    out[8832 + g*32 + t] = a;               // assignments [G,P]
  }
  __syncthreads();
  {
    float s=0.f;
    for(int pp=0;pp<32;pp++) s += asg[pp]*protos[pp*128+t];
    pe[t] = s;
    out[640 + g*128 + t] = s;               // proto_emb [G,H]
  }
  __syncthreads();
  if(t<10){
    float s = bc[t];
    for(int f=0;f<128;f++) s += pe[f]*Wc[f*10+t];
    out[g*10 + t] = s;                      // logits [G,C]
  }
  for(int j=t;j<256;j+=128){
    float s = bd1[j];
    for(int f=0;f<128;f++) s += p[f]*Wd1[f*256+j];
    t1[j] = fmaxf(s, 0.f);
  }
  __syncthreads();
  {
    float s = bd2[t];
    for(int j=0;j<256;j++) s += t1[j]*Wd2[j*128+t];
    out[10880 + g*128 + t] = s;             // reconstructed [G,F]
  }
}

__global__ void k_sentinel(float* out, float code){
  out[0] = code;
}

extern "C" void kernel_launch(void* const* d_in, const int* in_sizes, int n_in,
                              void* d_out, int out_size, void* d_ws, size_t ws_size,
                              hipStream_t stream){
  const float* X    = (const float*)d_in[0];
  const int*  EI    = (const int*)d_in[1];
  const int*  batch = (const int*)d_in[2];
  const int* src = EI;
  const int* dst = EI + E_;

  int iW1,ib1,iWl,iWr,ibs,iWg,ias,iad,ibg,ipr,iWc,ibc,iWd1,ibd1,iWd2,ibd2;
  int ig1,ibe1,im1,iv1,ig2,ibe2,im2,iv2,ig3,ibe3,im3,iv3;
  if(n_in >= 31 && in_sizes[5] == 128){
    iW1=3; ib1=4; ig1=5; ibe1=6; im1=7; iv1=8;
    iWl=9; iWr=10; ibs=11; ig2=12; ibe2=13; im2=14; iv2=15;
    iWg=16; ias=17; iad=18; ibg=19; ig3=20; ibe3=21; im3=22; iv3=23;
    ipr=24; iWc=25; ibc=26; iWd1=27; ibd1=28; iWd2=29; ibd2=30;
  }else{
    iW1=3; ib1=4; iWl=5; iWr=6; ibs=7; iWg=8; ias=9; iad=10; ibg=11;
    ipr=12; iWc=13; ibc=14; iWd1=15; ibd1=16; iWd2=17; ibd2=18;
    ig1=19; ibe1=20; im1=21; iv1=22; ig2=23; ibe2=24; im2=25; iv2=26;
    ig3=27; ibe3=28; im3=29; iv3=30;
  }
  const float* W1 = (const float*)d_in[iW1];   const float* b1 = (const float*)d_in[ib1];
  const float* Wl = (const float*)d_in[iWl];   const float* Wr = (const float*)d_in[iWr];
  const float* bs = (const float*)d_in[ibs];   const float* Wg = (const float*)d_in[iWg];
  const float* a_src = (const float*)d_in[ias]; const float* a_dst = (const float*)d_in[iad];
  const float* bg = (const float*)d_in[ibg];   const float* protos = (const float*)d_in[ipr];
  const float* Wc = (const float*)d_in[iWc];   const float* bc = (const float*)d_in[ibc];
  const float* Wd1 = (const float*)d_in[iWd1]; const float* bd1 = (const float*)d_in[ibd1];
  const float* Wd2 = (const float*)d_in[iWd2]; const float* bd2 = (const float*)d_in[ibd2];
  const float* g1 = (const float*)d_in[ig1];   const float* be1 = (const float*)d_in[ibe1];
  const float* m1 = (const float*)d_in[im1];   const float* v1 = (const float*)d_in[iv1];
  const float* g2 = (const float*)d_in[ig2];   const float* be2 = (const float*)d_in[ibe2];
  const float* m2 = (const float*)d_in[im2];   const float* v2 = (const float*)d_in[iv2];
  const float* g3 = (const float*)d_in[ig3];   const float* be3 = (const float*)d_in[ibe3];
  const float* m3 = (const float*)d_in[im3];   const float* v3 = (const float*)d_in[iv3];

  const size_t NF = (size_t)N_*H_;
  const size_t intN = (size_t)N_ + (N_+1) + N_ + E_;
  const size_t fltN = (size_t)3*N_ + G_*H_ + G_;
  const size_t NEED = NF*2*3 + intN*4 + fltN*4;
  if(ws_size < NEED){
    k_sentinel<<<1,1,0,stream>>>((float*)d_out, 1000.f + (float)(ws_size>>20));
    return;
  }
  bf16* RA = (bf16*)d_ws;            // h -> h2
  bf16* RB = RA + NF;                // h1 -> hgh (per head)
  bf16* RC = RB + NF;                // mean_nb -> h3 accumulator
  int*  cnt     = (int*)(RC + NF);
  int*  row_ptr = cnt + N_;
  int*  tmp     = row_ptr + (N_+1);
  int*  esrc    = tmp + N_;
  float* dinv   = (float*)(esrc + E_);
  float* als    = dinv + N_;
  float* ald    = als + N_;
  float* pooled = ald + N_;
  float* gcnt   = pooled + (size_t)G_*H_;

  // ---- CSR build ----
  hipMemsetAsync(cnt, 0, N_*sizeof(int), stream);
  k_count<<<(E_+255)/256, 256, 0, stream>>>(dst, cnt);
  k_scan<<<1, 1024, 0, stream>>>(cnt, row_ptr, tmp, dinv);
  k_scatter<<<(E_+255)/256, 256, 0, stream>>>(src, dst, tmp, esrc);

  const int GB = (N_+3)/4;
  // ---- GCN ----
  k_gemm_x_w1<<<(N_+63)/64, 256, 0, stream>>>(X, W1, RA);
  k_gcn_gather<<<GB, 256, 0, stream>>>(row_ptr, esrc, dinv, RA, b1, g1, be1, m1, v1, RB);
  // ---- SAGE ----
  k_sage_gather<<<GB, 256, 0, stream>>>(row_ptr, esrc, RB, RC);
  k_sage<<<(N_+63)/64, 256, 0, stream>>>(RC, RB, Wl, Wr, bs, g2, be2, m2, v2, RA);
  // ---- GAT (per head) ----
  for(int hh=0; hh<3; hh++){
    k_gat_gemm_h<<<(N_+63)/64, 256, 0, stream>>>(RA, Wg, hh, RB);
    k_al_h<<<(N_*64)/256, 256, 0, stream>>>(RB, a_src, a_dst, hh, als, ald);
    k_gat_gather<<<GB, 256, 0, stream>>>(row_ptr, esrc, als, ald, RB, hh, RC);
  }
  // ---- pool + heads ----
  hipMemsetAsync(pooled, 0, (size_t)(G_*H_+G_)*sizeof(float), stream);
  {
    int waves = (N_ + NPW_ - 1)/NPW_;
    int blocks = (waves + 3)/4;
    k_h3fin_pool<<<blocks, 256, 0, stream>>>(RC, bg, g3, be3, m3, v3, batch, pooled, gcnt);
  }
  k_head<<<G_, 128, 0, stream>>>(pooled, gcnt, protos, Wc, bc, Wd1, bd1, Wd2, bd2, (float*)d_out);
}

// Round 11
// 731.703 us; speedup vs baseline: 4.6975x; 1.3823x over previous
//
#include <hip/hip_runtime.h>
#include <hip/hip_bf16.h>
#include <stdint.h>
#include <stddef.h>

#define N_ 50000
#define E_ 600000
#define F_ 128
#define H_ 128
#define G_ 64
#define P_ 32
#define C_ 10

typedef __hip_bfloat16 bf16;

__device__ __forceinline__ float b2f(bf16 x){ return __bfloat162float(x); }
__device__ __forceinline__ float us2f(unsigned short u){ return __uint_as_float(((unsigned int)u)<<16); }
__device__ __forceinline__ unsigned short f2us(float x){ bf16 h = __float2bfloat16(x); return *(unsigned short*)&h; }
__device__ __forceinline__ float eluf(float x){ return x>0.f ? x : expm1f(x); }
__device__ __forceinline__ float bnf(float x,float m,float v,float g,float b){ return (x-m)*rsqrtf(v+1e-5f)*g+b; }
__device__ __forceinline__ float lrelu(float x){ return x>0.f ? x : 0.2f*x; }
__device__ __forceinline__ float expc(float x){ return __expf(fminf(x, 50.f)); }
__device__ __forceinline__ void atomAddF(float* a, float v){ unsafeAtomicAdd(a, v); }

union U8 { unsigned short s[8]; uint4 v; };

// ---------------- GEMM core: 64 rows x 128 cols per block, 256 threads ----------------
__device__ __forceinline__ void gemm_core(const float (*As)[132], const unsigned short (*Ws)[128],
                                          int cg, int rg, float acc[4][8]){
  for(int k=0;k<128;k++){
    uint4 wv = *(const uint4*)&Ws[k][cg*8];
    float w[8];
    w[0]=__uint_as_float(wv.x<<16); w[1]=__uint_as_float(wv.x&0xFFFF0000u);
    w[2]=__uint_as_float(wv.y<<16); w[3]=__uint_as_float(wv.y&0xFFFF0000u);
    w[4]=__uint_as_float(wv.z<<16); w[5]=__uint_as_float(wv.z&0xFFFF0000u);
    w[6]=__uint_as_float(wv.w<<16); w[7]=__uint_as_float(wv.w&0xFFFF0000u);
    float a0=As[rg*4+0][k], a1=As[rg*4+1][k], a2=As[rg*4+2][k], a3=As[rg*4+3][k];
    #pragma unroll
    for(int j=0;j<8;j++){
      acc[0][j]+=a0*w[j]; acc[1][j]+=a1*w[j]; acc[2][j]+=a2*w[j]; acc[3][j]+=a3*w[j];
    }
  }
}

__device__ __forceinline__ void stage_W128f(const float* W, unsigned short (*Ws)[128], int tid){
  unsigned short* d = &Ws[0][0];
  #pragma unroll
  for(int i=0;i<8;i++){
    int base = (tid + i*256)*8;
    float4 a = *(const float4*)(W + base);
    float4 b = *(const float4*)(W + base + 4);
    U8 u;
    u.s[0]=f2us(a.x); u.s[1]=f2us(a.y); u.s[2]=f2us(a.z); u.s[3]=f2us(a.w);
    u.s[4]=f2us(b.x); u.s[5]=f2us(b.y); u.s[6]=f2us(b.z); u.s[7]=f2us(b.w);
    *(uint4*)(d + base) = u.v;
  }
}

__device__ __forceinline__ void stage_A_bf16(const bf16* B, int row0, float (*As)[132], int tid){
  #pragma unroll
  for(int i=0;i<8;i++){
    int v = tid + i*256;
    int r = v>>5, c4 = (v&31)<<2;
    int gr = row0 + r;
    float4 f = make_float4(0.f,0.f,0.f,0.f);
    if(gr < N_){
      ushort4 u = *(const ushort4*)((const unsigned short*)B + (size_t)gr*H_ + c4);
      f.x=us2f(u.x); f.y=us2f(u.y); f.z=us2f(u.z); f.w=us2f(u.w);
    }
    *(float4*)&As[r][c4] = f;
  }
}

// hb(bf16) = X(f32) @ W1(f32)
__global__ __launch_bounds__(256) void k_gemm_x_w1(const float* __restrict__ X, const float* __restrict__ W,
                                                   bf16* __restrict__ HB){
  __shared__ __align__(16) float As[64][132];
  __shared__ __align__(16) unsigned short Ws[128][128];
  const int tid = threadIdx.x;
  const int row0 = blockIdx.x*64;
  stage_W128f(W, Ws, tid);
  #pragma unroll
  for(int i=0;i<8;i++){
    int v = tid + i*256;
    int r = v>>5, c4 = (v&31)<<2;
    int gr = row0 + r;
    float4 f = make_float4(0.f,0.f,0.f,0.f);
    if(gr < N_) f = *(const float4*)(X + (size_t)gr*F_ + c4);
    *(float4*)&As[r][c4] = f;
  }
  __syncthreads();
  const int cg = tid&15, rg = tid>>4;
  float acc[4][8];
  #pragma unroll
  for(int r=0;r<4;r++) for(int j=0;j<8;j++) acc[r][j]=0.f;
  gemm_core(As, Ws, cg, rg, acc);
  #pragma unroll
  for(int r=0;r<4;r++){
    int gr = row0 + rg*4 + r;
    if(gr < N_){
      U8 u;
      #pragma unroll
      for(int j=0;j<8;j++) u.s[j] = f2us(acc[r][j]);
      *(uint4*)((unsigned short*)HB + (size_t)gr*H_ + cg*8) = u.v;
    }
  }
}

// h2b(bf16) = elu(bn2( meanB@Wl + h1B@Wr + bs ))
__global__ __launch_bounds__(256) void k_sage(const bf16* __restrict__ MaB, const bf16* __restrict__ H1B,
    const float* __restrict__ Wl, const float* __restrict__ Wr,
    const float* __restrict__ bs, const float* __restrict__ g2, const float* __restrict__ be2,
    const float* __restrict__ m2, const float* __restrict__ v2, bf16* __restrict__ H2B){
  __shared__ __align__(16) float As[64][132];
  __shared__ __align__(16) unsigned short Ws[128][128];
  const int tid = threadIdx.x;
  const int row0 = blockIdx.x*64;
  const int cg = tid&15, rg = tid>>4;
  float acc[4][8];
  #pragma unroll
  for(int r=0;r<4;r++) for(int j=0;j<8;j++) acc[r][j]=0.f;

  stage_W128f(Wl, Ws, tid);
  stage_A_bf16(MaB, row0, As, tid);
  __syncthreads();
  gemm_core(As, Ws, cg, rg, acc);
  __syncthreads();
  stage_W128f(Wr, Ws, tid);
  stage_A_bf16(H1B, row0, As, tid);
  __syncthreads();
  gemm_core(As, Ws, cg, rg, acc);

  float bsv[8], gv[8], bev[8], mv[8], vv[8];
  #pragma unroll
  for(int j=0;j<8;j++){
    int c = cg*8+j;
    bsv[j]=bs[c]; gv[j]=g2[c]; bev[j]=be2[c]; mv[j]=m2[c]; vv[j]=v2[c];
  }
  #pragma unroll
  for(int r=0;r<4;r++){
    int gr = row0 + rg*4 + r;
    if(gr < N_){
      U8 u;
      #pragma unroll
      for(int j=0;j<8;j++){
        float x = acc[r][j] + bsv[j];
        u.s[j] = f2us(eluf(bnf(x, mv[j], vv[j], gv[j], bev[j])));
      }
      *(uint4*)((unsigned short*)H2B + (size_t)gr*H_ + cg*8) = u.v;
    }
  }
}

// hgh(bf16) = h2b @ Wg[:, hh*128:(hh+1)*128]; fused attention-logit epilogue -> als, ald
__global__ __launch_bounds__(256) void k_gat_gemm_h(const bf16* __restrict__ H2B, const float* __restrict__ Wg,
                                                    const float* __restrict__ a_src, const float* __restrict__ a_dst,
                                                    int hh, bf16* __restrict__ HGH,
                                                    float* __restrict__ als, float* __restrict__ ald){
  __shared__ __align__(16) float As[64][132];
  __shared__ __align__(16) unsigned short Ws[128][128];
  const int tid = threadIdx.x;
  const int row0 = blockIdx.x*64;
  const int cg = tid&15, rg = tid>>4;
  stage_A_bf16(H2B, row0, As, tid);
  #pragma unroll
  for(int i=0;i<8;i++){
    int v = tid + i*256;
    int k = v>>4, cs = v&15;
    const float* p = Wg + (size_t)k*384 + hh*128 + cs*8;
    float4 a = *(const float4*)p;
    float4 b = *(const float4*)(p+4);
    U8 u;
    u.s[0]=f2us(a.x); u.s[1]=f2us(a.y); u.s[2]=f2us(a.z); u.s[3]=f2us(a.w);
    u.s[4]=f2us(b.x); u.s[5]=f2us(b.y); u.s[6]=f2us(b.z); u.s[7]=f2us(b.w);
    *(uint4*)&Ws[k][cs*8] = u.v;
  }
  __syncthreads();
  float acc[4][8];
  #pragma unroll
  for(int r=0;r<4;r++) for(int j=0;j<8;j++) acc[r][j]=0.f;
  gemm_core(As, Ws, cg, rg, acc);

  // attention-logit partials: this thread's 8 columns of each of its 4 rows
  float asv[8], adv[8];
  #pragma unroll
  for(int j=0;j<8;j++){
    asv[j] = a_src[hh*128 + cg*8 + j];
    adv[j] = a_dst[hh*128 + cg*8 + j];
  }
  #pragma unroll
  for(int r=0;r<4;r++){
    int gr = row0 + rg*4 + r;
    float ps = 0.f, pd = 0.f;
    #pragma unroll
    for(int j=0;j<8;j++){ ps += acc[r][j]*asv[j]; pd += acc[r][j]*adv[j]; }
    // reduce across the 16 column-group lanes (contiguous within the wave)
    #pragma unroll
    for(int o=8;o>0;o>>=1){ ps += __shfl_down(ps,o,16); pd += __shfl_down(pd,o,16); }
    if(gr < N_){
      U8 u;
      #pragma unroll
      for(int j=0;j<8;j++) u.s[j] = f2us(acc[r][j]);
      *(uint4*)((unsigned short*)HGH + (size_t)gr*H_ + cg*8) = u.v;
      if(cg == 0){ als[gr] = ps; ald[gr] = pd; }
    }
  }
}

// ---------------- CSR build ----------------
__global__ __launch_bounds__(256) void k_count(const int* __restrict__ dst, int* __restrict__ cnt){
  int e = blockIdx.x*256 + threadIdx.x;
  if(e < E_) atomicAdd(&cnt[dst[e]], 1);
}

__global__ __launch_bounds__(1024) void k_scan(const int* __restrict__ cnt, int* __restrict__ row_ptr,
                                               int* __restrict__ tmp, float* __restrict__ dinv){
  __shared__ int wsum[16];
  __shared__ int carry_s;
  const int t = threadIdx.x;
  const int lane = t & 63, wid = t >> 6;
  if(t==0) carry_s = 0;
  __syncthreads();
  for(int base=0; base<N_; base+=1024){
    int i = base + t;
    int v = (i<N_) ? cnt[i] : 0;
    int x = v;
    #pragma unroll
    for(int o=1;o<64;o<<=1){
      int y = __shfl_up(x, o, 64);
      if(lane >= o) x += y;
    }
    if(lane==63) wsum[wid] = x;
    __syncthreads();
    if(wid==0){
      int s = (lane<16) ? wsum[lane] : 0;
      #pragma unroll
      for(int o=1;o<16;o<<=1){
        int y = __shfl_up(s, o, 64);
        if(lane >= o) s += y;
      }
      if(lane<16) wsum[lane] = s;
    }
    __syncthreads();
    int waveoff = (wid>0) ? wsum[wid-1] : 0;
    int incl = carry_s + waveoff + x;
    int excl = incl - v;
    if(i<N_){
      row_ptr[i] = excl;
      tmp[i] = excl;
      dinv[i] = rsqrtf((float)v + 1.f);
    }
    __syncthreads();
    if(t==1023) carry_s = incl;
    __syncthreads();
  }
  if(t==0) row_ptr[N_] = carry_s;
}

__global__ __launch_bounds__(256) void k_scatter(const int* __restrict__ src, const int* __restrict__ dst,
                                                 int* __restrict__ tmp, int* __restrict__ esrc){
  int e = blockIdx.x*256 + threadIdx.x;
  if(e < E_){
    int d = dst[e];
    int pos = atomicAdd(&tmp[d], 1);
    esrc[pos] = src[e];
  }
}

// ---------------- CSR gather kernels (1 wave = 1 node, 2 feats/lane) ----------------
__global__ __launch_bounds__(256) void k_gcn_gather(const int* __restrict__ row_ptr, const int* __restrict__ esrc,
    const float* __restrict__ dinv, const bf16* __restrict__ HB,
    const float* __restrict__ b1, const float* __restrict__ g1, const float* __restrict__ be1,
    const float* __restrict__ m1, const float* __restrict__ v1, bf16* __restrict__ H1B){
  int n = blockIdx.x*4 + (threadIdx.x>>6);
  int lane = threadIdx.x & 63;
  if(n >= N_) return;
  int beg = row_ptr[n], end = row_ptr[n+1];
  float dn = dinv[n];
  float a0 = 0.f, a1 = 0.f;
  const unsigned short* hb = (const unsigned short*)HB;
  int e = beg;
  for(; e+1 < end; e += 2){
    int s0 = esrc[e], s1 = esrc[e+1];
    unsigned int hv0 = *(const unsigned int*)(hb + (size_t)s0*H_ + lane*2);
    unsigned int hv1 = *(const unsigned int*)(hb + (size_t)s1*H_ + lane*2);
    float c0 = dinv[s0]*dn, c1 = dinv[s1]*dn;
    a0 += c0*us2f((unsigned short)(hv0 & 0xFFFFu)) + c1*us2f((unsigned short)(hv1 & 0xFFFFu));
    a1 += c0*us2f((unsigned short)(hv0 >> 16))     + c1*us2f((unsigned short)(hv1 >> 16));
  }
  if(e < end){
    int s = esrc[e];
    float c = dinv[s]*dn;
    unsigned int hv = *(const unsigned int*)(hb + (size_t)s*H_ + lane*2);
    a0 += c*us2f((unsigned short)(hv & 0xFFFFu));
    a1 += c*us2f((unsigned short)(hv >> 16));
  }
  unsigned int hv = *(const unsigned int*)(hb + (size_t)n*H_ + lane*2);
  int f0 = lane*2, f1 = f0+1;
  float x0 = a0 + us2f((unsigned short)(hv & 0xFFFFu))*dn*dn + b1[f0];
  float x1 = a1 + us2f((unsigned short)(hv >> 16))*dn*dn + b1[f1];
  x0 = eluf(bnf(x0, m1[f0], v1[f0], g1[f0], be1[f0]));
  x1 = eluf(bnf(x1, m1[f1], v1[f1], g1[f1], be1[f1]));
  unsigned int o = ((unsigned int)f2us(x1)<<16) | f2us(x0);
  *(unsigned int*)((unsigned short*)H1B + (size_t)n*H_ + lane*2) = o;
}

__global__ __launch_bounds__(256) void k_sage_gather(const int* __restrict__ row_ptr, const int* __restrict__ esrc,
    const bf16* __restrict__ H1B, bf16* __restrict__ MeanB){
  int n = blockIdx.x*4 + (threadIdx.x>>6);
  int lane = threadIdx.x & 63;
  if(n >= N_) return;
  int beg = row_ptr[n], end = row_ptr[n+1];
  float a0 = 0.f, a1 = 0.f;
  const unsigned short* hb = (const unsigned short*)H1B;
  int e = beg;
  for(; e+1 < end; e += 2){
    int s0 = esrc[e], s1 = esrc[e+1];
    unsigned int hv0 = *(const unsigned int*)(hb + (size_t)s0*H_ + lane*2);
    unsigned int hv1 = *(const unsigned int*)(hb + (size_t)s1*H_ + lane*2);
    a0 += us2f((unsigned short)(hv0 & 0xFFFFu)) + us2f((unsigned short)(hv1 & 0xFFFFu));
    a1 += us2f((unsigned short)(hv0 >> 16))     + us2f((unsigned short)(hv1 >> 16));
  }
  if(e < end){
    unsigned int hv = *(const unsigned int*)(hb + (size_t)esrc[e]*H_ + lane*2);
    a0 += us2f((unsigned short)(hv & 0xFFFFu));
    a1 += us2f((unsigned short)(hv >> 16));
  }
  float inv = 1.f / fmaxf((float)(end-beg), 1.f);
  unsigned int o = ((unsigned int)f2us(a1*inv)<<16) | f2us(a0*inv);
  *(unsigned int*)((unsigned short*)MeanB + (size_t)n*H_ + lane*2) = o;
}

// GAT gather, single pass: unnormalized sum + den together, divide at end; head-mean into bf16 acc
__global__ __launch_bounds__(256) void k_gat_gather(const int* __restrict__ row_ptr, const int* __restrict__ esrc,
    const float* __restrict__ als, const float* __restrict__ ald, const bf16* __restrict__ HGH,
    int hh, bf16* __restrict__ ACCB){
  int n = blockIdx.x*4 + (threadIdx.x>>6);
  int lane = threadIdx.x & 63;
  if(n >= N_) return;
  int beg = row_ptr[n], end = row_ptr[n+1];
  float aldn = ald[n];
  float eself = expc(lrelu(als[n] + aldn));
  const unsigned short* hb = (const unsigned short*)HGH;
  unsigned int hv = *(const unsigned int*)(hb + (size_t)n*H_ + lane*2);
  float den = eself;
  float a0 = eself*us2f((unsigned short)(hv & 0xFFFFu));
  float a1 = eself*us2f((unsigned short)(hv >> 16));
  int e = beg;
  for(; e+1 < end; e += 2){
    int s0 = esrc[e], s1 = esrc[e+1];
    unsigned int sv0 = *(const unsigned int*)(hb + (size_t)s0*H_ + lane*2);
    unsigned int sv1 = *(const unsigned int*)(hb + (size_t)s1*H_ + lane*2);
    float w0 = expc(lrelu(als[s0] + aldn));
    float w1 = expc(lrelu(als[s1] + aldn));
    den += w0 + w1;
    a0 += w0*us2f((unsigned short)(sv0 & 0xFFFFu)) + w1*us2f((unsigned short)(sv1 & 0xFFFFu));
    a1 += w0*us2f((unsigned short)(sv0 >> 16))     + w1*us2f((unsigned short)(sv1 >> 16));
  }
  if(e < end){
    int s = esrc[e];
    float w = expc(lrelu(als[s] + aldn));
    unsigned int sv = *(const unsigned int*)(hb + (size_t)s*H_ + lane*2);
    den += w;
    a0 += w*us2f((unsigned short)(sv & 0xFFFFu));
    a1 += w*us2f((unsigned short)(sv >> 16));
  }
  float inv = 1.f/(3.f*den);
  a0 *= inv; a1 *= inv;
  unsigned int* acc = (unsigned int*)((unsigned short*)ACCB + (size_t)n*H_ + lane*2);
  if(hh != 0){
    unsigned int old = *acc;
    a0 += us2f((unsigned short)(old & 0xFFFFu));
    a1 += us2f((unsigned short)(old >> 16));
  }
  *acc = ((unsigned int)f2us(a1)<<16) | f2us(a0);
}

// h3 finalize + pool: wave = 16-node span, register-accumulate per batch segment (batch sorted)
#define NPW_ 16
__global__ __launch_bounds__(256) void k_h3fin_pool(const bf16* __restrict__ ACCB, const float* __restrict__ bg,
    const float* __restrict__ g3, const float* __restrict__ be3, const float* __restrict__ m3, const float* __restrict__ v3,
    const int* __restrict__ batch, float* __restrict__ pooled, float* __restrict__ gcnt){
  int wave = blockIdx.x*4 + (threadIdx.x>>6);
  int lane = threadIdx.x & 63;
  int n0 = wave*NPW_;
  if(n0 >= N_) return;
  int n1 = n0 + NPW_; if(n1 > N_) n1 = N_;
  int f0 = lane*2, f1 = f0+1;
  float bg0=bg[f0], bg1=bg[f1];
  float g30=g3[f0], g31=g3[f1], be30=be3[f0], be31=be3[f1];
  float m30=m3[f0], m31=m3[f1], v30=v3[f0], v31=v3[f1];
  float r0=0.f, r1=0.f;
  int cur = batch[n0];
  int seg = 0;
  for(int n=n0; n<n1; n++){
    int b = batch[n];
    if(b != cur){
      atomAddF(&pooled[cur*H_ + f0], r0);
      atomAddF(&pooled[cur*H_ + f1], r1);
      if(lane==0) atomAddF(&gcnt[cur], (float)seg);
      r0 = 0.f; r1 = 0.f; seg = 0; cur = b;
    }
    unsigned int hv = *(const unsigned int*)((const unsigned short*)ACCB + (size_t)n*H_ + lane*2);
    float x0 = us2f((unsigned short)(hv & 0xFFFFu)) + bg0;
    float x1 = us2f((unsigned short)(hv >> 16)) + bg1;
    r0 += eluf(bnf(x0, m30, v30, g30, be30));
    r1 += eluf(bnf(x1, m31, v31, g31, be31));
    seg++;
  }
  atomAddF(&pooled[cur*H_ + f0], r0);
  atomAddF(&pooled[cur*H_ + f1], r1);
  if(lane==0) atomAddF(&gcnt[cur], (float)seg);
}

// per-graph head — fp32 output
__global__ __launch_bounds__(128) void k_head(const float* __restrict__ pooledacc, const float* __restrict__ gcnt,
    const float* __restrict__ protos, const float* __restrict__ Wc, const float* __restrict__ bc,
    const float* __restrict__ Wd1, const float* __restrict__ bd1, const float* __restrict__ Wd2, const float* __restrict__ bd2,
    float* __restrict__ out){
  const int g = blockIdx.x, t = threadIdx.x;
  __shared__ float p[128], xn[128], red[128], sims[32], es[32], asg[32], pe[128], t1[256];
  __shared__ float nrm;
  float cg_ = fmaxf(gcnt[g], 1.f);
  p[t] = pooledacc[g*128 + t] / cg_;
  __syncthreads();
  red[t] = p[t]*p[t];
  __syncthreads();
  for(int s=64;s>0;s>>=1){ if(t<s) red[t]+=red[t+s]; __syncthreads(); }
  if(t==0) nrm = fmaxf(sqrtf(red[0]), 1e-8f);
  __syncthreads();
  xn[t] = p[t]/nrm;
  __syncthreads();
  if(t<32){
    float s=0.f, pn=0.f;
    for(int f=0;f<128;f++){ float pv=protos[t*128+f]; s += xn[f]*pv; pn += pv*pv; }
    sims[t] = s / fmaxf(sqrtf(pn), 1e-8f);
  }
  __syncthreads();
  if(t<32){
    float mx=-1e30f;
    for(int j=0;j<32;j++) mx = fmaxf(mx, sims[j]);
    es[t] = __expf(sims[t]-mx);
  }
  __syncthreads();
  if(t<32){
    float sm=0.f;
    for(int j=0;j<32;j++) sm += es[j];
    float a = es[t]/fmaxf(sm,1e-20f);
    asg[t] = a;
    out[8832 + g*32 + t] = a;               // assignments [G,P]
  }
  __syncthreads();
  {
    float s=0.f;
    for(int pp=0;pp<32;pp++) s += asg[pp]*protos[pp*128+t];
    pe[t] = s;
    out[640 + g*128 + t] = s;               // proto_emb [G,H]
  }
  __syncthreads();
  if(t<10){
    float s = bc[t];
    for(int f=0;f<128;f++) s += pe[f]*Wc[f*10+t];
    out[g*10 + t] = s;                      // logits [G,C]
  }
  for(int j=t;j<256;j+=128){
    float s = bd1[j];
    for(int f=0;f<128;f++) s += p[f]*Wd1[f*256+j];
    t1[j] = fmaxf(s, 0.f);
  }
  __syncthreads();
  {
    float s = bd2[t];
    for(int j=0;j<256;j++) s += t1[j]*Wd2[j*128+t];
    out[10880 + g*128 + t] = s;             // reconstructed [G,F]
  }
}

__global__ void k_sentinel(float* out, float code){
  out[0] = code;
}

extern "C" void kernel_launch(void* const* d_in, const int* in_sizes, int n_in,
                              void* d_out, int out_size, void* d_ws, size_t ws_size,
                              hipStream_t stream){
  const float* X    = (const float*)d_in[0];
  const int*  EI    = (const int*)d_in[1];
  const int*  batch = (const int*)d_in[2];
  const int* src = EI;
  const int* dst = EI + E_;

  int iW1,ib1,iWl,iWr,ibs,iWg,ias,iad,ibg,ipr,iWc,ibc,iWd1,ibd1,iWd2,ibd2;
  int ig1,ibe1,im1,iv1,ig2,ibe2,im2,iv2,ig3,ibe3,im3,iv3;
  if(n_in >= 31 && in_sizes[5] == 128){
    iW1=3; ib1=4; ig1=5; ibe1=6; im1=7; iv1=8;
    iWl=9; iWr=10; ibs=11; ig2=12; ibe2=13; im2=14; iv2=15;
    iWg=16; ias=17; iad=18; ibg=19; ig3=20; ibe3=21; im3=22; iv3=23;
    ipr=24; iWc=25; ibc=26; iWd1=27; ibd1=28; iWd2=29; ibd2=30;
  }else{
    iW1=3; ib1=4; iWl=5; iWr=6; ibs=7; iWg=8; ias=9; iad=10; ibg=11;
    ipr=12; iWc=13; ibc=14; iWd1=15; ibd1=16; iWd2=17; ibd2=18;
    ig1=19; ibe1=20; im1=21; iv1=22; ig2=23; ibe2=24; im2=25; iv2=26;
    ig3=27; ibe3=28; im3=29; iv3=30;
  }
  const float* W1 = (const float*)d_in[iW1];   const float* b1 = (const float*)d_in[ib1];
  const float* Wl = (const float*)d_in[iWl];   const float* Wr = (const float*)d_in[iWr];
  const float* bs = (const float*)d_in[ibs];   const float* Wg = (const float*)d_in[iWg];
  const float* a_src = (const float*)d_in[ias]; const float* a_dst = (const float*)d_in[iad];
  const float* bg = (const float*)d_in[ibg];   const float* protos = (const float*)d_in[ipr];
  const float* Wc = (const float*)d_in[iWc];   const float* bc = (const float*)d_in[ibc];
  const float* Wd1 = (const float*)d_in[iWd1]; const float* bd1 = (const float*)d_in[ibd1];
  const float* Wd2 = (const float*)d_in[iWd2]; const float* bd2 = (const float*)d_in[ibd2];
  const float* g1 = (const float*)d_in[ig1];   const float* be1 = (const float*)d_in[ibe1];
  const float* m1 = (const float*)d_in[im1];   const float* v1 = (const float*)d_in[iv1];
  const float* g2 = (const float*)d_in[ig2];   const float* be2 = (const float*)d_in[ibe2];
  const float* m2 = (const float*)d_in[im2];   const float* v2 = (const float*)d_in[iv2];
  const float* g3 = (const float*)d_in[ig3];   const float* be3 = (const float*)d_in[ibe3];
  const float* m3 = (const float*)d_in[im3];   const float* v3 = (const float*)d_in[iv3];

  const size_t NF = (size_t)N_*H_;
  const size_t intN = (size_t)N_ + (N_+1) + N_ + E_;
  const size_t fltN = (size_t)3*N_ + G_*H_ + G_;
  const size_t NEED = NF*2*3 + intN*4 + fltN*4;
  if(ws_size < NEED){
    k_sentinel<<<1,1,0,stream>>>((float*)d_out, 1000.f + (float)(ws_size>>20));
    return;
  }
  bf16* RA = (bf16*)d_ws;            // h -> h2
  bf16* RB = RA + NF;                // h1 -> hgh (per head)
  bf16* RC = RB + NF;                // mean_nb -> h3 accumulator
  int*  cnt     = (int*)(RC + NF);
  int*  row_ptr = cnt + N_;
  int*  tmp     = row_ptr + (N_+1);
  int*  esrc    = tmp + N_;
  float* dinv   = (float*)(esrc + E_);
  float* als    = dinv + N_;
  float* ald    = als + N_;
  float* pooled = ald + N_;
  float* gcnt   = pooled + (size_t)G_*H_;

  // ---- CSR build ----
  hipMemsetAsync(cnt, 0, N_*sizeof(int), stream);
  k_count<<<(E_+255)/256, 256, 0, stream>>>(dst, cnt);
  k_scan<<<1, 1024, 0, stream>>>(cnt, row_ptr, tmp, dinv);
  k_scatter<<<(E_+255)/256, 256, 0, stream>>>(src, dst, tmp, esrc);

  const int GB = (N_+3)/4;
  // ---- GCN ----
  k_gemm_x_w1<<<(N_+63)/64, 256, 0, stream>>>(X, W1, RA);
  k_gcn_gather<<<GB, 256, 0, stream>>>(row_ptr, esrc, dinv, RA, b1, g1, be1, m1, v1, RB);
  // ---- SAGE ----
  k_sage_gather<<<GB, 256, 0, stream>>>(row_ptr, esrc, RB, RC);
  k_sage<<<(N_+63)/64, 256, 0, stream>>>(RC, RB, Wl, Wr, bs, g2, be2, m2, v2, RA);
  // ---- GAT (per head) ----
  for(int hh=0; hh<3; hh++){
    k_gat_gemm_h<<<(N_+63)/64, 256, 0, stream>>>(RA, Wg, a_src, a_dst, hh, RB, als, ald);
    k_gat_gather<<<GB, 256, 0, stream>>>(row_ptr, esrc, als, ald, RB, hh, RC);
  }
  // ---- pool + heads ----
  hipMemsetAsync(pooled, 0, (size_t)(G_*H_+G_)*sizeof(float), stream);
  {
    int waves = (N_ + NPW_ - 1)/NPW_;
    int blocks = (waves + 3)/4;
    k_h3fin_pool<<<blocks, 256, 0, stream>>>(RC, bg, g3, be3, m3, v3, batch, pooled, gcnt);
  }
  k_head<<<G_, 128, 0, stream>>>(pooled, gcnt, protos, Wc, bc, Wd1, bd1, Wd2, bd2, (float*)d_out);
}

// Round 12
// 572.118 us; speedup vs baseline: 6.0078x; 1.2789x over previous
//
#include <hip/hip_runtime.h>
#include <hip/hip_bf16.h>
#include <stdint.h>
#include <stddef.h>

#define N_ 50000
#define E_ 600000
#define F_ 128
#define H_ 128
#define G_ 64
#define P_ 32
#define C_ 10

typedef __hip_bfloat16 bf16;
typedef __attribute__((ext_vector_type(8))) short short8;
typedef __attribute__((ext_vector_type(4))) float float4v;

__device__ __forceinline__ float b2f(bf16 x){ return __bfloat162float(x); }
__device__ __forceinline__ float us2f(unsigned short u){ return __uint_as_float(((unsigned int)u)<<16); }
__device__ __forceinline__ unsigned short f2us(float x){ bf16 h = __float2bfloat16(x); return *(unsigned short*)&h; }
__device__ __forceinline__ float eluf(float x){ return x>0.f ? x : expm1f(x); }
__device__ __forceinline__ float bnf(float x,float m,float v,float g,float b){ return (x-m)*rsqrtf(v+1e-5f)*g+b; }
__device__ __forceinline__ float lrelu(float x){ return x>0.f ? x : 0.2f*x; }
__device__ __forceinline__ float expc(float x){ return __expf(fminf(x, 50.f)); }
__device__ __forceinline__ void atomAddF(float* a, float v){ unsafeAtomicAdd(a, v); }

// ---------------- weight prep: WT[m][n][k] (bf16) = W_m[k][n] ----------------
// m: 0=W1, 1=Wl, 2=Wr, 3..5=Wg head 0..2
__global__ __launch_bounds__(256) void k_wprep(const float* __restrict__ W1, const float* __restrict__ Wl,
    const float* __restrict__ Wr, const float* __restrict__ Wg, unsigned short* __restrict__ WT){
  int idx = blockIdx.x*256 + threadIdx.x;
  if(idx >= 6*16384) return;
  int m = idx >> 14, rem = idx & 16383;
  int n = rem >> 7, k = rem & 127;
  float v;
  if(m==0)      v = W1[k*128+n];
  else if(m==1) v = Wl[k*128+n];
  else if(m==2) v = Wr[k*128+n];
  else          v = Wg[k*384 + (m-3)*128 + n];
  WT[idx] = f2us(v);
}

// ---------------- MFMA GEMM helpers ----------------
// LDS holds WT (128 out x 128 k, bf16), row stride 256B, 16B-chunk XOR-swizzled by (n&15)
__device__ __forceinline__ void stage_WT(const unsigned short* __restrict__ WTg, unsigned short* lds, int tid){
  #pragma unroll
  for(int i=0;i<8;i++){
    int idx = tid + i*256;           // uint4 index
    int n = idx>>4, c = idx&15;
    uint4 v = *(const uint4*)(WTg + (size_t)idx*8);
    int cs = c ^ (n & 15);
    *(uint4*)(lds + n*128 + cs*8) = v;
  }
}
__device__ __forceinline__ short8 read_Bfrag(const unsigned short* lds, int tile, int kc, int lane){
  int n = tile*16 + (lane&15);
  int c = kc*4 + (lane>>4);
  int cs = c ^ (lane & 15);
  return *(const short8*)(lds + n*128 + cs*8);
}
__device__ __forceinline__ void load_Afrag_bf16(const bf16* A, int row, int lane, short8 af[4]){
  const unsigned short* ap = (const unsigned short*)A + (size_t)row*128 + (lane>>4)*8;
  #pragma unroll
  for(int kc=0;kc<4;kc++) af[kc] = *(const short8*)(ap + kc*32);
}
__device__ __forceinline__ void mfma_pass(const unsigned short* lds, const short8 af[4], int lane, float4v acc[8]){
  #pragma unroll
  for(int tile=0;tile<8;tile++){
    #pragma unroll
    for(int kc=0;kc<4;kc++){
      short8 bfv = read_Bfrag(lds, tile, kc, lane);
      acc[tile] = __builtin_amdgcn_mfma_f32_16x16x32_bf16(af[kc], bfv, acc[tile], 0, 0, 0);
    }
  }
}

// h(bf16) = X(f32) @ W1
__global__ __launch_bounds__(256) void k_mm_x(const float* __restrict__ X, const unsigned short* __restrict__ WTg,
                                              bf16* __restrict__ HB){
  __shared__ unsigned short Wlds[128*128];
  const int tid = threadIdx.x, lane = tid&63, w = tid>>6;
  const int row0 = blockIdx.x*64;
  stage_WT(WTg, Wlds, tid);
  int arow = row0 + w*16 + (lane&15);
  int ar = arow < N_ ? arow : N_-1;
  const float* ap = X + (size_t)ar*128 + (lane>>4)*8;
  short8 af[4];
  #pragma unroll
  for(int kc=0;kc<4;kc++){
    float4 a = *(const float4*)(ap + kc*32);
    float4 b = *(const float4*)(ap + kc*32 + 4);
    short8 v;
    v[0]=(short)f2us(a.x); v[1]=(short)f2us(a.y); v[2]=(short)f2us(a.z); v[3]=(short)f2us(a.w);
    v[4]=(short)f2us(b.x); v[5]=(short)f2us(b.y); v[6]=(short)f2us(b.z); v[7]=(short)f2us(b.w);
    af[kc]=v;
  }
  __syncthreads();
  float4v acc[8];
  #pragma unroll
  for(int t=0;t<8;t++){ acc[t][0]=0.f; acc[t][1]=0.f; acc[t][2]=0.f; acc[t][3]=0.f; }
  mfma_pass(Wlds, af, lane, acc);
  const int colb = lane&15, q = lane>>4;
  unsigned short* ob = (unsigned short*)HB;
  #pragma unroll
  for(int r=0;r<4;r++){
    int ro = row0 + w*16 + q*4 + r;
    if(ro < N_){
      #pragma unroll
      for(int tile=0;tile<8;tile++)
        ob[(size_t)ro*128 + tile*16 + colb] = f2us(acc[tile][r]);
    }
  }
}

// h2(bf16) = elu(bn2( mean@Wl + h1@Wr + bs ))
__global__ __launch_bounds__(256) void k_sage_mm(const bf16* __restrict__ MaB, const bf16* __restrict__ H1B,
    const unsigned short* __restrict__ WlT, const unsigned short* __restrict__ WrT,
    const float* __restrict__ bs, const float* __restrict__ g2, const float* __restrict__ be2,
    const float* __restrict__ m2, const float* __restrict__ v2, bf16* __restrict__ H2B){
  __shared__ unsigned short Wlds[128*128];
  const int tid = threadIdx.x, lane = tid&63, w = tid>>6;
  const int row0 = blockIdx.x*64;
  int arow = row0 + w*16 + (lane&15);
  int ar = arow < N_ ? arow : N_-1;
  float4v acc[8];
  #pragma unroll
  for(int t=0;t<8;t++){ acc[t][0]=0.f; acc[t][1]=0.f; acc[t][2]=0.f; acc[t][3]=0.f; }
  short8 af[4];

  stage_WT(WlT, Wlds, tid);
  load_Afrag_bf16(MaB, ar, lane, af);
  __syncthreads();
  mfma_pass(Wlds, af, lane, acc);
  __syncthreads();
  stage_WT(WrT, Wlds, tid);
  load_Afrag_bf16(H1B, ar, lane, af);
  __syncthreads();
  mfma_pass(Wlds, af, lane, acc);

  const int colb = lane&15, q = lane>>4;
  unsigned short* ob = (unsigned short*)H2B;
  #pragma unroll
  for(int tile=0;tile<8;tile++){
    int col = tile*16 + colb;
    float bsv=bs[col], gv=g2[col], bev=be2[col], mv=m2[col], vv=v2[col];
    #pragma unroll
    for(int r=0;r<4;r++){
      int ro = row0 + w*16 + q*4 + r;
      if(ro < N_){
        float x = acc[tile][r] + bsv;
        ob[(size_t)ro*128 + col] = f2us(eluf(bnf(x, mv, vv, gv, bev)));
      }
    }
  }
}

// hgh(bf16) = h2 @ Wg_head; fused attention-logit epilogue -> als, ald
__global__ __launch_bounds__(256) void k_gat_mm(const bf16* __restrict__ H2B, const unsigned short* __restrict__ WgT,
    const float* __restrict__ a_src, const float* __restrict__ a_dst, int hh,
    bf16* __restrict__ HGH, float* __restrict__ als, float* __restrict__ ald){
  __shared__ unsigned short Wlds[128*128];
  const int tid = threadIdx.x, lane = tid&63, w = tid>>6;
  const int row0 = blockIdx.x*64;
  stage_WT(WgT, Wlds, tid);
  int arow = row0 + w*16 + (lane&15);
  int ar = arow < N_ ? arow : N_-1;
  short8 af[4];
  load_Afrag_bf16(H2B, ar, lane, af);
  __syncthreads();
  float4v acc[8];
  #pragma unroll
  for(int t=0;t<8;t++){ acc[t][0]=0.f; acc[t][1]=0.f; acc[t][2]=0.f; acc[t][3]=0.f; }
  mfma_pass(Wlds, af, lane, acc);

  const int colb = lane&15, q = lane>>4;
  float asv[8], adv[8];
  #pragma unroll
  for(int tile=0;tile<8;tile++){
    asv[tile] = a_src[hh*128 + tile*16 + colb];
    adv[tile] = a_dst[hh*128 + tile*16 + colb];
  }
  unsigned short* ob = (unsigned short*)HGH;
  #pragma unroll
  for(int r=0;r<4;r++){
    int ro = row0 + w*16 + q*4 + r;
    float ps = 0.f, pd = 0.f;
    #pragma unroll
    for(int tile=0;tile<8;tile++){ ps += acc[tile][r]*asv[tile]; pd += acc[tile][r]*adv[tile]; }
    #pragma unroll
    for(int o=8;o>0;o>>=1){ ps += __shfl_down(ps,o,16); pd += __shfl_down(pd,o,16); }
    if(ro < N_){
      #pragma unroll
      for(int tile=0;tile<8;tile++)
        ob[(size_t)ro*128 + tile*16 + colb] = f2us(acc[tile][r]);
      if(colb == 0){ als[ro] = ps; ald[ro] = pd; }
    }
  }
}

// ---------------- CSR build ----------------
__global__ __launch_bounds__(256) void k_count(const int* __restrict__ dst, int* __restrict__ cnt){
  int e = blockIdx.x*256 + threadIdx.x;
  if(e < E_) atomicAdd(&cnt[dst[e]], 1);
}

__global__ __launch_bounds__(1024) void k_scan(const int* __restrict__ cnt, int* __restrict__ row_ptr,
                                               int* __restrict__ tmp, float* __restrict__ dinv){
  __shared__ int wsum[16];
  __shared__ int carry_s;
  const int t = threadIdx.x;
  const int lane = t & 63, wid = t >> 6;
  if(t==0) carry_s = 0;
  __syncthreads();
  for(int base=0; base<N_; base+=1024){
    int i = base + t;
    int v = (i<N_) ? cnt[i] : 0;
    int x = v;
    #pragma unroll
    for(int o=1;o<64;o<<=1){
      int y = __shfl_up(x, o, 64);
      if(lane >= o) x += y;
    }
    if(lane==63) wsum[wid] = x;
    __syncthreads();
    if(wid==0){
      int s = (lane<16) ? wsum[lane] : 0;
      #pragma unroll
      for(int o=1;o<16;o<<=1){
        int y = __shfl_up(s, o, 64);
        if(lane >= o) s += y;
      }
      if(lane<16) wsum[lane] = s;
    }
    __syncthreads();
    int waveoff = (wid>0) ? wsum[wid-1] : 0;
    int incl = carry_s + waveoff + x;
    int excl = incl - v;
    if(i<N_){
      row_ptr[i] = excl;
      tmp[i] = excl;
      dinv[i] = rsqrtf((float)v + 1.f);
    }
    __syncthreads();
    if(t==1023) carry_s = incl;
    __syncthreads();
  }
  if(t==0) row_ptr[N_] = carry_s;
}

__global__ __launch_bounds__(256) void k_scatter(const int* __restrict__ src, const int* __restrict__ dst,
                                                 int* __restrict__ tmp, int* __restrict__ esrc){
  int e = blockIdx.x*256 + threadIdx.x;
  if(e < E_){
    int d = dst[e];
    int pos = atomicAdd(&tmp[d], 1);
    esrc[pos] = src[e];
  }
}

// ---------------- CSR gather kernels (1 wave = 1 node, 2 feats/lane) ----------------
__global__ __launch_bounds__(256) void k_gcn_gather(const int* __restrict__ row_ptr, const int* __restrict__ esrc,
    const float* __restrict__ dinv, const bf16* __restrict__ HB,
    const float* __restrict__ b1, const float* __restrict__ g1, const float* __restrict__ be1,
    const float* __restrict__ m1, const float* __restrict__ v1, bf16* __restrict__ H1B){
  int n = blockIdx.x*4 + (threadIdx.x>>6);
  int lane = threadIdx.x & 63;
  if(n >= N_) return;
  int beg = row_ptr[n], end = row_ptr[n+1];
  float dn = dinv[n];
  float a0 = 0.f, a1 = 0.f;
  const unsigned short* hb = (const unsigned short*)HB;
  int e = beg;
  for(; e+1 < end; e += 2){
    int s0 = esrc[e], s1 = esrc[e+1];
    unsigned int hv0 = *(const unsigned int*)(hb + (size_t)s0*H_ + lane*2);
    unsigned int hv1 = *(const unsigned int*)(hb + (size_t)s1*H_ + lane*2);
    float c0 = dinv[s0]*dn, c1 = dinv[s1]*dn;
    a0 += c0*us2f((unsigned short)(hv0 & 0xFFFFu)) + c1*us2f((unsigned short)(hv1 & 0xFFFFu));
    a1 += c0*us2f((unsigned short)(hv0 >> 16))     + c1*us2f((unsigned short)(hv1 >> 16));
  }
  if(e < end){
    int s = esrc[e];
    float c = dinv[s]*dn;
    unsigned int hv = *(const unsigned int*)(hb + (size_t)s*H_ + lane*2);
    a0 += c*us2f((unsigned short)(hv & 0xFFFFu));
    a1 += c*us2f((unsigned short)(hv >> 16));
  }
  unsigned int hv = *(const unsigned int*)(hb + (size_t)n*H_ + lane*2);
  int f0 = lane*2, f1 = f0+1;
  float x0 = a0 + us2f((unsigned short)(hv & 0xFFFFu))*dn*dn + b1[f0];
  float x1 = a1 + us2f((unsigned short)(hv >> 16))*dn*dn + b1[f1];
  x0 = eluf(bnf(x0, m1[f0], v1[f0], g1[f0], be1[f0]));
  x1 = eluf(bnf(x1, m1[f1], v1[f1], g1[f1], be1[f1]));
  unsigned int o = ((unsigned int)f2us(x1)<<16) | f2us(x0);
  *(unsigned int*)((unsigned short*)H1B + (size_t)n*H_ + lane*2) = o;
}

__global__ __launch_bounds__(256) void k_sage_gather(const int* __restrict__ row_ptr, const int* __restrict__ esrc,
    const bf16* __restrict__ H1B, bf16* __restrict__ MeanB){
  int n = blockIdx.x*4 + (threadIdx.x>>6);
  int lane = threadIdx.x & 63;
  if(n >= N_) return;
  int beg = row_ptr[n], end = row_ptr[n+1];
  float a0 = 0.f, a1 = 0.f;
  const unsigned short* hb = (const unsigned short*)H1B;
  int e = beg;
  for(; e+1 < end; e += 2){
    int s0 = esrc[e], s1 = esrc[e+1];
    unsigned int hv0 = *(const unsigned int*)(hb + (size_t)s0*H_ + lane*2);
    unsigned int hv1 = *(const unsigned int*)(hb + (size_t)s1*H_ + lane*2);
    a0 += us2f((unsigned short)(hv0 & 0xFFFFu)) + us2f((unsigned short)(hv1 & 0xFFFFu));
    a1 += us2f((unsigned short)(hv0 >> 16))     + us2f((unsigned short)(hv1 >> 16));
  }
  if(e < end){
    unsigned int hv = *(const unsigned int*)(hb + (size_t)esrc[e]*H_ + lane*2);
    a0 += us2f((unsigned short)(hv & 0xFFFFu));
    a1 += us2f((unsigned short)(hv >> 16));
  }
  float inv = 1.f / fmaxf((float)(end-beg), 1.f);
  unsigned int o = ((unsigned int)f2us(a1*inv)<<16) | f2us(a0*inv);
  *(unsigned int*)((unsigned short*)MeanB + (size_t)n*H_ + lane*2) = o;
}

// GAT gather, single pass: unnormalized sum + den together; head-mean into bf16 acc
__global__ __launch_bounds__(256) void k_gat_gather(const int* __restrict__ row_ptr, const int* __restrict__ esrc,
    const float* __restrict__ als, const float* __restrict__ ald, const bf16* __restrict__ HGH,
    int hh, bf16* __restrict__ ACCB){
  int n = blockIdx.x*4 + (threadIdx.x>>6);
  int lane = threadIdx.x & 63;
  if(n >= N_) return;
  int beg = row_ptr[n], end = row_ptr[n+1];
  float aldn = ald[n];
  float eself = expc(lrelu(als[n] + aldn));
  const unsigned short* hb = (const unsigned short*)HGH;
  unsigned int hv = *(const unsigned int*)(hb + (size_t)n*H_ + lane*2);
  float den = eself;
  float a0 = eself*us2f((unsigned short)(hv & 0xFFFFu));
  float a1 = eself*us2f((unsigned short)(hv >> 16));
  int e = beg;
  for(; e+1 < end; e += 2){
    int s0 = esrc[e], s1 = esrc[e+1];
    unsigned int sv0 = *(const unsigned int*)(hb + (size_t)s0*H_ + lane*2);
    unsigned int sv1 = *(const unsigned int*)(hb + (size_t)s1*H_ + lane*2);
    float w0 = expc(lrelu(als[s0] + aldn));
    float w1 = expc(lrelu(als[s1] + aldn));
    den += w0 + w1;
    a0 += w0*us2f((unsigned short)(sv0 & 0xFFFFu)) + w1*us2f((unsigned short)(sv1 & 0xFFFFu));
    a1 += w0*us2f((unsigned short)(sv0 >> 16))     + w1*us2f((unsigned short)(sv1 >> 16));
  }
  if(e < end){
    int s = esrc[e];
    float w = expc(lrelu(als[s] + aldn));
    unsigned int sv = *(const unsigned int*)(hb + (size_t)s*H_ + lane*2);
    den += w;
    a0 += w*us2f((unsigned short)(sv & 0xFFFFu));
    a1 += w*us2f((unsigned short)(sv >> 16));
  }
  float inv = 1.f/(3.f*den);
  a0 *= inv; a1 *= inv;
  unsigned int* acc = (unsigned int*)((unsigned short*)ACCB + (size_t)n*H_ + lane*2);
  if(hh != 0){
    unsigned int old = *acc;
    a0 += us2f((unsigned short)(old & 0xFFFFu));
    a1 += us2f((unsigned short)(old >> 16));
  }
  *acc = ((unsigned int)f2us(a1)<<16) | f2us(a0);
}

// h3 finalize + pool
#define NPW_ 16
__global__ __launch_bounds__(256) void k_h3fin_pool(const bf16* __restrict__ ACCB, const float* __restrict__ bg,
    const float* __restrict__ g3, const float* __restrict__ be3, const float* __restrict__ m3, const float* __restrict__ v3,
    const int* __restrict__ batch, float* __restrict__ pooled, float* __restrict__ gcnt){
  int wave = blockIdx.x*4 + (threadIdx.x>>6);
  int lane = threadIdx.x & 63;
  int n0 = wave*NPW_;
  if(n0 >= N_) return;
  int n1 = n0 + NPW_; if(n1 > N_) n1 = N_;
  int f0 = lane*2, f1 = f0+1;
  float bg0=bg[f0], bg1=bg[f1];
  float g30=g3[f0], g31=g3[f1], be30=be3[f0], be31=be3[f1];
  float m30=m3[f0], m31=m3[f1], v30=v3[f0], v31=v3[f1];
  float r0=0.f, r1=0.f;
  int cur = batch[n0];
  int seg = 0;
  for(int n=n0; n<n1; n++){
    int b = batch[n];
    if(b != cur){
      atomAddF(&pooled[cur*H_ + f0], r0);
      atomAddF(&pooled[cur*H_ + f1], r1);
      if(lane==0) atomAddF(&gcnt[cur], (float)seg);
      r0 = 0.f; r1 = 0.f; seg = 0; cur = b;
    }
    unsigned int hv = *(const unsigned int*)((const unsigned short*)ACCB + (size_t)n*H_ + lane*2);
    float x0 = us2f((unsigned short)(hv & 0xFFFFu)) + bg0;
    float x1 = us2f((unsigned short)(hv >> 16)) + bg1;
    r0 += eluf(bnf(x0, m30, v30, g30, be30));
    r1 += eluf(bnf(x1, m31, v31, g31, be31));
    seg++;
  }
  atomAddF(&pooled[cur*H_ + f0], r0);
  atomAddF(&pooled[cur*H_ + f1], r1);
  if(lane==0) atomAddF(&gcnt[cur], (float)seg);
}

// per-graph head — fp32 output
__global__ __launch_bounds__(128) void k_head(const float* __restrict__ pooledacc, const float* __restrict__ gcnt,
    const float* __restrict__ protos, const float* __restrict__ Wc, const float* __restrict__ bc,
    const float* __restrict__ Wd1, const float* __restrict__ bd1, const float* __restrict__ Wd2, const float* __restrict__ bd2,
    float* __restrict__ out){
  const int g = blockIdx.x, t = threadIdx.x;
  __shared__ float p[128], xn[128], red[128], sims[32], es[32], asg[32], pe[128], t1[256];
  __shared__ float nrm;
  float cg_ = fmaxf(gcnt[g], 1.f);
  p[t] = pooledacc[g*128 + t] / cg_;
  __syncthreads();
  red[t] = p[t]*p[t];
  __syncthreads();
  for(int s=64;s>0;s>>=1){ if(t<s) red[t]+=red[t+s]; __syncthreads(); }
  if(t==0) nrm = fmaxf(sqrtf(red[0]), 1e-8f);
  __syncthreads();
  xn[t] = p[t]/nrm;
  __syncthreads();
  if(t<32){
    float s=0.f, pn=0.f;
    for(int f=0;f<128;f++){ float pv=protos[t*128+f]; s += xn[f]*pv; pn += pv*pv; }
    sims[t] = s / fmaxf(sqrtf(pn), 1e-8f);
  }
  __syncthreads();
  if(t<32){
    float mx=-1e30f;
    for(int j=0;j<32;j++) mx = fmaxf(mx, sims[j]);
    es[t] = __expf(sims[t]-mx);
  }
  __syncthreads();
  if(t<32){
    float sm=0.f;
    for(int j=0;j<32;j++) sm += es[j];
    float a = es[t]/fmaxf(sm,1e-20f);
    asg[t] = a;
    out[8832 + g*32 + t] = a;
  }
  __syncthreads();
  {
    float s=0.f;
    for(int pp=0;pp<32;pp++) s += asg[pp]*protos[pp*128+t];
    pe[t] = s;
    out[640 + g*128 + t] = s;
  }
  __syncthreads();
  if(t<10){
    float s = bc[t];
    for(int f=0;f<128;f++) s += pe[f]*Wc[f*10+t];
    out[g*10 + t] = s;
  }
  for(int j=t;j<256;j+=128){
    float s = bd1[j];
    for(int f=0;f<128;f++) s += p[f]*Wd1[f*256+j];
    t1[j] = fmaxf(s, 0.f);
  }
  __syncthreads();
  {
    float s = bd2[t];
    for(int j=0;j<256;j++) s += t1[j]*Wd2[j*128+t];
    out[10880 + g*128 + t] = s;
  }
}

__global__ void k_sentinel(float* out, float code){
  out[0] = code;
}

extern "C" void kernel_launch(void* const* d_in, const int* in_sizes, int n_in,
                              void* d_out, int out_size, void* d_ws, size_t ws_size,
                              hipStream_t stream){
  const float* X    = (const float*)d_in[0];
  const int*  EI    = (const int*)d_in[1];
  const int*  batch = (const int*)d_in[2];
  const int* src = EI;
  const int* dst = EI + E_;

  int iW1,ib1,iWl,iWr,ibs,iWg,ias,iad,ibg,ipr,iWc,ibc,iWd1,ibd1,iWd2,ibd2;
  int ig1,ibe1,im1,iv1,ig2,ibe2,im2,iv2,ig3,ibe3,im3,iv3;
  if(n_in >= 31 && in_sizes[5] == 128){
    iW1=3; ib1=4; ig1=5; ibe1=6; im1=7; iv1=8;
    iWl=9; iWr=10; ibs=11; ig2=12; ibe2=13; im2=14; iv2=15;
    iWg=16; ias=17; iad=18; ibg=19; ig3=20; ibe3=21; im3=22; iv3=23;
    ipr=24; iWc=25; ibc=26; iWd1=27; ibd1=28; iWd2=29; ibd2=30;
  }else{
    iW1=3; ib1=4; iWl=5; iWr=6; ibs=7; iWg=8; ias=9; iad=10; ibg=11;
    ipr=12; iWc=13; ibc=14; iWd1=15; ibd1=16; iWd2=17; ibd2=18;
    ig1=19; ibe1=20; im1=21; iv1=22; ig2=23; ibe2=24; im2=25; iv2=26;
    ig3=27; ibe3=28; im3=29; iv3=30;
  }
  const float* W1 = (const float*)d_in[iW1];   const float* b1 = (const float*)d_in[ib1];
  const float* Wl = (const float*)d_in[iWl];   const float* Wr = (const float*)d_in[iWr];
  const float* bs = (const float*)d_in[ibs];   const float* Wg = (const float*)d_in[iWg];
  const float* a_src = (const float*)d_in[ias]; const float* a_dst = (const float*)d_in[iad];
  const float* bg = (const float*)d_in[ibg];   const float* protos = (const float*)d_in[ipr];
  const float* Wc = (const float*)d_in[iWc];   const float* bc = (const float*)d_in[ibc];
  const float* Wd1 = (const float*)d_in[iWd1]; const float* bd1 = (const float*)d_in[ibd1];
  const float* Wd2 = (const float*)d_in[iWd2]; const float* bd2 = (const float*)d_in[ibd2];
  const float* g1 = (const float*)d_in[ig1];   const float* be1 = (const float*)d_in[ibe1];
  const float* m1 = (const float*)d_in[im1];   const float* v1 = (const float*)d_in[iv1];
  const float* g2 = (const float*)d_in[ig2];   const float* be2 = (const float*)d_in[ibe2];
  const float* m2 = (const float*)d_in[im2];   const float* v2 = (const float*)d_in[iv2];
  const float* g3 = (const float*)d_in[ig3];   const float* be3 = (const float*)d_in[ibe3];
  const float* m3 = (const float*)d_in[im3];   const float* v3 = (const float*)d_in[iv3];

  const size_t NF = (size_t)N_*H_;
  const size_t intN = (size_t)N_ + (N_+1) + N_ + E_;
  const size_t fltN = (size_t)3*N_ + G_*H_ + G_;
  const size_t NEED = NF*2*3 + intN*4 + fltN*4 + (size_t)6*16384*2;
  if(ws_size < NEED){
    k_sentinel<<<1,1,0,stream>>>((float*)d_out, 1000.f + (float)(ws_size>>20));
    return;
  }
  bf16* RA = (bf16*)d_ws;            // h -> h2
  bf16* RB = RA + NF;                // h1 -> hgh (per head)
  bf16* RC = RB + NF;                // mean_nb -> h3 accumulator
  int*  cnt     = (int*)(RC + NF);
  int*  row_ptr = cnt + N_;
  int*  tmp     = row_ptr + (N_+1);
  int*  esrc    = tmp + N_;
  float* dinv   = (float*)(esrc + E_);
  float* als    = dinv + N_;
  float* ald    = als + N_;
  float* pooled = ald + N_;
  float* gcnt   = pooled + (size_t)G_*H_;
  unsigned short* WTg = (unsigned short*)(gcnt + G_);  // 6 x 128 x 128 bf16

  // ---- weight prep + CSR build ----
  k_wprep<<<(6*16384+255)/256, 256, 0, stream>>>(W1, Wl, Wr, Wg, WTg);
  hipMemsetAsync(cnt, 0, N_*sizeof(int), stream);
  k_count<<<(E_+255)/256, 256, 0, stream>>>(dst, cnt);
  k_scan<<<1, 1024, 0, stream>>>(cnt, row_ptr, tmp, dinv);
  k_scatter<<<(E_+255)/256, 256, 0, stream>>>(src, dst, tmp, esrc);

  const int GB = (N_+3)/4;
  const int MB = (N_+63)/64;
  // ---- GCN ----
  k_mm_x<<<MB, 256, 0, stream>>>(X, WTg, RA);
  k_gcn_gather<<<GB, 256, 0, stream>>>(row_ptr, esrc, dinv, RA, b1, g1, be1, m1, v1, RB);
  // ---- SAGE ----
  k_sage_gather<<<GB, 256, 0, stream>>>(row_ptr, esrc, RB, RC);
  k_sage_mm<<<MB, 256, 0, stream>>>(RC, RB, WTg + 16384, WTg + 2*16384, bs, g2, be2, m2, v2, RA);
  // ---- GAT (per head) ----
  for(int hh=0; hh<3; hh++){
    k_gat_mm<<<MB, 256, 0, stream>>>(RA, WTg + (3+hh)*16384, a_src, a_dst, hh, RB, als, ald);
    k_gat_gather<<<GB, 256, 0, stream>>>(row_ptr, esrc, als, ald, RB, hh, RC);
  }
  // ---- pool + heads ----
  hipMemsetAsync(pooled, 0, (size_t)(G_*H_+G_)*sizeof(float), stream);
  {
    int waves = (N_ + NPW_ - 1)/NPW_;
    int blocks = (waves + 3)/4;
    k_h3fin_pool<<<blocks, 256, 0, stream>>>(RC, bg, g3, be3, m3, v3, batch, pooled, gcnt);
  }
  k_head<<<G_, 128, 0, stream>>>(pooled, gcnt, protos, Wc, bc, Wd1, bd1, Wd2, bd2, (float*)d_out);
}

// Round 13
// 482.260 us; speedup vs baseline: 7.1272x; 1.1863x over previous
//
#include <hip/hip_runtime.h>
#include <hip/hip_bf16.h>
#include <stdint.h>
#include <stddef.h>

#define N_ 50000
#define E_ 600000
#define F_ 128
#define H_ 128
#define G_ 64
#define P_ 32
#define C_ 10
#define NB_ 49   // scan blocks: ceil(N/1024)

typedef __hip_bfloat16 bf16;
typedef __attribute__((ext_vector_type(8))) short short8;
typedef __attribute__((ext_vector_type(4))) float float4v;

__device__ __forceinline__ float b2f(bf16 x){ return __bfloat162float(x); }
__device__ __forceinline__ float us2f(unsigned short u){ return __uint_as_float(((unsigned int)u)<<16); }
__device__ __forceinline__ unsigned short f2us(float x){ bf16 h = __float2bfloat16(x); return *(unsigned short*)&h; }
__device__ __forceinline__ float eluf(float x){ return x>0.f ? x : expm1f(x); }
__device__ __forceinline__ float bnf(float x,float m,float v,float g,float b){ return (x-m)*rsqrtf(v+1e-5f)*g+b; }
__device__ __forceinline__ float lrelu(float x){ return x>0.f ? x : 0.2f*x; }
__device__ __forceinline__ float expc(float x){ return __expf(fminf(x, 50.f)); }
__device__ __forceinline__ void atomAddF(float* a, float v){ unsafeAtomicAdd(a, v); }

// ---------------- weight prep: WT[m][n][k] (bf16) = W_m[k][n] ----------------
__global__ __launch_bounds__(256) void k_wprep(const float* __restrict__ W1, const float* __restrict__ Wl,
    const float* __restrict__ Wr, const float* __restrict__ Wg, unsigned short* __restrict__ WT){
  int idx = blockIdx.x*256 + threadIdx.x;
  if(idx >= 6*16384) return;
  int m = idx >> 14, rem = idx & 16383;
  int n = rem >> 7, k = rem & 127;
  float v;
  if(m==0)      v = W1[k*128+n];
  else if(m==1) v = Wl[k*128+n];
  else if(m==2) v = Wr[k*128+n];
  else          v = Wg[k*384 + (m-3)*128 + n];
  WT[idx] = f2us(v);
}

// ---------------- MFMA GEMM helpers ----------------
__device__ __forceinline__ void stage_WT(const unsigned short* __restrict__ WTg, unsigned short* lds, int tid){
  #pragma unroll
  for(int i=0;i<8;i++){
    int idx = tid + i*256;
    int n = idx>>4, c = idx&15;
    uint4 v = *(const uint4*)(WTg + (size_t)idx*8);
    int cs = c ^ (n & 15);
    *(uint4*)(lds + n*128 + cs*8) = v;
  }
}
__device__ __forceinline__ short8 read_Bfrag(const unsigned short* lds, int tile, int kc, int lane){
  int n = tile*16 + (lane&15);
  int c = kc*4 + (lane>>4);
  int cs = c ^ (lane & 15);
  return *(const short8*)(lds + n*128 + cs*8);
}
__device__ __forceinline__ void load_Afrag_bf16(const bf16* A, int row, int lane, short8 af[4]){
  const unsigned short* ap = (const unsigned short*)A + (size_t)row*128 + (lane>>4)*8;
  #pragma unroll
  for(int kc=0;kc<4;kc++) af[kc] = *(const short8*)(ap + kc*32);
}
__device__ __forceinline__ void mfma_pass(const unsigned short* lds, const short8 af[4], int lane, float4v acc[8]){
  #pragma unroll
  for(int tile=0;tile<8;tile++){
    #pragma unroll
    for(int kc=0;kc<4;kc++){
      short8 bfv = read_Bfrag(lds, tile, kc, lane);
      acc[tile] = __builtin_amdgcn_mfma_f32_16x16x32_bf16(af[kc], bfv, acc[tile], 0, 0, 0);
    }
  }
}

// h(bf16) = X(f32) @ W1
__global__ __launch_bounds__(256) void k_mm_x(const float* __restrict__ X, const unsigned short* __restrict__ WTg,
                                              bf16* __restrict__ HB){
  __shared__ unsigned short Wlds[128*128];
  const int tid = threadIdx.x, lane = tid&63, w = tid>>6;
  const int row0 = blockIdx.x*64;
  stage_WT(WTg, Wlds, tid);
  int arow = row0 + w*16 + (lane&15);
  int ar = arow < N_ ? arow : N_-1;
  const float* ap = X + (size_t)ar*128 + (lane>>4)*8;
  short8 af[4];
  #pragma unroll
  for(int kc=0;kc<4;kc++){
    float4 a = *(const float4*)(ap + kc*32);
    float4 b = *(const float4*)(ap + kc*32 + 4);
    short8 v;
    v[0]=(short)f2us(a.x); v[1]=(short)f2us(a.y); v[2]=(short)f2us(a.z); v[3]=(short)f2us(a.w);
    v[4]=(short)f2us(b.x); v[5]=(short)f2us(b.y); v[6]=(short)f2us(b.z); v[7]=(short)f2us(b.w);
    af[kc]=v;
  }
  __syncthreads();
  float4v acc[8];
  #pragma unroll
  for(int t=0;t<8;t++){ acc[t][0]=0.f; acc[t][1]=0.f; acc[t][2]=0.f; acc[t][3]=0.f; }
  mfma_pass(Wlds, af, lane, acc);
  const int colb = lane&15, q = lane>>4;
  unsigned short* ob = (unsigned short*)HB;
  #pragma unroll
  for(int r=0;r<4;r++){
    int ro = row0 + w*16 + q*4 + r;
    if(ro < N_){
      #pragma unroll
      for(int tile=0;tile<8;tile++)
        ob[(size_t)ro*128 + tile*16 + colb] = f2us(acc[tile][r]);
    }
  }
}

// h2(bf16) = elu(bn2( mean@Wl + h1@Wr + bs ))
__global__ __launch_bounds__(256) void k_sage_mm(const bf16* __restrict__ MaB, const bf16* __restrict__ H1B,
    const unsigned short* __restrict__ WlT, const unsigned short* __restrict__ WrT,
    const float* __restrict__ bs, const float* __restrict__ g2, const float* __restrict__ be2,
    const float* __restrict__ m2, const float* __restrict__ v2, bf16* __restrict__ H2B){
  __shared__ unsigned short Wlds[128*128];
  const int tid = threadIdx.x, lane = tid&63, w = tid>>6;
  const int row0 = blockIdx.x*64;
  int arow = row0 + w*16 + (lane&15);
  int ar = arow < N_ ? arow : N_-1;
  float4v acc[8];
  #pragma unroll
  for(int t=0;t<8;t++){ acc[t][0]=0.f; acc[t][1]=0.f; acc[t][2]=0.f; acc[t][3]=0.f; }
  short8 af[4];

  stage_WT(WlT, Wlds, tid);
  load_Afrag_bf16(MaB, ar, lane, af);
  __syncthreads();
  mfma_pass(Wlds, af, lane, acc);
  __syncthreads();
  stage_WT(WrT, Wlds, tid);
  load_Afrag_bf16(H1B, ar, lane, af);
  __syncthreads();
  mfma_pass(Wlds, af, lane, acc);

  const int colb = lane&15, q = lane>>4;
  unsigned short* ob = (unsigned short*)H2B;
  #pragma unroll
  for(int tile=0;tile<8;tile++){
    int col = tile*16 + colb;
    float bsv=bs[col], gv=g2[col], bev=be2[col], mv=m2[col], vv=v2[col];
    #pragma unroll
    for(int r=0;r<4;r++){
      int ro = row0 + w*16 + q*4 + r;
      if(ro < N_){
        float x = acc[tile][r] + bsv;
        ob[(size_t)ro*128 + col] = f2us(eluf(bnf(x, mv, vv, gv, bev)));
      }
    }
  }
}

// hgh(bf16) = h2 @ Wg_head; fused attention-logit epilogue -> als, ald
__global__ __launch_bounds__(256) void k_gat_mm(const bf16* __restrict__ H2B, const unsigned short* __restrict__ WgT,
    const float* __restrict__ a_src, const float* __restrict__ a_dst, int hh,
    bf16* __restrict__ HGH, float* __restrict__ als, float* __restrict__ ald){
  __shared__ unsigned short Wlds[128*128];
  const int tid = threadIdx.x, lane = tid&63, w = tid>>6;
  const int row0 = blockIdx.x*64;
  stage_WT(WgT, Wlds, tid);
  int arow = row0 + w*16 + (lane&15);
  int ar = arow < N_ ? arow : N_-1;
  short8 af[4];
  load_Afrag_bf16(H2B, ar, lane, af);
  __syncthreads();
  float4v acc[8];
  #pragma unroll
  for(int t=0;t<8;t++){ acc[t][0]=0.f; acc[t][1]=0.f; acc[t][2]=0.f; acc[t][3]=0.f; }
  mfma_pass(Wlds, af, lane, acc);

  const int colb = lane&15, q = lane>>4;
  float asv[8], adv[8];
  #pragma unroll
  for(int tile=0;tile<8;tile++){
    asv[tile] = a_src[hh*128 + tile*16 + colb];
    adv[tile] = a_dst[hh*128 + tile*16 + colb];
  }
  unsigned short* ob = (unsigned short*)HGH;
  #pragma unroll
  for(int r=0;r<4;r++){
    int ro = row0 + w*16 + q*4 + r;
    float ps = 0.f, pd = 0.f;
    #pragma unroll
    for(int tile=0;tile<8;tile++){ ps += acc[tile][r]*asv[tile]; pd += acc[tile][r]*adv[tile]; }
    #pragma unroll
    for(int o=8;o>0;o>>=1){ ps += __shfl_down(ps,o,16); pd += __shfl_down(pd,o,16); }
    if(ro < N_){
      #pragma unroll
      for(int tile=0;tile<8;tile++)
        ob[(size_t)ro*128 + tile*16 + colb] = f2us(acc[tile][r]);
      if(colb == 0){ als[ro] = ps; ald[ro] = pd; }
    }
  }
}

// ---------------- CSR build ----------------
__global__ __launch_bounds__(256) void k_count(const int* __restrict__ dst, int* __restrict__ cnt){
  int e = blockIdx.x*256 + threadIdx.x;
  if(e < E_) atomicAdd(&cnt[dst[e]], 1);
}

// phase 1: per-block local scan + block totals + dinv
__global__ __launch_bounds__(1024) void k_scan1(const int* __restrict__ cnt, int* __restrict__ row_ptr,
                                                float* __restrict__ dinv, int* __restrict__ bsum){
  __shared__ int wsum[16];
  const int t = threadIdx.x, lane = t & 63, wid = t >> 6;
  int i = blockIdx.x*1024 + t;
  int v = (i<N_) ? cnt[i] : 0;
  int x = v;
  #pragma unroll
  for(int o=1;o<64;o<<=1){
    int y = __shfl_up(x, o, 64);
    if(lane >= o) x += y;
  }
  if(lane==63) wsum[wid] = x;
  __syncthreads();
  if(wid==0){
    int s = (lane<16) ? wsum[lane] : 0;
    #pragma unroll
    for(int o=1;o<16;o<<=1){
      int y = __shfl_up(s, o, 64);
      if(lane >= o) s += y;
    }
    if(lane<16) wsum[lane] = s;
  }
  __syncthreads();
  int waveoff = (wid>0) ? wsum[wid-1] : 0;
  int incl = waveoff + x;
  if(i<N_){
    row_ptr[i] = incl - v;            // local exclusive
    dinv[i] = rsqrtf((float)v + 1.f);
  }
  if(t==1023) bsum[blockIdx.x] = incl;
}

// phase 2: one wave scans NB_ block totals -> exclusive offsets; writes row_ptr[N]
__global__ __launch_bounds__(64) void k_scan2(const int* __restrict__ bsum, int* __restrict__ boff,
                                              int* __restrict__ row_ptr){
  int lane = threadIdx.x;
  int v = (lane < NB_) ? bsum[lane] : 0;
  int x = v;
  #pragma unroll
  for(int o=1;o<64;o<<=1){
    int y = __shfl_up(x, o, 64);
    if(lane >= o) x += y;
  }
  if(lane < NB_) boff[lane] = x - v;
  if(lane == 63) row_ptr[N_] = x;
}

// phase 3: add block offsets
__global__ __launch_bounds__(256) void k_scan3(int* __restrict__ row_ptr, const int* __restrict__ boff,
                                               int* __restrict__ tmp){
  int i = blockIdx.x*256 + threadIdx.x;
  if(i < N_){
    int r = row_ptr[i] + boff[i>>10];
    row_ptr[i] = r;
    tmp[i] = r;
  }
}

__global__ __launch_bounds__(256) void k_scatter(const int* __restrict__ src, const int* __restrict__ dst,
                                                 int* __restrict__ tmp, int* __restrict__ esrc){
  int e = blockIdx.x*256 + threadIdx.x;
  if(e < E_){
    int d = dst[e];
    int pos = atomicAdd(&tmp[d], 1);
    esrc[pos] = src[e];
  }
}

// ---------------- CSR gather kernels (1 wave = 1 node, 2 feats/lane, unroll-4) ----------------
__global__ __launch_bounds__(256) void k_gcn_gather(const int* __restrict__ row_ptr, const int* __restrict__ esrc,
    const float* __restrict__ dinv, const bf16* __restrict__ HB,
    const float* __restrict__ b1, const float* __restrict__ g1, const float* __restrict__ be1,
    const float* __restrict__ m1, const float* __restrict__ v1, bf16* __restrict__ H1B){
  int n = blockIdx.x*4 + (threadIdx.x>>6);
  int lane = threadIdx.x & 63;
  if(n >= N_) return;
  int beg = row_ptr[n], end = row_ptr[n+1];
  float dn = dinv[n];
  float a0 = 0.f, a1 = 0.f;
  const unsigned short* hb = (const unsigned short*)HB;
  int e = beg;
  for(; e+3 < end; e += 4){
    int s0 = esrc[e], s1 = esrc[e+1], s2 = esrc[e+2], s3 = esrc[e+3];
    unsigned int hv0 = *(const unsigned int*)(hb + (size_t)s0*H_ + lane*2);
    unsigned int hv1 = *(const unsigned int*)(hb + (size_t)s1*H_ + lane*2);
    unsigned int hv2 = *(const unsigned int*)(hb + (size_t)s2*H_ + lane*2);
    unsigned int hv3 = *(const unsigned int*)(hb + (size_t)s3*H_ + lane*2);
    float c0 = dinv[s0]*dn, c1 = dinv[s1]*dn, c2 = dinv[s2]*dn, c3 = dinv[s3]*dn;
    a0 += c0*us2f((unsigned short)(hv0 & 0xFFFFu)) + c1*us2f((unsigned short)(hv1 & 0xFFFFu))
        + c2*us2f((unsigned short)(hv2 & 0xFFFFu)) + c3*us2f((unsigned short)(hv3 & 0xFFFFu));
    a1 += c0*us2f((unsigned short)(hv0 >> 16)) + c1*us2f((unsigned short)(hv1 >> 16))
        + c2*us2f((unsigned short)(hv2 >> 16)) + c3*us2f((unsigned short)(hv3 >> 16));
  }
  for(; e < end; e++){
    int s = esrc[e];
    float c = dinv[s]*dn;
    unsigned int hv = *(const unsigned int*)(hb + (size_t)s*H_ + lane*2);
    a0 += c*us2f((unsigned short)(hv & 0xFFFFu));
    a1 += c*us2f((unsigned short)(hv >> 16));
  }
  unsigned int hv = *(const unsigned int*)(hb + (size_t)n*H_ + lane*2);
  int f0 = lane*2, f1 = f0+1;
  float x0 = a0 + us2f((unsigned short)(hv & 0xFFFFu))*dn*dn + b1[f0];
  float x1 = a1 + us2f((unsigned short)(hv >> 16))*dn*dn + b1[f1];
  x0 = eluf(bnf(x0, m1[f0], v1[f0], g1[f0], be1[f0]));
  x1 = eluf(bnf(x1, m1[f1], v1[f1], g1[f1], be1[f1]));
  unsigned int o = ((unsigned int)f2us(x1)<<16) | f2us(x0);
  *(unsigned int*)((unsigned short*)H1B + (size_t)n*H_ + lane*2) = o;
}

__global__ __launch_bounds__(256) void k_sage_gather(const int* __restrict__ row_ptr, const int* __restrict__ esrc,
    const bf16* __restrict__ H1B, bf16* __restrict__ MeanB){
  int n = blockIdx.x*4 + (threadIdx.x>>6);
  int lane = threadIdx.x & 63;
  if(n >= N_) return;
  int beg = row_ptr[n], end = row_ptr[n+1];
  float a0 = 0.f, a1 = 0.f;
  const unsigned short* hb = (const unsigned short*)H1B;
  int e = beg;
  for(; e+3 < end; e += 4){
    int s0 = esrc[e], s1 = esrc[e+1], s2 = esrc[e+2], s3 = esrc[e+3];
    unsigned int hv0 = *(const unsigned int*)(hb + (size_t)s0*H_ + lane*2);
    unsigned int hv1 = *(const unsigned int*)(hb + (size_t)s1*H_ + lane*2);
    unsigned int hv2 = *(const unsigned int*)(hb + (size_t)s2*H_ + lane*2);
    unsigned int hv3 = *(const unsigned int*)(hb + (size_t)s3*H_ + lane*2);
    a0 += us2f((unsigned short)(hv0 & 0xFFFFu)) + us2f((unsigned short)(hv1 & 0xFFFFu))
        + us2f((unsigned short)(hv2 & 0xFFFFu)) + us2f((unsigned short)(hv3 & 0xFFFFu));
    a1 += us2f((unsigned short)(hv0 >> 16)) + us2f((unsigned short)(hv1 >> 16))
        + us2f((unsigned short)(hv2 >> 16)) + us2f((unsigned short)(hv3 >> 16));
  }
  for(; e < end; e++){
    unsigned int hv = *(const unsigned int*)(hb + (size_t)esrc[e]*H_ + lane*2);
    a0 += us2f((unsigned short)(hv & 0xFFFFu));
    a1 += us2f((unsigned short)(hv >> 16));
  }
  float inv = 1.f / fmaxf((float)(end-beg), 1.f);
  unsigned int o = ((unsigned int)f2us(a1*inv)<<16) | f2us(a0*inv);
  *(unsigned int*)((unsigned short*)MeanB + (size_t)n*H_ + lane*2) = o;
}

// GAT gather, single pass, unroll-4
__global__ __launch_bounds__(256) void k_gat_gather(const int* __restrict__ row_ptr, const int* __restrict__ esrc,
    const float* __restrict__ als, const float* __restrict__ ald, const bf16* __restrict__ HGH,
    int hh, bf16* __restrict__ ACCB){
  int n = blockIdx.x*4 + (threadIdx.x>>6);
  int lane = threadIdx.x & 63;
  if(n >= N_) return;
  int beg = row_ptr[n], end = row_ptr[n+1];
  float aldn = ald[n];
  float eself = expc(lrelu(als[n] + aldn));
  const unsigned short* hb = (const unsigned short*)HGH;
  unsigned int hv = *(const unsigned int*)(hb + (size_t)n*H_ + lane*2);
  float den = eself;
  float a0 = eself*us2f((unsigned short)(hv & 0xFFFFu));
  float a1 = eself*us2f((unsigned short)(hv >> 16));
  int e = beg;
  for(; e+3 < end; e += 4){
    int s0 = esrc[e], s1 = esrc[e+1], s2 = esrc[e+2], s3 = esrc[e+3];
    unsigned int sv0 = *(const unsigned int*)(hb + (size_t)s0*H_ + lane*2);
    unsigned int sv1 = *(const unsigned int*)(hb + (size_t)s1*H_ + lane*2);
    unsigned int sv2 = *(const unsigned int*)(hb + (size_t)s2*H_ + lane*2);
    unsigned int sv3 = *(const unsigned int*)(hb + (size_t)s3*H_ + lane*2);
    float w0 = expc(lrelu(als[s0] + aldn));
    float w1 = expc(lrelu(als[s1] + aldn));
    float w2 = expc(lrelu(als[s2] + aldn));
    float w3 = expc(lrelu(als[s3] + aldn));
    den += w0 + w1 + w2 + w3;
    a0 += w0*us2f((unsigned short)(sv0 & 0xFFFFu)) + w1*us2f((unsigned short)(sv1 & 0xFFFFu))
        + w2*us2f((unsigned short)(sv2 & 0xFFFFu)) + w3*us2f((unsigned short)(sv3 & 0xFFFFu));
    a1 += w0*us2f((unsigned short)(sv0 >> 16)) + w1*us2f((unsigned short)(sv1 >> 16))
        + w2*us2f((unsigned short)(sv2 >> 16)) + w3*us2f((unsigned short)(sv3 >> 16));
  }
  for(; e < end; e++){
    int s = esrc[e];
    float w = expc(lrelu(als[s] + aldn));
    unsigned int sv = *(const unsigned int*)(hb + (size_t)s*H_ + lane*2);
    den += w;
    a0 += w*us2f((unsigned short)(sv & 0xFFFFu));
    a1 += w*us2f((unsigned short)(sv >> 16));
  }
  float inv = 1.f/(3.f*den);
  a0 *= inv; a1 *= inv;
  unsigned int* acc = (unsigned int*)((unsigned short*)ACCB + (size_t)n*H_ + lane*2);
  if(hh != 0){
    unsigned int old = *acc;
    a0 += us2f((unsigned short)(old & 0xFFFFu));
    a1 += us2f((unsigned short)(old >> 16));
  }
  *acc = ((unsigned int)f2us(a1)<<16) | f2us(a0);
}

// h3 finalize + pool
#define NPW_ 16
__global__ __launch_bounds__(256) void k_h3fin_pool(const bf16* __restrict__ ACCB, const float* __restrict__ bg,
    const float* __restrict__ g3, const float* __restrict__ be3, const float* __restrict__ m3, const float* __restrict__ v3,
    const int* __restrict__ batch, float* __restrict__ pooled, float* __restrict__ gcnt){
  int wave = blockIdx.x*4 + (threadIdx.x>>6);
  int lane = threadIdx.x & 63;
  int n0 = wave*NPW_;
  if(n0 >= N_) return;
  int n1 = n0 + NPW_; if(n1 > N_) n1 = N_;
  int f0 = lane*2, f1 = f0+1;
  float bg0=bg[f0], bg1=bg[f1];
  float g30=g3[f0], g31=g3[f1], be30=be3[f0], be31=be3[f1];
  float m30=m3[f0], m31=m3[f1], v30=v3[f0], v31=v3[f1];
  float r0=0.f, r1=0.f;
  int cur = batch[n0];
  int seg = 0;
  for(int n=n0; n<n1; n++){
    int b = batch[n];
    if(b != cur){
      atomAddF(&pooled[cur*H_ + f0], r0);
      atomAddF(&pooled[cur*H_ + f1], r1);
      if(lane==0) atomAddF(&gcnt[cur], (float)seg);
      r0 = 0.f; r1 = 0.f; seg = 0; cur = b;
    }
    unsigned int hv = *(const unsigned int*)((const unsigned short*)ACCB + (size_t)n*H_ + lane*2);
    float x0 = us2f((unsigned short)(hv & 0xFFFFu)) + bg0;
    float x1 = us2f((unsigned short)(hv >> 16)) + bg1;
    r0 += eluf(bnf(x0, m30, v30, g30, be30));
    r1 += eluf(bnf(x1, m31, v31, g31, be31));
    seg++;
  }
  atomAddF(&pooled[cur*H_ + f0], r0);
  atomAddF(&pooled[cur*H_ + f1], r1);
  if(lane==0) atomAddF(&gcnt[cur], (float)seg);
}

// per-graph head — fp32 output
__global__ __launch_bounds__(128) void k_head(const float* __restrict__ pooledacc, const float* __restrict__ gcnt,
    const float* __restrict__ protos, const float* __restrict__ Wc, const float* __restrict__ bc,
    const float* __restrict__ Wd1, const float* __restrict__ bd1, const float* __restrict__ Wd2, const float* __restrict__ bd2,
    float* __restrict__ out){
  const int g = blockIdx.x, t = threadIdx.x;
  __shared__ float p[128], xn[128], red[128], sims[32], es[32], asg[32], pe[128], t1[256];
  __shared__ float nrm;
  float cg_ = fmaxf(gcnt[g], 1.f);
  p[t] = pooledacc[g*128 + t] / cg_;
  __syncthreads();
  red[t] = p[t]*p[t];
  __syncthreads();
  for(int s=64;s>0;s>>=1){ if(t<s) red[t]+=red[t+s]; __syncthreads(); }
  if(t==0) nrm = fmaxf(sqrtf(red[0]), 1e-8f);
  __syncthreads();
  xn[t] = p[t]/nrm;
  __syncthreads();
  if(t<32){
    float s=0.f, pn=0.f;
    for(int f=0;f<128;f++){ float pv=protos[t*128+f]; s += xn[f]*pv; pn += pv*pv; }
    sims[t] = s / fmaxf(sqrtf(pn), 1e-8f);
  }
  __syncthreads();
  if(t<32){
    float mx=-1e30f;
    for(int j=0;j<32;j++) mx = fmaxf(mx, sims[j]);
    es[t] = __expf(sims[t]-mx);
  }
  __syncthreads();
  if(t<32){
    float sm=0.f;
    for(int j=0;j<32;j++) sm += es[j];
    float a = es[t]/fmaxf(sm,1e-20f);
    asg[t] = a;
    out[8832 + g*32 + t] = a;
  }
  __syncthreads();
  {
    float s=0.f;
    for(int pp=0;pp<32;pp++) s += asg[pp]*protos[pp*128+t];
    pe[t] = s;
    out[640 + g*128 + t] = s;
  }
  __syncthreads();
  if(t<10){
    float s = bc[t];
    for(int f=0;f<128;f++) s += pe[f]*Wc[f*10+t];
    out[g*10 + t] = s;
  }
  for(int j=t;j<256;j+=128){
    float s = bd1[j];
    for(int f=0;f<128;f++) s += p[f]*Wd1[f*256+j];
    t1[j] = fmaxf(s, 0.f);
  }
  __syncthreads();
  {
    float s = bd2[t];
    for(int j=0;j<256;j++) s += t1[j]*Wd2[j*128+t];
    out[10880 + g*128 + t] = s;
  }
}

__global__ void k_sentinel(float* out, float code){
  out[0] = code;
}

extern "C" void kernel_launch(void* const* d_in, const int* in_sizes, int n_in,
                              void* d_out, int out_size, void* d_ws, size_t ws_size,
                              hipStream_t stream){
  const float* X    = (const float*)d_in[0];
  const int*  EI    = (const int*)d_in[1];
  const int*  batch = (const int*)d_in[2];
  const int* src = EI;
  const int* dst = EI + E_;

  int iW1,ib1,iWl,iWr,ibs,iWg,ias,iad,ibg,ipr,iWc,ibc,iWd1,ibd1,iWd2,ibd2;
  int ig1,ibe1,im1,iv1,ig2,ibe2,im2,iv2,ig3,ibe3,im3,iv3;
  if(n_in >= 31 && in_sizes[5] == 128){
    iW1=3; ib1=4; ig1=5; ibe1=6; im1=7; iv1=8;
    iWl=9; iWr=10; ibs=11; ig2=12; ibe2=13; im2=14; iv2=15;
    iWg=16; ias=17; iad=18; ibg=19; ig3=20; ibe3=21; im3=22; iv3=23;
    ipr=24; iWc=25; ibc=26; iWd1=27; ibd1=28; iWd2=29; ibd2=30;
  }else{
    iW1=3; ib1=4; iWl=5; iWr=6; ibs=7; iWg=8; ias=9; iad=10; ibg=11;
    ipr=12; iWc=13; ibc=14; iWd1=15; ibd1=16; iWd2=17; ibd2=18;
    ig1=19; ibe1=20; im1=21; iv1=22; ig2=23; ibe2=24; im2=25; iv2=26;
    ig3=27; ibe3=28; im3=29; iv3=30;
  }
  const float* W1 = (const float*)d_in[iW1];   const float* b1 = (const float*)d_in[ib1];
  const float* Wl = (const float*)d_in[iWl];   const float* Wr = (const float*)d_in[iWr];
  const float* bs = (const float*)d_in[ibs];   const float* Wg = (const float*)d_in[iWg];
  const float* a_src = (const float*)d_in[ias]; const float* a_dst = (const float*)d_in[iad];
  const float* bg = (const float*)d_in[ibg];   const float* protos = (const float*)d_in[ipr];
  const float* Wc = (const float*)d_in[iWc];   const float* bc = (const float*)d_in[ibc];
  const float* Wd1 = (const float*)d_in[iWd1]; const float* bd1 = (const float*)d_in[ibd1];
  const float* Wd2 = (const float*)d_in[iWd2]; const float* bd2 = (const float*)d_in[ibd2];
  const float* g1 = (const float*)d_in[ig1];   const float* be1 = (const float*)d_in[ibe1];
  const float* m1 = (const float*)d_in[im1];   const float* v1 = (const float*)d_in[iv1];
  const float* g2 = (const float*)d_in[ig2];   const float* be2 = (const float*)d_in[ibe2];
  const float* m2 = (const float*)d_in[im2];   const float* v2 = (const float*)d_in[iv2];
  const float* g3 = (const float*)d_in[ig3];   const float* be3 = (const float*)d_in[ibe3];
  const float* m3 = (const float*)d_in[im3];   const float* v3 = (const float*)d_in[iv3];

  const size_t NF = (size_t)N_*H_;
  const size_t intN = (size_t)N_ + (N_+1) + N_ + E_ + 128;
  const size_t fltN = (size_t)3*N_ + G_*H_ + G_;
  const size_t NEED = NF*2*3 + intN*4 + fltN*4 + (size_t)6*16384*2;
  if(ws_size < NEED){
    k_sentinel<<<1,1,0,stream>>>((float*)d_out, 1000.f + (float)(ws_size>>20));
    return;
  }
  bf16* RA = (bf16*)d_ws;            // h -> h2
  bf16* RB = RA + NF;                // h1 -> hgh (per head)
  bf16* RC = RB + NF;                // mean_nb -> h3 accumulator
  int*  cnt     = (int*)(RC + NF);
  int*  row_ptr = cnt + N_;
  int*  tmp     = row_ptr + (N_+1);
  int*  esrc    = tmp + N_;
  int*  bsum    = esrc + E_;         // 64
  int*  boff    = bsum + 64;         // 64
  float* dinv   = (float*)(boff + 64);
  float* als    = dinv + N_;
  float* ald    = als + N_;
  float* pooled = ald + N_;
  float* gcnt   = pooled + (size_t)G_*H_;
  unsigned short* WTg = (unsigned short*)(gcnt + G_);

  // ---- weight prep + CSR build ----
  k_wprep<<<(6*16384+255)/256, 256, 0, stream>>>(W1, Wl, Wr, Wg, WTg);
  hipMemsetAsync(cnt, 0, N_*sizeof(int), stream);
  k_count<<<(E_+255)/256, 256, 0, stream>>>(dst, cnt);
  k_scan1<<<NB_, 1024, 0, stream>>>(cnt, row_ptr, dinv, bsum);
  k_scan2<<<1, 64, 0, stream>>>(bsum, boff, row_ptr);
  k_scan3<<<(N_+255)/256, 256, 0, stream>>>(row_ptr, boff, tmp);
  k_scatter<<<(E_+255)/256, 256, 0, stream>>>(src, dst, tmp, esrc);

  const int GB = (N_+3)/4;
  const int MB = (N_+63)/64;
  // ---- GCN ----
  k_mm_x<<<MB, 256, 0, stream>>>(X, WTg, RA);
  k_gcn_gather<<<GB, 256, 0, stream>>>(row_ptr, esrc, dinv, RA, b1, g1, be1, m1, v1, RB);
  // ---- SAGE ----
  k_sage_gather<<<GB, 256, 0, stream>>>(row_ptr, esrc, RB, RC);
  k_sage_mm<<<MB, 256, 0, stream>>>(RC, RB, WTg + 16384, WTg + 2*16384, bs, g2, be2, m2, v2, RA);
  // ---- GAT (per head) ----
  for(int hh=0; hh<3; hh++){
    k_gat_mm<<<MB, 256, 0, stream>>>(RA, WTg + (3+hh)*16384, a_src, a_dst, hh, RB, als, ald);
    k_gat_gather<<<GB, 256, 0, stream>>>(row_ptr, esrc, als, ald, RB, hh, RC);
  }
  // ---- pool + heads ----
  hipMemsetAsync(pooled, 0, (size_t)(G_*H_+G_)*sizeof(float), stream);
  {
    int waves = (N_ + NPW_ - 1)/NPW_;
    int blocks = (waves + 3)/4;
    k_h3fin_pool<<<blocks, 256, 0, stream>>>(RC, bg, g3, be3, m3, v3, batch, pooled, gcnt);
  }
  k_head<<<G_, 128, 0, stream>>>(pooled, gcnt, protos, Wc, bc, Wd1, bd1, Wd2, bd2, (float*)d_out);
}

// Round 14
// 435.208 us; speedup vs baseline: 7.8977x; 1.1081x over previous
//
#include <hip/hip_runtime.h>
#include <hip/hip_bf16.h>
#include <stdint.h>
#include <stddef.h>

#define N_ 50000
#define E_ 600000
#define F_ 128
#define H_ 128
#define G_ 64
#define P_ 32
#define C_ 10
#define NB_ 49   // scan blocks: ceil(N/1024)

typedef __hip_bfloat16 bf16;
typedef __attribute__((ext_vector_type(8))) short short8;
typedef __attribute__((ext_vector_type(4))) float float4v;

__device__ __forceinline__ float b2f(bf16 x){ return __bfloat162float(x); }
__device__ __forceinline__ float us2f(unsigned short u){ return __uint_as_float(((unsigned int)u)<<16); }
__device__ __forceinline__ unsigned short f2us(float x){ bf16 h = __float2bfloat16(x); return *(unsigned short*)&h; }
__device__ __forceinline__ float eluf(float x){ return x>0.f ? x : expm1f(x); }
__device__ __forceinline__ float bnf(float x,float m,float v,float g,float b){ return (x-m)*rsqrtf(v+1e-5f)*g+b; }
__device__ __forceinline__ float lrelu(float x){ return x>0.f ? x : 0.2f*x; }
__device__ __forceinline__ float expc(float x){ return __expf(fminf(x, 50.f)); }
__device__ __forceinline__ void atomAddF(float* a, float v){ unsafeAtomicAdd(a, v); }

// ---------------- weight prep: WT[m][n][k] (bf16) = W_m[k][n] ----------------
__global__ __launch_bounds__(256) void k_wprep(const float* __restrict__ W1, const float* __restrict__ Wl,
    const float* __restrict__ Wr, const float* __restrict__ Wg, unsigned short* __restrict__ WT){
  int idx = blockIdx.x*256 + threadIdx.x;
  if(idx >= 6*16384) return;
  int m = idx >> 14, rem = idx & 16383;
  int n = rem >> 7, k = rem & 127;
  float v;
  if(m==0)      v = W1[k*128+n];
  else if(m==1) v = Wl[k*128+n];
  else if(m==2) v = Wr[k*128+n];
  else          v = Wg[k*384 + (m-3)*128 + n];
  WT[idx] = f2us(v);
}

// ---------------- MFMA GEMM helpers ----------------
__device__ __forceinline__ void stage_WT(const unsigned short* __restrict__ WTg, unsigned short* lds, int tid){
  #pragma unroll
  for(int i=0;i<8;i++){
    int idx = tid + i*256;
    int n = idx>>4, c = idx&15;
    uint4 v = *(const uint4*)(WTg + (size_t)idx*8);
    int cs = c ^ (n & 15);
    *(uint4*)(lds + n*128 + cs*8) = v;
  }
}
__device__ __forceinline__ short8 read_Bfrag(const unsigned short* lds, int tile, int kc, int lane){
  int n = tile*16 + (lane&15);
  int c = kc*4 + (lane>>4);
  int cs = c ^ (lane & 15);
  return *(const short8*)(lds + n*128 + cs*8);
}
__device__ __forceinline__ void load_Afrag_bf16(const bf16* A, int row, int lane, short8 af[4]){
  const unsigned short* ap = (const unsigned short*)A + (size_t)row*128 + (lane>>4)*8;
  #pragma unroll
  for(int kc=0;kc<4;kc++) af[kc] = *(const short8*)(ap + kc*32);
}
__device__ __forceinline__ void mfma_pass(const unsigned short* lds, const short8 af[4], int lane, float4v acc[8]){
  #pragma unroll
  for(int tile=0;tile<8;tile++){
    #pragma unroll
    for(int kc=0;kc<4;kc++){
      short8 bfv = read_Bfrag(lds, tile, kc, lane);
      acc[tile] = __builtin_amdgcn_mfma_f32_16x16x32_bf16(af[kc], bfv, acc[tile], 0, 0, 0);
    }
  }
}

// h(bf16) = X(f32) @ W1
__global__ __launch_bounds__(256) void k_mm_x(const float* __restrict__ X, const unsigned short* __restrict__ WTg,
                                              bf16* __restrict__ HB){
  __shared__ unsigned short Wlds[128*128];
  const int tid = threadIdx.x, lane = tid&63, w = tid>>6;
  const int row0 = blockIdx.x*64;
  stage_WT(WTg, Wlds, tid);
  int arow = row0 + w*16 + (lane&15);
  int ar = arow < N_ ? arow : N_-1;
  const float* ap = X + (size_t)ar*128 + (lane>>4)*8;
  short8 af[4];
  #pragma unroll
  for(int kc=0;kc<4;kc++){
    float4 a = *(const float4*)(ap + kc*32);
    float4 b = *(const float4*)(ap + kc*32 + 4);
    short8 v;
    v[0]=(short)f2us(a.x); v[1]=(short)f2us(a.y); v[2]=(short)f2us(a.z); v[3]=(short)f2us(a.w);
    v[4]=(short)f2us(b.x); v[5]=(short)f2us(b.y); v[6]=(short)f2us(b.z); v[7]=(short)f2us(b.w);
    af[kc]=v;
  }
  __syncthreads();
  float4v acc[8];
  #pragma unroll
  for(int t=0;t<8;t++){ acc[t][0]=0.f; acc[t][1]=0.f; acc[t][2]=0.f; acc[t][3]=0.f; }
  mfma_pass(Wlds, af, lane, acc);
  const int colb = lane&15, q = lane>>4;
  unsigned short* ob = (unsigned short*)HB;
  #pragma unroll
  for(int r=0;r<4;r++){
    int ro = row0 + w*16 + q*4 + r;
    if(ro < N_){
      #pragma unroll
      for(int tile=0;tile<8;tile++)
        ob[(size_t)ro*128 + tile*16 + colb] = f2us(acc[tile][r]);
    }
  }
}

// h2(bf16) = elu(bn2( mean@Wl + h1@Wr + bs ))
__global__ __launch_bounds__(256) void k_sage_mm(const bf16* __restrict__ MaB, const bf16* __restrict__ H1B,
    const unsigned short* __restrict__ WlT, const unsigned short* __restrict__ WrT,
    const float* __restrict__ bs, const float* __restrict__ g2, const float* __restrict__ be2,
    const float* __restrict__ m2, const float* __restrict__ v2, bf16* __restrict__ H2B){
  __shared__ unsigned short Wlds[128*128];
  const int tid = threadIdx.x, lane = tid&63, w = tid>>6;
  const int row0 = blockIdx.x*64;
  int arow = row0 + w*16 + (lane&15);
  int ar = arow < N_ ? arow : N_-1;
  float4v acc[8];
  #pragma unroll
  for(int t=0;t<8;t++){ acc[t][0]=0.f; acc[t][1]=0.f; acc[t][2]=0.f; acc[t][3]=0.f; }
  short8 af[4];

  stage_WT(WlT, Wlds, tid);
  load_Afrag_bf16(MaB, ar, lane, af);
  __syncthreads();
  mfma_pass(Wlds, af, lane, acc);
  __syncthreads();
  stage_WT(WrT, Wlds, tid);
  load_Afrag_bf16(H1B, ar, lane, af);
  __syncthreads();
  mfma_pass(Wlds, af, lane, acc);

  const int colb = lane&15, q = lane>>4;
  unsigned short* ob = (unsigned short*)H2B;
  #pragma unroll
  for(int tile=0;tile<8;tile++){
    int col = tile*16 + colb;
    float bsv=bs[col], gv=g2[col], bev=be2[col], mv=m2[col], vv=v2[col];
    #pragma unroll
    for(int r=0;r<4;r++){
      int ro = row0 + w*16 + q*4 + r;
      if(ro < N_){
        float x = acc[tile][r] + bsv;
        ob[(size_t)ro*128 + col] = f2us(eluf(bnf(x, mv, vv, gv, bev)));
      }
    }
  }
}

// HG3[n][hh][128](bf16) = h2 @ Wg_hh for all 3 heads; fused logits -> als3/ald3[n*3+hh]
__global__ __launch_bounds__(256) void k_gat_mm_all(const bf16* __restrict__ H2B, const unsigned short* __restrict__ WgT,
    const float* __restrict__ a_src, const float* __restrict__ a_dst,
    bf16* __restrict__ HG3, float* __restrict__ als3, float* __restrict__ ald3){
  __shared__ unsigned short Wlds[128*128];
  const int tid = threadIdx.x, lane = tid&63, w = tid>>6;
  const int row0 = blockIdx.x*64;
  int arow = row0 + w*16 + (lane&15);
  int ar = arow < N_ ? arow : N_-1;
  short8 af[4];
  load_Afrag_bf16(H2B, ar, lane, af);
  const int colb = lane&15, q = lane>>4;
  unsigned short* ob = (unsigned short*)HG3;
  for(int hh=0; hh<3; hh++){
    if(hh) __syncthreads();
    stage_WT(WgT + hh*16384, Wlds, tid);
    __syncthreads();
    float4v acc[8];
    #pragma unroll
    for(int t=0;t<8;t++){ acc[t][0]=0.f; acc[t][1]=0.f; acc[t][2]=0.f; acc[t][3]=0.f; }
    mfma_pass(Wlds, af, lane, acc);
    float asv[8], adv[8];
    #pragma unroll
    for(int tile=0;tile<8;tile++){
      asv[tile] = a_src[hh*128 + tile*16 + colb];
      adv[tile] = a_dst[hh*128 + tile*16 + colb];
    }
    #pragma unroll
    for(int r=0;r<4;r++){
      int ro = row0 + w*16 + q*4 + r;
      float ps = 0.f, pd = 0.f;
      #pragma unroll
      for(int tile=0;tile<8;tile++){ ps += acc[tile][r]*asv[tile]; pd += acc[tile][r]*adv[tile]; }
      #pragma unroll
      for(int o=8;o>0;o>>=1){ ps += __shfl_down(ps,o,16); pd += __shfl_down(pd,o,16); }
      if(ro < N_){
        #pragma unroll
        for(int tile=0;tile<8;tile++)
          ob[(size_t)ro*384 + hh*128 + tile*16 + colb] = f2us(acc[tile][r]);
        if(colb == 0){ als3[ro*3+hh] = ps; ald3[ro*3+hh] = pd; }
      }
    }
  }
}

// ---------------- CSR build ----------------
__global__ __launch_bounds__(256) void k_count(const int* __restrict__ dst, int* __restrict__ cnt){
  int e = blockIdx.x*256 + threadIdx.x;
  if(e < E_) atomicAdd(&cnt[dst[e]], 1);
}

__global__ __launch_bounds__(1024) void k_scan1(const int* __restrict__ cnt, int* __restrict__ row_ptr,
                                                float* __restrict__ dinv, int* __restrict__ bsum){
  __shared__ int wsum[16];
  const int t = threadIdx.x, lane = t & 63, wid = t >> 6;
  int i = blockIdx.x*1024 + t;
  int v = (i<N_) ? cnt[i] : 0;
  int x = v;
  #pragma unroll
  for(int o=1;o<64;o<<=1){
    int y = __shfl_up(x, o, 64);
    if(lane >= o) x += y;
  }
  if(lane==63) wsum[wid] = x;
  __syncthreads();
  if(wid==0){
    int s = (lane<16) ? wsum[lane] : 0;
    #pragma unroll
    for(int o=1;o<16;o<<=1){
      int y = __shfl_up(s, o, 64);
      if(lane >= o) s += y;
    }
    if(lane<16) wsum[lane] = s;
  }
  __syncthreads();
  int waveoff = (wid>0) ? wsum[wid-1] : 0;
  int incl = waveoff + x;
  if(i<N_){
    row_ptr[i] = incl - v;
    dinv[i] = rsqrtf((float)v + 1.f);
  }
  if(t==1023) bsum[blockIdx.x] = incl;
}

__global__ __launch_bounds__(64) void k_scan2(const int* __restrict__ bsum, int* __restrict__ boff,
                                              int* __restrict__ row_ptr){
  int lane = threadIdx.x;
  int v = (lane < NB_) ? bsum[lane] : 0;
  int x = v;
  #pragma unroll
  for(int o=1;o<64;o<<=1){
    int y = __shfl_up(x, o, 64);
    if(lane >= o) x += y;
  }
  if(lane < NB_) boff[lane] = x - v;
  if(lane == 63) row_ptr[N_] = x;
}

__global__ __launch_bounds__(256) void k_scan3(int* __restrict__ row_ptr, const int* __restrict__ boff,
                                               int* __restrict__ tmp){
  int i = blockIdx.x*256 + threadIdx.x;
  if(i < N_){
    int r = row_ptr[i] + boff[i>>10];
    row_ptr[i] = r;
    tmp[i] = r;
  }
}

__global__ __launch_bounds__(256) void k_scatter(const int* __restrict__ src, const int* __restrict__ dst,
                                                 int* __restrict__ tmp, int* __restrict__ esrc){
  int e = blockIdx.x*256 + threadIdx.x;
  if(e < E_){
    int d = dst[e];
    int pos = atomicAdd(&tmp[d], 1);
    esrc[pos] = src[e];
  }
}

// ---------------- CSR gather kernels ----------------
__global__ __launch_bounds__(256) void k_gcn_gather(const int* __restrict__ row_ptr, const int* __restrict__ esrc,
    const float* __restrict__ dinv, const bf16* __restrict__ HB,
    const float* __restrict__ b1, const float* __restrict__ g1, const float* __restrict__ be1,
    const float* __restrict__ m1, const float* __restrict__ v1, bf16* __restrict__ H1B){
  int n = blockIdx.x*4 + (threadIdx.x>>6);
  int lane = threadIdx.x & 63;
  if(n >= N_) return;
  int beg = row_ptr[n], end = row_ptr[n+1];
  float dn = dinv[n];
  float a0 = 0.f, a1 = 0.f;
  const unsigned short* hb = (const unsigned short*)HB;
  int e = beg;
  for(; e+3 < end; e += 4){
    int s0 = esrc[e], s1 = esrc[e+1], s2 = esrc[e+2], s3 = esrc[e+3];
    unsigned int hv0 = *(const unsigned int*)(hb + (size_t)s0*H_ + lane*2);
    unsigned int hv1 = *(const unsigned int*)(hb + (size_t)s1*H_ + lane*2);
    unsigned int hv2 = *(const unsigned int*)(hb + (size_t)s2*H_ + lane*2);
    unsigned int hv3 = *(const unsigned int*)(hb + (size_t)s3*H_ + lane*2);
    float c0 = dinv[s0]*dn, c1 = dinv[s1]*dn, c2 = dinv[s2]*dn, c3 = dinv[s3]*dn;
    a0 += c0*us2f((unsigned short)(hv0 & 0xFFFFu)) + c1*us2f((unsigned short)(hv1 & 0xFFFFu))
        + c2*us2f((unsigned short)(hv2 & 0xFFFFu)) + c3*us2f((unsigned short)(hv3 & 0xFFFFu));
    a1 += c0*us2f((unsigned short)(hv0 >> 16)) + c1*us2f((unsigned short)(hv1 >> 16))
        + c2*us2f((unsigned short)(hv2 >> 16)) + c3*us2f((unsigned short)(hv3 >> 16));
  }
  for(; e < end; e++){
    int s = esrc[e];
    float c = dinv[s]*dn;
    unsigned int hv = *(const unsigned int*)(hb + (size_t)s*H_ + lane*2);
    a0 += c*us2f((unsigned short)(hv & 0xFFFFu));
    a1 += c*us2f((unsigned short)(hv >> 16));
  }
  unsigned int hv = *(const unsigned int*)(hb + (size_t)n*H_ + lane*2);
  int f0 = lane*2, f1 = f0+1;
  float x0 = a0 + us2f((unsigned short)(hv & 0xFFFFu))*dn*dn + b1[f0];
  float x1 = a1 + us2f((unsigned short)(hv >> 16))*dn*dn + b1[f1];
  x0 = eluf(bnf(x0, m1[f0], v1[f0], g1[f0], be1[f0]));
  x1 = eluf(bnf(x1, m1[f1], v1[f1], g1[f1], be1[f1]));
  unsigned int o = ((unsigned int)f2us(x1)<<16) | f2us(x0);
  *(unsigned int*)((unsigned short*)H1B + (size_t)n*H_ + lane*2) = o;
}

__global__ __launch_bounds__(256) void k_sage_gather(const int* __restrict__ row_ptr, const int* __restrict__ esrc,
    const bf16* __restrict__ H1B, bf16* __restrict__ MeanB){
  int n = blockIdx.x*4 + (threadIdx.x>>6);
  int lane = threadIdx.x & 63;
  if(n >= N_) return;
  int beg = row_ptr[n], end = row_ptr[n+1];
  float a0 = 0.f, a1 = 0.f;
  const unsigned short* hb = (const unsigned short*)H1B;
  int e = beg;
  for(; e+3 < end; e += 4){
    int s0 = esrc[e], s1 = esrc[e+1], s2 = esrc[e+2], s3 = esrc[e+3];
    unsigned int hv0 = *(const unsigned int*)(hb + (size_t)s0*H_ + lane*2);
    unsigned int hv1 = *(const unsigned int*)(hb + (size_t)s1*H_ + lane*2);
    unsigned int hv2 = *(const unsigned int*)(hb + (size_t)s2*H_ + lane*2);
    unsigned int hv3 = *(const unsigned int*)(hb + (size_t)s3*H_ + lane*2);
    a0 += us2f((unsigned short)(hv0 & 0xFFFFu)) + us2f((unsigned short)(hv1 & 0xFFFFu))
        + us2f((unsigned short)(hv2 & 0xFFFFu)) + us2f((unsigned short)(hv3 & 0xFFFFu));
    a1 += us2f((unsigned short)(hv0 >> 16)) + us2f((unsigned short)(hv1 >> 16))
        + us2f((unsigned short)(hv2 >> 16)) + us2f((unsigned short)(hv3 >> 16));
  }
  for(; e < end; e++){
    unsigned int hv = *(const unsigned int*)(hb + (size_t)esrc[e]*H_ + lane*2);
    a0 += us2f((unsigned short)(hv & 0xFFFFu));
    a1 += us2f((unsigned short)(hv >> 16));
  }
  float inv = 1.f / fmaxf((float)(end-beg), 1.f);
  unsigned int o = ((unsigned int)f2us(a1*inv)<<16) | f2us(a0*inv);
  *(unsigned int*)((unsigned short*)MeanB + (size_t)n*H_ + lane*2) = o;
}

// GAT gather, all 3 heads in one traversal; writes h3 head-mean (bf16) once
__global__ __launch_bounds__(256) void k_gat_gather3(const int* __restrict__ row_ptr, const int* __restrict__ esrc,
    const float* __restrict__ als3, const float* __restrict__ ald3, const bf16* __restrict__ HG3,
    bf16* __restrict__ H3B){
  int n = blockIdx.x*4 + (threadIdx.x>>6);
  int lane = threadIdx.x & 63;
  if(n >= N_) return;
  int beg = row_ptr[n], end = row_ptr[n+1];
  float ald0 = ald3[n*3+0], ald1 = ald3[n*3+1], ald2 = ald3[n*3+2];
  float es0 = expc(lrelu(als3[n*3+0] + ald0));
  float es1 = expc(lrelu(als3[n*3+1] + ald1));
  float es2 = expc(lrelu(als3[n*3+2] + ald2));
  const unsigned short* hb = (const unsigned short*)HG3;
  size_t nb = (size_t)n*384 + lane*2;
  unsigned int h0 = *(const unsigned int*)(hb + nb);
  unsigned int h1 = *(const unsigned int*)(hb + nb + 128);
  unsigned int h2 = *(const unsigned int*)(hb + nb + 256);
  float den0 = es0, den1 = es1, den2 = es2;
  float a00 = es0*us2f((unsigned short)(h0 & 0xFFFFu)), a01 = es0*us2f((unsigned short)(h0 >> 16));
  float a10 = es1*us2f((unsigned short)(h1 & 0xFFFFu)), a11 = es1*us2f((unsigned short)(h1 >> 16));
  float a20 = es2*us2f((unsigned short)(h2 & 0xFFFFu)), a21 = es2*us2f((unsigned short)(h2 >> 16));
  int e = beg;
  for(; e+1 < end; e += 2){
    int s0 = esrc[e], s1 = esrc[e+1];
    size_t b0 = (size_t)s0*384 + lane*2, b1 = (size_t)s1*384 + lane*2;
    unsigned int p00 = *(const unsigned int*)(hb + b0);
    unsigned int p01 = *(const unsigned int*)(hb + b0 + 128);
    unsigned int p02 = *(const unsigned int*)(hb + b0 + 256);
    unsigned int p10 = *(const unsigned int*)(hb + b1);
    unsigned int p11 = *(const unsigned int*)(hb + b1 + 128);
    unsigned int p12 = *(const unsigned int*)(hb + b1 + 256);
    float w00 = expc(lrelu(als3[s0*3+0] + ald0));
    float w01 = expc(lrelu(als3[s0*3+1] + ald1));
    float w02 = expc(lrelu(als3[s0*3+2] + ald2));
    float w10 = expc(lrelu(als3[s1*3+0] + ald0));
    float w11 = expc(lrelu(als3[s1*3+1] + ald1));
    float w12 = expc(lrelu(als3[s1*3+2] + ald2));
    den0 += w00 + w10; den1 += w01 + w11; den2 += w02 + w12;
    a00 += w00*us2f((unsigned short)(p00 & 0xFFFFu)) + w10*us2f((unsigned short)(p10 & 0xFFFFu));
    a01 += w00*us2f((unsigned short)(p00 >> 16))     + w10*us2f((unsigned short)(p10 >> 16));
    a10 += w01*us2f((unsigned short)(p01 & 0xFFFFu)) + w11*us2f((unsigned short)(p11 & 0xFFFFu));
    a11 += w01*us2f((unsigned short)(p01 >> 16))     + w11*us2f((unsigned short)(p11 >> 16));
    a20 += w02*us2f((unsigned short)(p02 & 0xFFFFu)) + w12*us2f((unsigned short)(p12 & 0xFFFFu));
    a21 += w02*us2f((unsigned short)(p02 >> 16))     + w12*us2f((unsigned short)(p12 >> 16));
  }
  if(e < end){
    int s = esrc[e];
    size_t b0 = (size_t)s*384 + lane*2;
    unsigned int p0 = *(const unsigned int*)(hb + b0);
    unsigned int p1 = *(const unsigned int*)(hb + b0 + 128);
    unsigned int p2 = *(const unsigned int*)(hb + b0 + 256);
    float w0 = expc(lrelu(als3[s*3+0] + ald0));
    float w1 = expc(lrelu(als3[s*3+1] + ald1));
    float w2 = expc(lrelu(als3[s*3+2] + ald2));
    den0 += w0; den1 += w1; den2 += w2;
    a00 += w0*us2f((unsigned short)(p0 & 0xFFFFu)); a01 += w0*us2f((unsigned short)(p0 >> 16));
    a10 += w1*us2f((unsigned short)(p1 & 0xFFFFu)); a11 += w1*us2f((unsigned short)(p1 >> 16));
    a20 += w2*us2f((unsigned short)(p2 & 0xFFFFu)); a21 += w2*us2f((unsigned short)(p2 >> 16));
  }
  float i0 = 1.f/(3.f*den0), i1 = 1.f/(3.f*den1), i2 = 1.f/(3.f*den2);
  float r0 = a00*i0 + a10*i1 + a20*i2;
  float r1 = a01*i0 + a11*i1 + a21*i2;
  unsigned int o = ((unsigned int)f2us(r1)<<16) | f2us(r0);
  *(unsigned int*)((unsigned short*)H3B + (size_t)n*H_ + lane*2) = o;
}

// h3 finalize + pool
#define NPW_ 16
__global__ __launch_bounds__(256) void k_h3fin_pool(const bf16* __restrict__ ACCB, const float* __restrict__ bg,
    const float* __restrict__ g3, const float* __restrict__ be3, const float* __restrict__ m3, const float* __restrict__ v3,
    const int* __restrict__ batch, float* __restrict__ pooled, float* __restrict__ gcnt){
  int wave = blockIdx.x*4 + (threadIdx.x>>6);
  int lane = threadIdx.x & 63;
  int n0 = wave*NPW_;
  if(n0 >= N_) return;
  int n1 = n0 + NPW_; if(n1 > N_) n1 = N_;
  int f0 = lane*2, f1 = f0+1;
  float bg0=bg[f0], bg1=bg[f1];
  float g30=g3[f0], g31=g3[f1], be30=be3[f0], be31=be3[f1];
  float m30=m3[f0], m31=m3[f1], v30=v3[f0], v31=v3[f1];
  float r0=0.f, r1=0.f;
  int cur = batch[n0];
  int seg = 0;
  for(int n=n0; n<n1; n++){
    int b = batch[n];
    if(b != cur){
      atomAddF(&pooled[cur*H_ + f0], r0);
      atomAddF(&pooled[cur*H_ + f1], r1);
      if(lane==0) atomAddF(&gcnt[cur], (float)seg);
      r0 = 0.f; r1 = 0.f; seg = 0; cur = b;
    }
    unsigned int hv = *(const unsigned int*)((const unsigned short*)ACCB + (size_t)n*H_ + lane*2);
    float x0 = us2f((unsigned short)(hv & 0xFFFFu)) + bg0;
    float x1 = us2f((unsigned short)(hv >> 16)) + bg1;
    r0 += eluf(bnf(x0, m30, v30, g30, be30));
    r1 += eluf(bnf(x1, m31, v31, g31, be31));
    seg++;
  }
  atomAddF(&pooled[cur*H_ + f0], r0);
  atomAddF(&pooled[cur*H_ + f1], r1);
  if(lane==0) atomAddF(&gcnt[cur], (float)seg);
}

// per-graph head — fp32 output
__global__ __launch_bounds__(128) void k_head(const float* __restrict__ pooledacc, const float* __restrict__ gcnt,
    const float* __restrict__ protos, const float* __restrict__ Wc, const float* __restrict__ bc,
    const float* __restrict__ Wd1, const float* __restrict__ bd1, const float* __restrict__ Wd2, const float* __restrict__ bd2,
    float* __restrict__ out){
  const int g = blockIdx.x, t = threadIdx.x;
  __shared__ float p[128], xn[128], red[128], sims[32], es[32], asg[32], pe[128], t1[256];
  __shared__ float nrm;
  float cg_ = fmaxf(gcnt[g], 1.f);
  p[t] = pooledacc[g*128 + t] / cg_;
  __syncthreads();
  red[t] = p[t]*p[t];
  __syncthreads();
  for(int s=64;s>0;s>>=1){ if(t<s) red[t]+=red[t+s]; __syncthreads(); }
  if(t==0) nrm = fmaxf(sqrtf(red[0]), 1e-8f);
  __syncthreads();
  xn[t] = p[t]/nrm;
  __syncthreads();
  if(t<32){
    float s=0.f, pn=0.f;
    for(int f=0;f<128;f++){ float pv=protos[t*128+f]; s += xn[f]*pv; pn += pv*pv; }
    sims[t] = s / fmaxf(sqrtf(pn), 1e-8f);
  }
  __syncthreads();
  if(t<32){
    float mx=-1e30f;
    for(int j=0;j<32;j++) mx = fmaxf(mx, sims[j]);
    es[t] = __expf(sims[t]-mx);
  }
  __syncthreads();
  if(t<32){
    float sm=0.f;
    for(int j=0;j<32;j++) sm += es[j];
    float a = es[t]/fmaxf(sm,1e-20f);
    asg[t] = a;
    out[8832 + g*32 + t] = a;
  }
  __syncthreads();
  {
    float s=0.f;
    for(int pp=0;pp<32;pp++) s += asg[pp]*protos[pp*128+t];
    pe[t] = s;
    out[640 + g*128 + t] = s;
  }
  __syncthreads();
  if(t<10){
    float s = bc[t];
    for(int f=0;f<128;f++) s += pe[f]*Wc[f*10+t];
    out[g*10 + t] = s;
  }
  for(int j=t;j<256;j+=128){
    float s = bd1[j];
    for(int f=0;f<128;f++) s += p[f]*Wd1[f*256+j];
    t1[j] = fmaxf(s, 0.f);
  }
  __syncthreads();
  {
    float s = bd2[t];
    for(int j=0;j<256;j++) s += t1[j]*Wd2[j*128+t];
    out[10880 + g*128 + t] = s;
  }
}

__global__ void k_sentinel(float* out, float code){
  out[0] = code;
}

extern "C" void kernel_launch(void* const* d_in, const int* in_sizes, int n_in,
                              void* d_out, int out_size, void* d_ws, size_t ws_size,
                              hipStream_t stream){
  const float* X    = (const float*)d_in[0];
  const int*  EI    = (const int*)d_in[1];
  const int*  batch = (const int*)d_in[2];
  const int* src = EI;
  const int* dst = EI + E_;

  int iW1,ib1,iWl,iWr,ibs,iWg,ias,iad,ibg,ipr,iWc,ibc,iWd1,ibd1,iWd2,ibd2;
  int ig1,ibe1,im1,iv1,ig2,ibe2,im2,iv2,ig3,ibe3,im3,iv3;
  if(n_in >= 31 && in_sizes[5] == 128){
    iW1=3; ib1=4; ig1=5; ibe1=6; im1=7; iv1=8;
    iWl=9; iWr=10; ibs=11; ig2=12; ibe2=13; im2=14; iv2=15;
    iWg=16; ias=17; iad=18; ibg=19; ig3=20; ibe3=21; im3=22; iv3=23;
    ipr=24; iWc=25; ibc=26; iWd1=27; ibd1=28; iWd2=29; ibd2=30;
  }else{
    iW1=3; ib1=4; iWl=5; iWr=6; ibs=7; iWg=8; ias=9; iad=10; ibg=11;
    ipr=12; iWc=13; ibc=14; iWd1=15; ibd1=16; iWd2=17; ibd2=18;
    ig1=19; ibe1=20; im1=21; iv1=22; ig2=23; ibe2=24; im2=25; iv2=26;
    ig3=27; ibe3=28; im3=29; iv3=30;
  }
  const float* W1 = (const float*)d_in[iW1];   const float* b1 = (const float*)d_in[ib1];
  const float* Wl = (const float*)d_in[iWl];   const float* Wr = (const float*)d_in[iWr];
  const float* bs = (const float*)d_in[ibs];   const float* Wg = (const float*)d_in[iWg];
  const float* a_src = (const float*)d_in[ias]; const float* a_dst = (const float*)d_in[iad];
  const float* bg = (const float*)d_in[ibg];   const float* protos = (const float*)d_in[ipr];
  const float* Wc = (const float*)d_in[iWc];   const float* bc = (const float*)d_in[ibc];
  const float* Wd1 = (const float*)d_in[iWd1]; const float* bd1 = (const float*)d_in[ibd1];
  const float* Wd2 = (const float*)d_in[iWd2]; const float* bd2 = (const float*)d_in[ibd2];
  const float* g1 = (const float*)d_in[ig1];   const float* be1 = (const float*)d_in[ibe1];
  const float* m1 = (const float*)d_in[im1];   const float* v1 = (const float*)d_in[iv1];
  const float* g2 = (const float*)d_in[ig2];   const float* be2 = (const float*)d_in[ibe2];
  const float* m2 = (const float*)d_in[im2];   const float* v2 = (const float*)d_in[iv2];
  const float* g3 = (const float*)d_in[ig3];   const float* be3 = (const float*)d_in[ibe3];
  const float* m3 = (const float*)d_in[im3];   const float* v3 = (const float*)d_in[iv3];

  const size_t NF = (size_t)N_*H_;
  const size_t intN = (size_t)N_ + (N_+1) + N_ + E_ + 128;
  const size_t fltN = (size_t)6*N_ + G_*H_ + G_;
  const size_t NEED = NF*2*3 + (size_t)N_*384*2 + intN*4 + fltN*4 + (size_t)6*16384*2;
  if(ws_size < NEED){
    k_sentinel<<<1,1,0,stream>>>((float*)d_out, 1000.f + (float)(ws_size>>20));
    return;
  }
  bf16* RA = (bf16*)d_ws;            // h -> h2
  bf16* RB = RA + NF;                // h1
  bf16* RC = RB + NF;                // mean_nb -> h3
  bf16* HG3 = RC + NF;               // N x 384 (3 heads)
  int*  cnt     = (int*)(HG3 + (size_t)N_*384);
  int*  row_ptr = cnt + N_;
  int*  tmp     = row_ptr + (N_+1);
  int*  esrc    = tmp + N_;
  int*  bsum    = esrc + E_;
  int*  boff    = bsum + 64;
  float* dinv   = (float*)(boff + 64);
  float* als3   = dinv + N_;         // N*3
  float* ald3   = als3 + (size_t)N_*3;
  float* pooled = ald3 + (size_t)N_*3;
  float* gcnt   = pooled + (size_t)G_*H_;
  unsigned short* WTg = (unsigned short*)(gcnt + G_);

  // ---- weight prep + CSR build ----
  k_wprep<<<(6*16384+255)/256, 256, 0, stream>>>(W1, Wl, Wr, Wg, WTg);
  hipMemsetAsync(cnt, 0, N_*sizeof(int), stream);
  k_count<<<(E_+255)/256, 256, 0, stream>>>(dst, cnt);
  k_scan1<<<NB_, 1024, 0, stream>>>(cnt, row_ptr, dinv, bsum);
  k_scan2<<<1, 64, 0, stream>>>(bsum, boff, row_ptr);
  k_scan3<<<(N_+255)/256, 256, 0, stream>>>(row_ptr, boff, tmp);
  k_scatter<<<(E_+255)/256, 256, 0, stream>>>(src, dst, tmp, esrc);

  const int GB = (N_+3)/4;
  const int MB = (N_+63)/64;
  // ---- GCN ----
  k_mm_x<<<MB, 256, 0, stream>>>(X, WTg, RA);
  k_gcn_gather<<<GB, 256, 0, stream>>>(row_ptr, esrc, dinv, RA, b1, g1, be1, m1, v1, RB);
  // ---- SAGE ----
  k_sage_gather<<<GB, 256, 0, stream>>>(row_ptr, esrc, RB, RC);
  k_sage_mm<<<MB, 256, 0, stream>>>(RC, RB, WTg + 16384, WTg + 2*16384, bs, g2, be2, m2, v2, RA);
  // ---- GAT (all heads fused) ----
  k_gat_mm_all<<<MB, 256, 0, stream>>>(RA, WTg + 3*16384, a_src, a_dst, HG3, als3, ald3);
  k_gat_gather3<<<GB, 256, 0, stream>>>(row_ptr, esrc, als3, ald3, HG3, RC);
  // ---- pool + heads ----
  hipMemsetAsync(pooled, 0, (size_t)(G_*H_+G_)*sizeof(float), stream);
  {
    int waves = (N_ + NPW_ - 1)/NPW_;
    int blocks = (waves + 3)/4;
    k_h3fin_pool<<<blocks, 256, 0, stream>>>(RC, bg, g3, be3, m3, v3, batch, pooled, gcnt);
  }
  k_head<<<G_, 128, 0, stream>>>(pooled, gcnt, protos, Wc, bc, Wd1, bd1, Wd2, bd2, (float*)d_out);
}